// Round 3
// baseline (5495.524 us; speedup 1.0000x reference)
//
#include <hip/hip_runtime.h>
#include <cstdint>

// ============================================================================
// Ladder transformer forward on MI355X (gfx950).  Round 3.
// Decision log:
//  - R2: f32 IO confirmed (finite absmax 2.125). Error = bf16 compute noise
//    (~17 sublayers x 0.2%/stage), not a bug. Threshold 0.77 needs ~f32-level
//    compute.
//  - R3: split-bf16 GEMM: every operand as hi+lo bf16 (RTNE), 3 MFMA per
//    fragment (Ah*Bh + Ah*Bl + Al*Bh). Rep error ~2^-17 -> cumulative error
//    ~0.05 absmax. 3x MFMA flops, 2x staging, MFMA density 3x m97 structure.
//  - All intermediates written hi/lo by producing epilogues; weights split
//    once per use by split_kernel. rs stays f32.
//  - WS ~221MB, lifetime-overlapped: REGION1 = {act-split | sc+P | h}.
// ============================================================================

typedef unsigned short u16;
typedef __attribute__((ext_vector_type(8))) __bf16 bf16x8;
typedef __attribute__((ext_vector_type(4))) float f32x4;

#define DI __device__ __forceinline__

constexpr int BB = 2, SSQ = 2048, HH0 = 2048, HH1 = 1024, NLAY = 8, HH4 = 4096;
constexpr int MM = BB * SSQ;  // 4096 token rows

DI float bf2f(u16 h) {
  union { uint32_t u; float f; } x; x.u = ((uint32_t)h) << 16; return x.f;
}
DI u16 f2bf(float f) {
  union { float f; uint32_t u; } x; x.f = f;
  uint32_t u = x.u;
  return (u16)((u + 0x7fffu + ((u >> 16) & 1u)) >> 16);  // RTNE
}

// ---- flags -----------------------------------------------------------------
enum {
  FB_BIAS = 1, FB_RES = 2, FB_RELU = 4, FB_F32 = 8, FB_SPLIT = 16,
  FB_CSKIP = 32, FB_CKLOOP = 64
};

// ============================================================================
// Split GEMM: C[M,N] = sum_k A[m,k]*B[n,k], A,B given as hi/lo bf16 pairs.
// acc += Ah*Bh + Ah*Bl + Al*Bh  (3x mfma_f32_16x16x32_bf16).
// 128x128 tile, BK=32, 256 threads = 4 waves (2x2 of 64x64), 4x4 16x16 frags.
// ============================================================================
template <int F>
__global__ __launch_bounds__(256) void gemm_split(
    const u16* __restrict__ Ah, const u16* __restrict__ Al, long sAz, int lda,
    const u16* __restrict__ Bh, const u16* __restrict__ Bl, long sBz, int ldb,
    const float* __restrict__ bias, const float* __restrict__ resF,
    float* Cf, u16* Ch, u16* Cl, long sCz, int ldc, int K) {
  int bx = blockIdx.x, by = blockIdx.y, bz = blockIdx.z;
  if ((F & FB_CSKIP) && bx > by) return;  // strictly-upper tile: never read

  __shared__ __align__(16) u16 Ash[128 * 32];
  __shared__ __align__(16) u16 Asl[128 * 32];
  __shared__ __align__(16) u16 Bsh[128 * 32];
  __shared__ __align__(16) u16 Bsl[128 * 32];

  int tid = threadIdx.x;
  int lane = tid & 63;
  int wave = tid >> 6;
  int wr = (wave >> 1) << 6;
  int wc = (wave & 1) << 6;
  int lrow = lane & 15;
  int kg = lane >> 4;
  int k8 = kg << 3;

  const u16* Abh = Ah + (long)bz * sAz + ((long)(by << 7)) * lda;
  const u16* Abl = Al + (long)bz * sAz + ((long)(by << 7)) * lda;
  const u16* Bbh = Bh + (long)bz * sBz + ((long)(bx << 7)) * ldb;
  const u16* Bbl = Bl + (long)bz * sBz + ((long)(bx << 7)) * ldb;

  int nK = (F & FB_CKLOOP) ? ((by + 1) << 2) : (K >> 5);

  f32x4 acc[4][4] = {};

  for (int kt = 0; kt < nK; ++kt) {
    __syncthreads();
    int k0 = kt << 5;
#pragma unroll
    for (int it = 0; it < 2; ++it) {
      int idx = (it << 8) + tid;      // 0..511, lane-consecutive within wave
      int r = idx >> 2;               // tile row 0..127
      int c8 = (idx & 3) << 3;        // col chunk 0/8/16/24
      long goff = (long)r * lda + (k0 + c8);
      long gofB = (long)r * ldb + (k0 + c8);
      int loff = idx << 3;
      __builtin_amdgcn_global_load_lds(
          (__attribute__((address_space(1))) void*)(Abh + goff),
          (__attribute__((address_space(3))) void*)(&Ash[loff]), 16, 0, 0);
      __builtin_amdgcn_global_load_lds(
          (__attribute__((address_space(1))) void*)(Abl + goff),
          (__attribute__((address_space(3))) void*)(&Asl[loff]), 16, 0, 0);
      __builtin_amdgcn_global_load_lds(
          (__attribute__((address_space(1))) void*)(Bbh + gofB),
          (__attribute__((address_space(3))) void*)(&Bsh[loff]), 16, 0, 0);
      __builtin_amdgcn_global_load_lds(
          (__attribute__((address_space(1))) void*)(Bbl + gofB),
          (__attribute__((address_space(3))) void*)(&Bsl[loff]), 16, 0, 0);
    }
    __syncthreads();

    bf16x8 afh[4], bfh[4], bfl[4];
#pragma unroll
    for (int mi = 0; mi < 4; ++mi)
      afh[mi] = *(const bf16x8*)&Ash[((wr + (mi << 4) + lrow) << 5) + k8];
#pragma unroll
    for (int ni = 0; ni < 4; ++ni) {
      bfh[ni] = *(const bf16x8*)&Bsh[((wc + (ni << 4) + lrow) << 5) + k8];
      bfl[ni] = *(const bf16x8*)&Bsl[((wc + (ni << 4) + lrow) << 5) + k8];
    }
#pragma unroll
    for (int mi = 0; mi < 4; ++mi)
#pragma unroll
      for (int ni = 0; ni < 4; ++ni) {
        acc[mi][ni] = __builtin_amdgcn_mfma_f32_16x16x32_bf16(
            afh[mi], bfh[ni], acc[mi][ni], 0, 0, 0);
        acc[mi][ni] = __builtin_amdgcn_mfma_f32_16x16x32_bf16(
            afh[mi], bfl[ni], acc[mi][ni], 0, 0, 0);
      }
    bf16x8 afl[4];
#pragma unroll
    for (int mi = 0; mi < 4; ++mi)
      afl[mi] = *(const bf16x8*)&Asl[((wr + (mi << 4) + lrow) << 5) + k8];
#pragma unroll
    for (int mi = 0; mi < 4; ++mi)
#pragma unroll
      for (int ni = 0; ni < 4; ++ni)
        acc[mi][ni] = __builtin_amdgcn_mfma_f32_16x16x32_bf16(
            afl[mi], bfh[ni], acc[mi][ni], 0, 0, 0);
  }

  // epilogue: row = by*128 + wr + mi*16 + kg*4 + r ; col = bx*128 + wc + ni*16 + lrow
  int m0 = (by << 7) + wr + (kg << 2);
  int n0 = (bx << 7) + wc;
#pragma unroll
  for (int mi = 0; mi < 4; ++mi) {
#pragma unroll
    for (int ni = 0; ni < 4; ++ni) {
      int col = n0 + (ni << 4) + lrow;
      float bv = 0.f;
      if (F & FB_BIAS) bv = bias[col];
      int rb = m0 + (mi << 4);
#pragma unroll
      for (int r = 0; r < 4; ++r) {
        float v = acc[mi][ni][r] + bv;
        if (F & FB_RELU) v = fmaxf(v, 0.f);
        long ci = (long)bz * sCz + (long)(rb + r) * ldc + col;
        if (F & FB_RES) v += resF[ci];
        if (F & FB_F32) Cf[ci] = v;
        if (F & FB_SPLIT) {
          u16 h = f2bf(v);
          Ch[ci] = h;
          Cl[ci] = f2bf(v - bf2f(h));
        }
      }
    }
  }
}

// ============================================================================
// elementwise split: f32 -> (hi, lo) bf16
// ============================================================================
__global__ void split_kernel(const float* __restrict__ src, u16* __restrict__ hi,
                             u16* __restrict__ lo) {
  long i = ((long)blockIdx.x * 256 + threadIdx.x) << 2;
  float4 v = *(const float4*)(src + i);
  ushort4 h, l;
  h.x = f2bf(v.x); l.x = f2bf(v.x - bf2f(h.x));
  h.y = f2bf(v.y); l.y = f2bf(v.y - bf2f(h.y));
  h.z = f2bf(v.z); l.z = f2bf(v.z - bf2f(h.z));
  h.w = f2bf(v.w); l.w = f2bf(v.w - bf2f(h.w));
  *(ushort4*)(hi + i) = h;
  *(ushort4*)(lo + i) = l;
}

// ============================================================================
// degenerate-row flags: deg[b*S+q] = 1 iff attmask[b, 0..q] all zero
// ============================================================================
__global__ void deg_kernel(const int* __restrict__ am, int* __restrict__ deg) {
  int i = blockIdx.x * 256 + threadIdx.x;
  int b = i >> 11, q = i & 2047;
  const int* a = am + b * SSQ;
  int any = 0;
  for (int k = 0; k <= q; ++k) any |= (a[k] != 0);
  deg[i] = !any;
}

// ============================================================================
// transpose (per batch, generic bf16 [b][S][H1] -> [b][H1][S])
// ============================================================================
__global__ void transpose_v(const u16* __restrict__ V, u16* __restrict__ VT) {
  __shared__ u16 t[64][68];
  int b = blockIdx.z;
  int c0 = blockIdx.x << 6;
  int r0 = blockIdx.y << 6;
  int tr = threadIdx.x >> 4, tc = threadIdx.x & 15;
  const u16* src = V + ((long)(b * SSQ + r0)) * HH1 + c0;
#pragma unroll
  for (int j = 0; j < 4; ++j) {
    int r = (j << 4) + tr;
    ushort4 u = *(const ushort4*)(src + (long)r * HH1 + (tc << 2));
    t[r][(tc << 2) + 0] = u.x; t[r][(tc << 2) + 1] = u.y;
    t[r][(tc << 2) + 2] = u.z; t[r][(tc << 2) + 3] = u.w;
  }
  __syncthreads();
  u16* dst = VT + ((long)b * HH1 + c0) * SSQ + r0;
#pragma unroll
  for (int j = 0; j < 4; ++j) {
    int c = (j << 4) + tr;
    ushort4 u;
    u.x = t[(tc << 2) + 0][c]; u.y = t[(tc << 2) + 1][c];
    u.z = t[(tc << 2) + 2][c]; u.w = t[(tc << 2) + 3][c];
    *(ushort4*)(dst + (long)c * SSQ + (tc << 2)) = u;
  }
}

// ============================================================================
// column mean of V (for degenerate rows)
// ============================================================================
__global__ void colmean_partial(const u16* __restrict__ Vh, const u16* __restrict__ Vl,
                                float* __restrict__ part) {
  int n = blockIdx.x * 256 + threadIdx.x;
  int b = blockIdx.y, kc = blockIdx.z;
  long base = ((long)(b * SSQ + kc * 256)) * HH1 + n;
  float s = 0.f;
  for (int k = 0; k < 256; ++k) {
    long o = base + (long)k * HH1;
    s += bf2f(Vh[o]) + bf2f(Vl[o]);
  }
  part[((kc * BB) + b) * HH1 + n] = s;
}
__global__ void colmean_final(const float* __restrict__ part, float* __restrict__ mV) {
  int i = blockIdx.x * 256 + threadIdx.x;
  int b = i >> 10, n = i & 1023;
  float s = 0.f;
  for (int kc = 0; kc < 8; ++kc) s += part[((kc * BB) + b) * HH1 + n];
  mV[i] = s * (1.f / (float)SSQ);
}

// ============================================================================
// row softmax (causal + key padding). Writes P hi/lo for k<qt_end.
// ============================================================================
__global__ void softmax_kernel(const float* __restrict__ sc, u16* __restrict__ Ph,
                               u16* __restrict__ Pl, const int* __restrict__ am,
                               const int* __restrict__ deg) {
  int q = blockIdx.x, b = blockIdx.y;
  int tid = threadIdx.x;
  long rowoff = ((long)b * SSQ + q) * SSQ;
  int qt_end = ((q >> 7) + 1) << 7;
  if (deg[b * SSQ + q]) {
    for (int k = tid; k < qt_end; k += 256) { Ph[rowoff + k] = 0; Pl[rowoff + k] = 0; }
    return;
  }
  const int* a = am + b * SSQ;
  const float scale = 0.03125f;  // 1/sqrt(1024)
  __shared__ float sred[8];
  int w = tid >> 6, ln = tid & 63;

  float m = -1e30f;
  for (int k = tid; k <= q; k += 256)
    if (a[k]) m = fmaxf(m, sc[rowoff + k]);
#pragma unroll
  for (int o = 32; o; o >>= 1) m = fmaxf(m, __shfl_xor(m, o));
  if (!ln) sred[w] = m;
  __syncthreads();
  float M = fmaxf(fmaxf(sred[0], sred[1]), fmaxf(sred[2], sred[3]));

  float s = 0.f;
  for (int k = tid; k <= q; k += 256)
    if (a[k]) s += expf((sc[rowoff + k] - M) * scale);
#pragma unroll
  for (int o = 32; o; o >>= 1) s += __shfl_xor(s, o);
  if (!ln) sred[4 + w] = s;
  __syncthreads();
  float Ssum = sred[4] + sred[5] + sred[6] + sred[7];
  float inv = 1.f / Ssum;

  for (int k = tid; k < qt_end; k += 256) {
    float p = 0.f;
    if (k <= q && a[k]) p = expf((sc[rowoff + k] - M) * scale) * inv;
    u16 h = f2bf(p);
    Ph[rowoff + k] = h;
    Pl[rowoff + k] = f2bf(p - bf2f(h));
  }
}

// ============================================================================
// post-attention: degenerate rows rs += meanV ; x hi/lo = split(rs)
// ============================================================================
__global__ void attn_post(float* __restrict__ rs, u16* __restrict__ xh,
                          u16* __restrict__ xl, const int* __restrict__ deg,
                          const float* __restrict__ mV) {
  long t = (long)blockIdx.x * 256 + threadIdx.x;
  long i = t << 2;
  int row = (int)(i >> 10);
  int col = (int)(i & 1023);
  int b = row >> 11;
  float4 v = *(const float4*)(rs + i);
  if (deg[row]) {
    const float* m = mV + (b << 10) + col;
    v.x += m[0]; v.y += m[1]; v.z += m[2]; v.w += m[3];
    *(float4*)(rs + i) = v;
  }
  ushort4 h, l;
  h.x = f2bf(v.x); l.x = f2bf(v.x - bf2f(h.x));
  h.y = f2bf(v.y); l.y = f2bf(v.y - bf2f(h.y));
  h.z = f2bf(v.z); l.z = f2bf(v.z - bf2f(h.z));
  h.w = f2bf(v.w); l.w = f2bf(v.w - bf2f(h.w));
  *(ushort4*)(xh + i) = h;
  *(ushort4*)(xl + i) = l;
}

// ============================================================================
// workspace layout (1 MB = 1<<20). Lifetimes:
//   REGION1 (96..160MB): act-split (start / i==1) -> sc+P (attn) -> h (mlp)
// ============================================================================
constexpr size_t MB = 1u << 20;
constexpr size_t OFF_RS   = 0;          // f32 [4096][1024]           16MB
constexpr size_t OFF_XH   = 16 * MB;    // bf16 [4096][1024]           8MB
constexpr size_t OFF_XL   = 24 * MB;
constexpr size_t OFF_QH   = 32 * MB;
constexpr size_t OFF_QL   = 40 * MB;
constexpr size_t OFF_KH   = 48 * MB;
constexpr size_t OFF_KL   = 56 * MB;
constexpr size_t OFF_VH   = 64 * MB;
constexpr size_t OFF_VL   = 72 * MB;
constexpr size_t OFF_VTH  = 80 * MB;
constexpr size_t OFF_VTL  = 88 * MB;
// REGION1:
constexpr size_t OFF_SC   = 96 * MB;    // f32 [B][S][S]              32MB
constexpr size_t OFF_PH   = 128 * MB;   // bf16 [B][S][S]             16MB
constexpr size_t OFF_PL   = 144 * MB;
constexpr size_t OFF_HH   = 96 * MB;    // bf16 [4096][4096]          32MB (alias)
constexpr size_t OFF_HL   = 128 * MB;   //                            32MB (alias)
constexpr size_t OFF_ACTH = 96 * MB;    // bf16 [4096][2048]          16MB (alias)
constexpr size_t OFF_ACTL = 112 * MB;
// weights:
constexpr size_t OFF_DPWH = 160 * MB;   // 2M elts -> 4MB each
constexpr size_t OFF_DPWL = 164 * MB;
constexpr size_t OFF_UPWH = 168 * MB;
constexpr size_t OFF_UPWL = 172 * MB;
constexpr size_t OFF_WQH  = 176 * MB;   // 1M -> 2MB each
constexpr size_t OFF_WQL  = 178 * MB;
constexpr size_t OFF_WKH  = 180 * MB;
constexpr size_t OFF_WKL  = 182 * MB;
constexpr size_t OFF_WVH  = 184 * MB;
constexpr size_t OFF_WVL  = 186 * MB;
constexpr size_t OFF_M1H  = 188 * MB;   // 4M -> 8MB each
constexpr size_t OFF_M1L  = 196 * MB;
constexpr size_t OFF_M2H  = 204 * MB;
constexpr size_t OFF_M2L  = 212 * MB;
constexpr size_t OFF_MV   = 220 * MB;          // f32 [B][H1]
constexpr size_t OFF_PART = OFF_MV + 64 * 1024;
constexpr size_t OFF_DEG  = OFF_PART + 128 * 1024;
// total ~221MB

extern "C" void kernel_launch(void* const* d_in, const int* in_sizes, int n_in,
                              void* d_out, int out_size, void* d_ws, size_t ws_size,
                              hipStream_t stream) {
  (void)in_sizes; (void)n_in; (void)out_size; (void)ws_size;

  const float* z    = (const float*)d_in[0];
  const float* act0 = (const float*)d_in[1];
  const float* act1 = (const float*)d_in[2];
  const int* amask  = (const int*)d_in[3];
  const float* dpw  = (const float*)d_in[4];
  const float* dpb  = (const float*)d_in[5];
  const float* upw  = (const float*)d_in[6];
  const float* upb  = (const float*)d_in[7];
  const float* wqw  = (const float*)d_in[8];
  const float* wqb  = (const float*)d_in[9];
  const float* wkw  = (const float*)d_in[10];
  const float* wkb  = (const float*)d_in[11];
  const float* wvw  = (const float*)d_in[12];
  const float* wvb  = (const float*)d_in[13];
  const float* m1w  = (const float*)d_in[14];
  const float* m1b  = (const float*)d_in[15];
  const float* m2w  = (const float*)d_in[16];
  const float* m2b  = (const float*)d_in[17];

  char* ws = (char*)d_ws;
  float* rs   = (float*)(ws + OFF_RS);
  u16* xh   = (u16*)(ws + OFF_XH);   u16* xl   = (u16*)(ws + OFF_XL);
  u16* Qh   = (u16*)(ws + OFF_QH);   u16* Ql   = (u16*)(ws + OFF_QL);
  u16* Kh   = (u16*)(ws + OFF_KH);   u16* Kl   = (u16*)(ws + OFF_KL);
  u16* Vh   = (u16*)(ws + OFF_VH);   u16* Vl   = (u16*)(ws + OFF_VL);
  u16* VTh  = (u16*)(ws + OFF_VTH);  u16* VTl  = (u16*)(ws + OFF_VTL);
  float* sc = (float*)(ws + OFF_SC);
  u16* Ph   = (u16*)(ws + OFF_PH);   u16* Pl   = (u16*)(ws + OFF_PL);
  u16* hh   = (u16*)(ws + OFF_HH);   u16* hl   = (u16*)(ws + OFF_HL);
  u16* acth = (u16*)(ws + OFF_ACTH); u16* actl = (u16*)(ws + OFF_ACTL);
  u16* dpwh = (u16*)(ws + OFF_DPWH); u16* dpwl = (u16*)(ws + OFF_DPWL);
  u16* upwh = (u16*)(ws + OFF_UPWH); u16* upwl = (u16*)(ws + OFF_UPWL);
  u16* wqh  = (u16*)(ws + OFF_WQH);  u16* wql  = (u16*)(ws + OFF_WQL);
  u16* wkh  = (u16*)(ws + OFF_WKH);  u16* wkl  = (u16*)(ws + OFF_WKL);
  u16* wvh  = (u16*)(ws + OFF_WVH);  u16* wvl  = (u16*)(ws + OFF_WVL);
  u16* m1h  = (u16*)(ws + OFF_M1H);  u16* m1l  = (u16*)(ws + OFF_M1L);
  u16* m2h  = (u16*)(ws + OFF_M2H);  u16* m2l  = (u16*)(ws + OFF_M2L);
  float* mV = (float*)(ws + OFF_MV);
  float* part = (float*)(ws + OFF_PART);
  int* deg  = (int*)(ws + OFF_DEG);

  deg_kernel<<<dim3((BB * SSQ) / 256), 256, 0, stream>>>(amask, deg);

  // one-time weight splits
  split_kernel<<<dim3((HH1 * HH0) / 1024), 256, 0, stream>>>(dpw, dpwh, dpwl);
  split_kernel<<<dim3((HH0 * HH1) / 1024), 256, 0, stream>>>(upw, upwh, upwl);

  // rs = dproj(act0) + b ; x = split(rs)
  split_kernel<<<dim3((MM * HH0) / 1024), 256, 0, stream>>>(act0, acth, actl);
  gemm_split<FB_BIAS | FB_F32 | FB_SPLIT>
      <<<dim3(HH1 / 128, MM / 128, 1), 256, 0, stream>>>(
      acth, actl, 0, HH0, dpwh, dpwl, 0, HH0, dpb, nullptr,
      rs, xh, xl, 0, HH1, HH0);

  for (int i = 0; i < NLAY; ++i) {
    // per-layer weight splits
    split_kernel<<<dim3((HH1 * HH1) / 1024), 256, 0, stream>>>(
        wqw + (size_t)i * HH1 * HH1, wqh, wql);
    split_kernel<<<dim3((HH1 * HH1) / 1024), 256, 0, stream>>>(
        wkw + (size_t)i * HH1 * HH1, wkh, wkl);
    split_kernel<<<dim3((HH1 * HH1) / 1024), 256, 0, stream>>>(
        wvw + (size_t)i * HH1 * HH1, wvh, wvl);
    split_kernel<<<dim3((HH4 * HH1) / 1024), 256, 0, stream>>>(
        m1w + (size_t)i * HH4 * HH1, m1h, m1l);
    split_kernel<<<dim3((HH1 * HH4) / 1024), 256, 0, stream>>>(
        m2w + (size_t)i * HH1 * HH4, m2h, m2l);

    if (i == 1) {
      // rs += dproj(act1) + b ; x = split(rs)   (act buffer aliases h region,
      // dead since previous m2; sc not yet written this layer)
      split_kernel<<<dim3((MM * HH0) / 1024), 256, 0, stream>>>(act1, acth, actl);
      gemm_split<FB_BIAS | FB_RES | FB_F32 | FB_SPLIT>
          <<<dim3(HH1 / 128, MM / 128, 1), 256, 0, stream>>>(
          acth, actl, 0, HH0, dpwh, dpwl, 0, HH0, dpb, rs,
          rs, xh, xl, 0, HH1, HH0);
    }

    // ---- attention ----
    gemm_split<FB_BIAS | FB_SPLIT><<<dim3(HH1 / 128, MM / 128, 1), 256, 0, stream>>>(
        xh, xl, 0, HH1, wqh, wql, 0, HH1, wqb + i * HH1, nullptr,
        nullptr, Qh, Ql, 0, HH1, HH1);
    gemm_split<FB_BIAS | FB_SPLIT><<<dim3(HH1 / 128, MM / 128, 1), 256, 0, stream>>>(
        xh, xl, 0, HH1, wkh, wkl, 0, HH1, wkb + i * HH1, nullptr,
        nullptr, Kh, Kl, 0, HH1, HH1);
    gemm_split<FB_BIAS | FB_SPLIT><<<dim3(HH1 / 128, MM / 128, 1), 256, 0, stream>>>(
        xh, xl, 0, HH1, wvh, wvl, 0, HH1, wvb + i * HH1, nullptr,
        nullptr, Vh, Vl, 0, HH1, HH1);

    transpose_v<<<dim3(HH1 / 64, SSQ / 64, BB), 256, 0, stream>>>(Vh, VTh);
    transpose_v<<<dim3(HH1 / 64, SSQ / 64, BB), 256, 0, stream>>>(Vl, VTl);
    colmean_partial<<<dim3(HH1 / 256, BB, 8), 256, 0, stream>>>(Vh, Vl, part);
    colmean_final<<<dim3((BB * HH1) / 256), 256, 0, stream>>>(part, mV);

    // scores = Q K^T (unscaled), causal tile skip
    gemm_split<FB_F32 | FB_CSKIP><<<dim3(SSQ / 128, SSQ / 128, BB), 256, 0, stream>>>(
        Qh, Ql, (long)SSQ * HH1, HH1, Kh, Kl, (long)SSQ * HH1, HH1, nullptr, nullptr,
        sc, nullptr, nullptr, (long)SSQ * SSQ, SSQ, HH1);

    softmax_kernel<<<dim3(SSQ, BB), 256, 0, stream>>>(sc, Ph, Pl, amask, deg);

    // rs += P @ V  (B = VT), causal-truncated K loop
    gemm_split<FB_RES | FB_F32 | FB_CKLOOP>
        <<<dim3(HH1 / 128, SSQ / 128, BB), 256, 0, stream>>>(
        Ph, Pl, (long)SSQ * SSQ, SSQ, VTh, VTl, (long)HH1 * SSQ, SSQ, nullptr, rs,
        rs, nullptr, nullptr, (long)SSQ * HH1, HH1, SSQ);

    attn_post<<<dim3((MM * HH1 / 4) / 256), 256, 0, stream>>>(rs, xh, xl, deg, mV);

    // ---- mlp ----
    gemm_split<FB_BIAS | FB_RELU | FB_SPLIT>
        <<<dim3(HH4 / 128, MM / 128, 1), 256, 0, stream>>>(
        xh, xl, 0, HH1, m1h, m1l, 0, HH1, m1b + i * HH4, nullptr,
        nullptr, hh, hl, 0, HH4, HH1);
    gemm_split<FB_BIAS | FB_RES | FB_F32 | FB_SPLIT>
        <<<dim3(HH1 / 128, MM / 128, 1), 256, 0, stream>>>(
        hh, hl, 0, HH4, m2h, m2l, 0, HH4, m2b + i * HH1, rs,
        rs, xh, xl, 0, HH1, HH4);
  }

  // out = uproj(x) + b + z   (f32 to d_out)
  gemm_split<FB_BIAS | FB_RES | FB_F32>
      <<<dim3(HH0 / 128, MM / 128, 1), 256, 0, stream>>>(
      xh, xl, 0, HH1, upwh, upwl, 0, HH1, upb, z,
      (float*)d_out, nullptr, nullptr, 0, HH0, HH1);
}

// Round 4
// 4413.574 us; speedup vs baseline: 1.2451x; 1.2451x over previous
//
#include <hip/hip_runtime.h>
#include <cstdint>

// ============================================================================
// Ladder transformer forward on MI355X (gfx950).  Round 4.
// Decision log:
//  - R3 passed (absmax 0.125, 5495us). Top dispatches = mlp2 @200us with
//    10.6% occupancy: grid 256 blocks = 1 block/CU -> barrier drains exposed.
//  - R4: split-K (z, deterministic 2-pass) for mlp2/dproj/scores/PV; QKV
//    fused into one N=3072 GEMM (768 blocks); bijective XCD swizzle (m204)
//    on all GEMMs; softmax caches summed row in LDS.
//  - Aliased ws regions keep total ~221MB:
//      32-80MB : QKV(h+l) -> Ph/Pl -> mlp2/dproj partial -> next QKV
//      96-160MB: act-split | scores partial[2] | h(h+l) ; PV partial @128-160
// ============================================================================

typedef unsigned short u16;
typedef __attribute__((ext_vector_type(8))) __bf16 bf16x8;
typedef __attribute__((ext_vector_type(4))) float f32x4;

#define DI __device__ __forceinline__

constexpr int BB = 2, SSQ = 2048, HH0 = 2048, HH1 = 1024, NLAY = 8, HH4 = 4096;
constexpr int MM = BB * SSQ;  // 4096 token rows

DI float bf2f(u16 h) {
  union { uint32_t u; float f; } x; x.u = ((uint32_t)h) << 16; return x.f;
}
DI u16 f2bf(float f) {
  union { float f; uint32_t u; } x; x.f = f;
  uint32_t u = x.u;
  return (u16)((u + 0x7fffu + ((u >> 16) & 1u)) >> 16);  // RTNE
}

enum {
  FB_BIAS = 1, FB_RES = 2, FB_RELU = 4, FB_F32 = 8, FB_SPLIT = 16,
  FB_CSKIP = 32, FB_CKLOOP = 64
};

// ============================================================================
// Split GEMM: C[M,N] = sum_k A[m,k]*B[n,k], operands hi/lo bf16.
// acc += Ah*Bh + Ah*Bl + Al*Bh. 128x128 tile, BK=32, 4 waves, 4x4 frags.
// KSP>1: K-range split over z; raw f32 partial written at ks*pstride.
// All blocks XCD-swizzled (bijective, m204).
// ============================================================================
template <int F, int KSP>
__global__ __launch_bounds__(256) void gemm_split(
    const u16* __restrict__ Ah, const u16* __restrict__ Al, long sAz, int lda,
    const u16* __restrict__ Bh, const u16* __restrict__ Bl, long sBz, int ldb,
    const float* __restrict__ bias, const float* __restrict__ resF,
    float* Cf, u16* Ch, u16* Cl, long sCz, int ldc, int K, long pstride) {
  // ---- bijective XCD swizzle over the full linear grid ----
  int gx = gridDim.x, gy = gridDim.y, gz = gridDim.z;
  long o = blockIdx.x + (long)gx * (blockIdx.y + (long)gy * blockIdx.z);
  long nwg = (long)gx * gy * gz;
  long cq = nwg >> 3, cr = nwg & 7;
  long xcd = o & 7, cidx = o >> 3;
  long sl = (xcd < cr ? xcd * (cq + 1) : cr * (cq + 1) + (xcd - cr) * cq) + cidx;
  int bx = (int)(sl % gx);
  long tt = sl / gx;
  int by = (int)(tt % gy);
  int bzf = (int)(tt / gy);
  int NB = gz / KSP;
  int bz = bzf % NB;
  int ks = bzf / NB;

  if ((F & FB_CSKIP) && bx > by) return;  // strictly-upper tile: never read

  __shared__ __align__(16) u16 Ash[128 * 32];
  __shared__ __align__(16) u16 Asl[128 * 32];
  __shared__ __align__(16) u16 Bsh[128 * 32];
  __shared__ __align__(16) u16 Bsl[128 * 32];

  int tid = threadIdx.x;
  int lane = tid & 63;
  int wave = tid >> 6;
  int wr = (wave >> 1) << 6;
  int wc = (wave & 1) << 6;
  int lrow = lane & 15;
  int kg = lane >> 4;
  int k8 = kg << 3;

  const u16* Abh = Ah + (long)bz * sAz + ((long)(by << 7)) * lda;
  const u16* Abl = Al + (long)bz * sAz + ((long)(by << 7)) * lda;
  const u16* Bbh = Bh + (long)bz * sBz + ((long)(bx << 7)) * ldb;
  const u16* Bbl = Bl + (long)bz * sBz + ((long)(bx << 7)) * ldb;

  int nKtot = (F & FB_CKLOOP) ? ((by + 1) << 2) : (K >> 5);
  int kbeg = (KSP > 1) ? (ks * nKtot) / KSP : 0;
  int kend = (KSP > 1) ? ((ks + 1) * nKtot) / KSP : nKtot;

  f32x4 acc[4][4] = {};

  for (int kt = kbeg; kt < kend; ++kt) {
    __syncthreads();
    int k0 = kt << 5;
#pragma unroll
    for (int it = 0; it < 2; ++it) {
      int sidx = (it << 8) + tid;     // 0..511
      int r = sidx >> 2;              // tile row 0..127
      int c8 = (sidx & 3) << 3;       // col chunk 0/8/16/24
      long goff = (long)r * lda + (k0 + c8);
      long gofB = (long)r * ldb + (k0 + c8);
      int loff = sidx << 3;
      __builtin_amdgcn_global_load_lds(
          (__attribute__((address_space(1))) void*)(Abh + goff),
          (__attribute__((address_space(3))) void*)(&Ash[loff]), 16, 0, 0);
      __builtin_amdgcn_global_load_lds(
          (__attribute__((address_space(1))) void*)(Abl + goff),
          (__attribute__((address_space(3))) void*)(&Asl[loff]), 16, 0, 0);
      __builtin_amdgcn_global_load_lds(
          (__attribute__((address_space(1))) void*)(Bbh + gofB),
          (__attribute__((address_space(3))) void*)(&Bsh[loff]), 16, 0, 0);
      __builtin_amdgcn_global_load_lds(
          (__attribute__((address_space(1))) void*)(Bbl + gofB),
          (__attribute__((address_space(3))) void*)(&Bsl[loff]), 16, 0, 0);
    }
    __syncthreads();

    bf16x8 afh[4], bfh[4], bfl[4];
#pragma unroll
    for (int mi = 0; mi < 4; ++mi)
      afh[mi] = *(const bf16x8*)&Ash[((wr + (mi << 4) + lrow) << 5) + k8];
#pragma unroll
    for (int ni = 0; ni < 4; ++ni) {
      bfh[ni] = *(const bf16x8*)&Bsh[((wc + (ni << 4) + lrow) << 5) + k8];
      bfl[ni] = *(const bf16x8*)&Bsl[((wc + (ni << 4) + lrow) << 5) + k8];
    }
#pragma unroll
    for (int mi = 0; mi < 4; ++mi)
#pragma unroll
      for (int ni = 0; ni < 4; ++ni) {
        acc[mi][ni] = __builtin_amdgcn_mfma_f32_16x16x32_bf16(
            afh[mi], bfh[ni], acc[mi][ni], 0, 0, 0);
        acc[mi][ni] = __builtin_amdgcn_mfma_f32_16x16x32_bf16(
            afh[mi], bfl[ni], acc[mi][ni], 0, 0, 0);
      }
    bf16x8 afl[4];
#pragma unroll
    for (int mi = 0; mi < 4; ++mi)
      afl[mi] = *(const bf16x8*)&Asl[((wr + (mi << 4) + lrow) << 5) + k8];
#pragma unroll
    for (int mi = 0; mi < 4; ++mi)
#pragma unroll
      for (int ni = 0; ni < 4; ++ni)
        acc[mi][ni] = __builtin_amdgcn_mfma_f32_16x16x32_bf16(
            afl[mi], bfh[ni], acc[mi][ni], 0, 0, 0);
  }

  int m0 = (by << 7) + wr + (kg << 2);
  int n0 = (bx << 7) + wc;
#pragma unroll
  for (int mi = 0; mi < 4; ++mi) {
#pragma unroll
    for (int ni = 0; ni < 4; ++ni) {
      int col = n0 + (ni << 4) + lrow;
      float bv = 0.f;
      if ((KSP == 1) && (F & FB_BIAS)) bv = bias[col];
      int rb = m0 + (mi << 4);
#pragma unroll
      for (int r = 0; r < 4; ++r) {
        float v = acc[mi][ni][r];
        long ci = (long)bz * sCz + (long)(rb + r) * ldc + col;
        if constexpr (KSP > 1) {
          Cf[(long)ks * pstride + ci] = v;  // raw partial
        } else {
          v += bv;
          if (F & FB_RELU) v = fmaxf(v, 0.f);
          if (F & FB_RES) v += resF[ci];
          if (F & FB_F32) Cf[ci] = v;
          if (F & FB_SPLIT) {
            u16 h = f2bf(v);
            Ch[ci] = h;
            Cl[ci] = f2bf(v - bf2f(h));
          }
        }
      }
    }
  }
}

// ============================================================================
// reduce for split-K N=1024 GEMMs: v = p0+p1+bias (+rs); rs=v; x=split(v)
// ============================================================================
template <bool RES>
__global__ void reduce_split(const float* __restrict__ p,
                             const float* __restrict__ bias,
                             float* __restrict__ rs, u16* __restrict__ xh,
                             u16* __restrict__ xl) {
  long i = ((long)blockIdx.x * 256 + threadIdx.x) << 2;
  int col = (int)(i & 1023);
  float4 a = *(const float4*)(p + i);
  float4 b = *(const float4*)(p + i + (long)MM * HH1);
  float4 v;
  v.x = a.x + b.x + bias[col];
  v.y = a.y + b.y + bias[col + 1];
  v.z = a.z + b.z + bias[col + 2];
  v.w = a.w + b.w + bias[col + 3];
  if (RES) {
    float4 r0 = *(const float4*)(rs + i);
    v.x += r0.x; v.y += r0.y; v.z += r0.z; v.w += r0.w;
  }
  *(float4*)(rs + i) = v;
  ushort4 h, l;
  h.x = f2bf(v.x); l.x = f2bf(v.x - bf2f(h.x));
  h.y = f2bf(v.y); l.y = f2bf(v.y - bf2f(h.y));
  h.z = f2bf(v.z); l.z = f2bf(v.z - bf2f(h.z));
  h.w = f2bf(v.w); l.w = f2bf(v.w - bf2f(h.w));
  *(ushort4*)(xh + i) = h;
  *(ushort4*)(xl + i) = l;
}

// ============================================================================
// elementwise split: f32 -> (hi, lo) bf16
// ============================================================================
__global__ void split_kernel(const float* __restrict__ src, u16* __restrict__ hi,
                             u16* __restrict__ lo) {
  long i = ((long)blockIdx.x * 256 + threadIdx.x) << 2;
  float4 v = *(const float4*)(src + i);
  ushort4 h, l;
  h.x = f2bf(v.x); l.x = f2bf(v.x - bf2f(h.x));
  h.y = f2bf(v.y); l.y = f2bf(v.y - bf2f(h.y));
  h.z = f2bf(v.z); l.z = f2bf(v.z - bf2f(h.z));
  h.w = f2bf(v.w); l.w = f2bf(v.w - bf2f(h.w));
  *(ushort4*)(hi + i) = h;
  *(ushort4*)(lo + i) = l;
}

__global__ void concat_bias(const float* __restrict__ qb, const float* __restrict__ kb,
                            const float* __restrict__ vb, float* __restrict__ dst) {
  int j = blockIdx.x * 256 + threadIdx.x;  // 0..3071
  float v = (j < 1024) ? qb[j] : ((j < 2048) ? kb[j - 1024] : vb[j - 2048]);
  dst[j] = v;
}

__global__ void deg_kernel(const int* __restrict__ am, int* __restrict__ deg) {
  int i = blockIdx.x * 256 + threadIdx.x;
  int b = i >> 11, q = i & 2047;
  const int* a = am + b * SSQ;
  int any = 0;
  for (int k = 0; k <= q; ++k) any |= (a[k] != 0);
  deg[i] = !any;
}

// ============================================================================
// transpose: VT[b][n][k] = V[b*S+k][n], V has leading dim sld
// ============================================================================
__global__ void transpose_v(const u16* __restrict__ V, int sld, u16* __restrict__ VT) {
  __shared__ u16 t[64][68];
  int b = blockIdx.z;
  int c0 = blockIdx.x << 6;
  int r0 = blockIdx.y << 6;
  int tr = threadIdx.x >> 4, tc = threadIdx.x & 15;
  const u16* src = V + ((long)(b * SSQ + r0)) * sld + c0;
#pragma unroll
  for (int j = 0; j < 4; ++j) {
    int r = (j << 4) + tr;
    ushort4 u = *(const ushort4*)(src + (long)r * sld + (tc << 2));
    t[r][(tc << 2) + 0] = u.x; t[r][(tc << 2) + 1] = u.y;
    t[r][(tc << 2) + 2] = u.z; t[r][(tc << 2) + 3] = u.w;
  }
  __syncthreads();
  u16* dst = VT + ((long)b * HH1 + c0) * SSQ + r0;
#pragma unroll
  for (int j = 0; j < 4; ++j) {
    int c = (j << 4) + tr;
    ushort4 u;
    u.x = t[(tc << 2) + 0][c]; u.y = t[(tc << 2) + 1][c];
    u.z = t[(tc << 2) + 2][c]; u.w = t[(tc << 2) + 3][c];
    *(ushort4*)(dst + (long)c * SSQ + (tc << 2)) = u;
  }
}

// ============================================================================
// column mean of V (degenerate rows); V hi/lo with leading dim ld
// ============================================================================
__global__ void colmean_partial(const u16* __restrict__ Vh, const u16* __restrict__ Vl,
                                int ld, float* __restrict__ part) {
  int n = blockIdx.x * 256 + threadIdx.x;
  int b = blockIdx.y, kc = blockIdx.z;
  long base = ((long)(b * SSQ + kc * 256)) * ld + n;
  float s = 0.f;
  for (int k = 0; k < 256; ++k) {
    long o = base + (long)k * ld;
    s += bf2f(Vh[o]) + bf2f(Vl[o]);
  }
  part[((kc * BB) + b) * HH1 + n] = s;
}
__global__ void colmean_final(const float* __restrict__ part, float* __restrict__ mV) {
  int i = blockIdx.x * 256 + threadIdx.x;
  int b = i >> 10, n = i & 1023;
  float s = 0.f;
  for (int kc = 0; kc < 8; ++kc) s += part[((kc * BB) + b) * HH1 + n];
  mV[i] = s * (1.f / (float)SSQ);
}

// ============================================================================
// row softmax: reads two score partials (ks0+ks1) into LDS row cache.
// ============================================================================
__global__ void softmax_kernel(const float* __restrict__ sc, u16* __restrict__ Ph,
                               u16* __restrict__ Pl, const int* __restrict__ am,
                               const int* __restrict__ deg) {
  int q = blockIdx.x, b = blockIdx.y;
  int tid = threadIdx.x;
  long rowoff = ((long)b * SSQ + q) * SSQ;
  int qt_end = ((q >> 7) + 1) << 7;
  if (deg[b * SSQ + q]) {
    for (int k = tid; k < qt_end; k += 256) { Ph[rowoff + k] = 0; Pl[rowoff + k] = 0; }
    return;
  }
  const int* a = am + b * SSQ;
  const float scale = 0.03125f;  // 1/sqrt(1024)
  constexpr long PSTR = (long)BB * SSQ * SSQ;
  __shared__ float rowbuf[2048];
  __shared__ float sred[8];
  int w = tid >> 6, ln = tid & 63;

  for (int k = tid; k < qt_end; k += 256)
    rowbuf[k] = sc[rowoff + k] + sc[rowoff + k + PSTR];
  __syncthreads();

  float m = -1e30f;
  for (int k = tid; k <= q; k += 256)
    if (a[k]) m = fmaxf(m, rowbuf[k]);
#pragma unroll
  for (int o = 32; o; o >>= 1) m = fmaxf(m, __shfl_xor(m, o));
  if (!ln) sred[w] = m;
  __syncthreads();
  float M = fmaxf(fmaxf(sred[0], sred[1]), fmaxf(sred[2], sred[3]));

  float s = 0.f;
  for (int k = tid; k <= q; k += 256)
    if (a[k]) s += expf((rowbuf[k] - M) * scale);
#pragma unroll
  for (int o = 32; o; o >>= 1) s += __shfl_xor(s, o);
  if (!ln) sred[4 + w] = s;
  __syncthreads();
  float Ssum = sred[4] + sred[5] + sred[6] + sred[7];
  float inv = 1.f / Ssum;

  for (int k = tid; k < qt_end; k += 256) {
    float p = 0.f;
    if (k <= q && a[k]) p = expf((rowbuf[k] - M) * scale) * inv;
    u16 h = f2bf(p);
    Ph[rowoff + k] = h;
    Pl[rowoff + k] = f2bf(p - bf2f(h));
  }
}

// ============================================================================
// post-attention: rs += pv0+pv1 (+meanV for degenerate rows); x = split(rs)
// ============================================================================
__global__ void attn_post(float* __restrict__ rs, const float* __restrict__ pv,
                          u16* __restrict__ xh, u16* __restrict__ xl,
                          const int* __restrict__ deg, const float* __restrict__ mV) {
  long t = (long)blockIdx.x * 256 + threadIdx.x;
  long i = t << 2;
  int row = (int)(i >> 10);
  int col = (int)(i & 1023);
  int b = row >> 11;
  constexpr long PSTR = (long)BB * SSQ * HH1;
  float4 v = *(const float4*)(rs + i);
  float4 a = *(const float4*)(pv + i);
  float4 c = *(const float4*)(pv + i + PSTR);
  v.x += a.x + c.x; v.y += a.y + c.y; v.z += a.z + c.z; v.w += a.w + c.w;
  if (deg[row]) {
    const float* m = mV + (b << 10) + col;
    v.x += m[0]; v.y += m[1]; v.z += m[2]; v.w += m[3];
  }
  *(float4*)(rs + i) = v;
  ushort4 h, l;
  h.x = f2bf(v.x); l.x = f2bf(v.x - bf2f(h.x));
  h.y = f2bf(v.y); l.y = f2bf(v.y - bf2f(h.y));
  h.z = f2bf(v.z); l.z = f2bf(v.z - bf2f(h.z));
  h.w = f2bf(v.w); l.w = f2bf(v.w - bf2f(h.w));
  *(ushort4*)(xh + i) = h;
  *(ushort4*)(xl + i) = l;
}

// ============================================================================
// workspace layout (1 MB = 1<<20), ~221MB, lifetime-aliased (see header)
// ============================================================================
constexpr size_t MB = 1u << 20;
constexpr size_t OFF_RS    = 0;         // f32 [4096][1024]   16MB
constexpr size_t OFF_XH    = 16 * MB;   // bf16 [4096][1024]   8MB
constexpr size_t OFF_XL    = 24 * MB;
constexpr size_t OFF_QKVH  = 32 * MB;   // bf16 [4096][3072]  24MB   | Ph/Pl | mlp2/dproj partial
constexpr size_t OFF_QKVL  = 56 * MB;
constexpr size_t OFF_PH    = 32 * MB;   // bf16 [B][S][S]     16MB (alias)
constexpr size_t OFF_PL    = 48 * MB;
constexpr size_t OFF_RED   = 32 * MB;   // f32 [2][4096][1024] 32MB (alias)
constexpr size_t OFF_VTH   = 80 * MB;   // bf16 [B][H1][S]     8MB
constexpr size_t OFF_VTL   = 88 * MB;
constexpr size_t OFF_SC    = 96 * MB;   // f32 [2][B][S][S]   64MB   | act-split | h
constexpr size_t OFF_ACTH  = 96 * MB;   // bf16 [4096][2048]  16MB (alias)
constexpr size_t OFF_ACTL  = 112 * MB;
constexpr size_t OFF_HH    = 96 * MB;   // bf16 [4096][4096]  32MB (alias)
constexpr size_t OFF_HL    = 128 * MB;
constexpr size_t OFF_PVP   = 128 * MB;  // f32 [2][B][S][H1]  32MB (alias, dead before h-upper)
constexpr size_t OFF_DPWH  = 160 * MB;  // dproj w hi/lo, 4MB each
constexpr size_t OFF_DPWL  = 164 * MB;
constexpr size_t OFF_UPWH  = 168 * MB;
constexpr size_t OFF_UPWL  = 172 * MB;
constexpr size_t OFF_WQKVH = 176 * MB;  // [3072][1024] 6MB each
constexpr size_t OFF_WQKVL = 182 * MB;
constexpr size_t OFF_M1H   = 188 * MB;  // 8MB each
constexpr size_t OFF_M1L   = 196 * MB;
constexpr size_t OFF_M2H   = 204 * MB;
constexpr size_t OFF_M2L   = 212 * MB;
constexpr size_t OFF_QKVB  = 220 * MB;              // f32 [3072]
constexpr size_t OFF_MV    = OFF_QKVB + 16 * 1024;  // f32 [B][H1]
constexpr size_t OFF_PART  = OFF_MV + 16 * 1024;    // f32 [8][B][H1]
constexpr size_t OFF_DEG   = OFF_PART + 128 * 1024; // i32 [B][S]

extern "C" void kernel_launch(void* const* d_in, const int* in_sizes, int n_in,
                              void* d_out, int out_size, void* d_ws, size_t ws_size,
                              hipStream_t stream) {
  (void)in_sizes; (void)n_in; (void)out_size; (void)ws_size;

  const float* z    = (const float*)d_in[0];
  const float* act0 = (const float*)d_in[1];
  const float* act1 = (const float*)d_in[2];
  const int* amask  = (const int*)d_in[3];
  const float* dpw  = (const float*)d_in[4];
  const float* dpb  = (const float*)d_in[5];
  const float* upw  = (const float*)d_in[6];
  const float* upb  = (const float*)d_in[7];
  const float* wqw  = (const float*)d_in[8];
  const float* wqb  = (const float*)d_in[9];
  const float* wkw  = (const float*)d_in[10];
  const float* wkb  = (const float*)d_in[11];
  const float* wvw  = (const float*)d_in[12];
  const float* wvb  = (const float*)d_in[13];
  const float* m1w  = (const float*)d_in[14];
  const float* m1b  = (const float*)d_in[15];
  const float* m2w  = (const float*)d_in[16];
  const float* m2b  = (const float*)d_in[17];

  char* ws = (char*)d_ws;
  float* rs    = (float*)(ws + OFF_RS);
  u16* xh      = (u16*)(ws + OFF_XH);    u16* xl    = (u16*)(ws + OFF_XL);
  u16* qkvh    = (u16*)(ws + OFF_QKVH);  u16* qkvl  = (u16*)(ws + OFF_QKVL);
  u16* Ph      = (u16*)(ws + OFF_PH);    u16* Pl    = (u16*)(ws + OFF_PL);
  float* redp  = (float*)(ws + OFF_RED);
  u16* VTh     = (u16*)(ws + OFF_VTH);   u16* VTl   = (u16*)(ws + OFF_VTL);
  float* scb   = (float*)(ws + OFF_SC);
  u16* acth    = (u16*)(ws + OFF_ACTH);  u16* actl  = (u16*)(ws + OFF_ACTL);
  u16* hh      = (u16*)(ws + OFF_HH);    u16* hl    = (u16*)(ws + OFF_HL);
  float* pvp   = (float*)(ws + OFF_PVP);
  u16* dpwh    = (u16*)(ws + OFF_DPWH);  u16* dpwl  = (u16*)(ws + OFF_DPWL);
  u16* upwh    = (u16*)(ws + OFF_UPWH);  u16* upwl  = (u16*)(ws + OFF_UPWL);
  u16* wqkvh   = (u16*)(ws + OFF_WQKVH); u16* wqkvl = (u16*)(ws + OFF_WQKVL);
  u16* m1h     = (u16*)(ws + OFF_M1H);   u16* m1l   = (u16*)(ws + OFF_M1L);
  u16* m2h     = (u16*)(ws + OFF_M2H);   u16* m2l   = (u16*)(ws + OFF_M2L);
  float* qkvb  = (float*)(ws + OFF_QKVB);
  float* mV    = (float*)(ws + OFF_MV);
  float* part  = (float*)(ws + OFF_PART);
  int* deg     = (int*)(ws + OFF_DEG);

  deg_kernel<<<dim3((BB * SSQ) / 256), 256, 0, stream>>>(amask, deg);
  split_kernel<<<dim3((HH1 * HH0) / 1024), 256, 0, stream>>>(dpw, dpwh, dpwl);
  split_kernel<<<dim3((HH0 * HH1) / 1024), 256, 0, stream>>>(upw, upwh, upwl);

  // rs = dproj(act0) + b ; x = split(rs)   [split-K=2 + reduce]
  split_kernel<<<dim3((MM * HH0) / 1024), 256, 0, stream>>>(act0, acth, actl);
  gemm_split<0, 2><<<dim3(HH1 / 128, MM / 128, 2), 256, 0, stream>>>(
      acth, actl, 0, HH0, dpwh, dpwl, 0, HH0, nullptr, nullptr,
      redp, nullptr, nullptr, 0, HH1, HH0, (long)MM * HH1);
  reduce_split<false><<<dim3(MM * HH1 / 1024), 256, 0, stream>>>(redp, dpb, rs, xh, xl);

  for (int i = 0; i < NLAY; ++i) {
    // per-layer weight splits + bias concat
    split_kernel<<<dim3((HH1 * HH1) / 1024), 256, 0, stream>>>(
        wqw + (size_t)i * HH1 * HH1, wqkvh, wqkvl);
    split_kernel<<<dim3((HH1 * HH1) / 1024), 256, 0, stream>>>(
        wkw + (size_t)i * HH1 * HH1, wqkvh + HH1 * HH1, wqkvl + HH1 * HH1);
    split_kernel<<<dim3((HH1 * HH1) / 1024), 256, 0, stream>>>(
        wvw + (size_t)i * HH1 * HH1, wqkvh + 2 * HH1 * HH1, wqkvl + 2 * HH1 * HH1);
    concat_bias<<<dim3(12), 256, 0, stream>>>(wqb + i * HH1, wkb + i * HH1,
                                              wvb + i * HH1, qkvb);
    split_kernel<<<dim3((HH4 * HH1) / 1024), 256, 0, stream>>>(
        m1w + (size_t)i * HH4 * HH1, m1h, m1l);
    split_kernel<<<dim3((HH1 * HH4) / 1024), 256, 0, stream>>>(
        m2w + (size_t)i * HH1 * HH4, m2h, m2l);

    if (i == 1) {
      split_kernel<<<dim3((MM * HH0) / 1024), 256, 0, stream>>>(act1, acth, actl);
      gemm_split<0, 2><<<dim3(HH1 / 128, MM / 128, 2), 256, 0, stream>>>(
          acth, actl, 0, HH0, dpwh, dpwl, 0, HH0, nullptr, nullptr,
          redp, nullptr, nullptr, 0, HH1, HH0, (long)MM * HH1);
      reduce_split<true><<<dim3(MM * HH1 / 1024), 256, 0, stream>>>(redp, dpb, rs, xh, xl);
    }

    // ---- attention ----
    // fused QKV: [4096][3072] = x @ [wq;wk;wv]^T
    gemm_split<FB_BIAS | FB_SPLIT, 1><<<dim3(3072 / 128, MM / 128, 1), 256, 0, stream>>>(
        xh, xl, 0, HH1, wqkvh, wqkvl, 0, HH1, qkvb, nullptr,
        nullptr, qkvh, qkvl, 0, 3072, HH1, 0);

    transpose_v<<<dim3(HH1 / 64, SSQ / 64, BB), 256, 0, stream>>>(qkvh + 2048, 3072, VTh);
    transpose_v<<<dim3(HH1 / 64, SSQ / 64, BB), 256, 0, stream>>>(qkvl + 2048, 3072, VTl);
    colmean_partial<<<dim3(HH1 / 256, BB, 8), 256, 0, stream>>>(
        qkvh + 2048, qkvl + 2048, 3072, part);
    colmean_final<<<dim3((BB * HH1) / 256), 256, 0, stream>>>(part, mV);

    // scores = Q K^T, causal tile skip, split-K=2 -> partials in scb
    gemm_split<FB_CSKIP, 2><<<dim3(SSQ / 128, SSQ / 128, BB * 2), 256, 0, stream>>>(
        qkvh, qkvl, (long)SSQ * 3072, 3072, qkvh + 1024, qkvl + 1024,
        (long)SSQ * 3072, 3072, nullptr, nullptr,
        scb, nullptr, nullptr, (long)SSQ * SSQ, SSQ, HH1, (long)BB * SSQ * SSQ);

    softmax_kernel<<<dim3(SSQ, BB), 256, 0, stream>>>(scb, Ph, Pl, amask, deg);

    // PV: split-K=2 over causal-truncated K loop -> partials in pvp
    gemm_split<FB_CKLOOP, 2><<<dim3(HH1 / 128, SSQ / 128, BB * 2), 256, 0, stream>>>(
        Ph, Pl, (long)SSQ * SSQ, SSQ, VTh, VTl, (long)HH1 * SSQ, SSQ, nullptr, nullptr,
        pvp, nullptr, nullptr, (long)SSQ * HH1, HH1, SSQ, (long)BB * SSQ * HH1);

    attn_post<<<dim3((MM * HH1 / 4) / 256), 256, 0, stream>>>(rs, pvp, xh, xl, deg, mV);

    // ---- mlp ----
    gemm_split<FB_BIAS | FB_RELU | FB_SPLIT, 1>
        <<<dim3(HH4 / 128, MM / 128, 1), 256, 0, stream>>>(
        xh, xl, 0, HH1, m1h, m1l, 0, HH1, m1b + i * HH4, nullptr,
        nullptr, hh, hl, 0, HH4, HH1, 0);
    gemm_split<0, 2><<<dim3(HH1 / 128, MM / 128, 2), 256, 0, stream>>>(
        hh, hl, 0, HH4, m2h, m2l, 0, HH4, nullptr, nullptr,
        redp, nullptr, nullptr, 0, HH1, HH4, (long)MM * HH1);
    reduce_split<true><<<dim3(MM * HH1 / 1024), 256, 0, stream>>>(
        redp, m2b + i * HH1, rs, xh, xl);
  }

  // out = uproj(x) + b + z
  gemm_split<FB_BIAS | FB_RES | FB_F32, 1>
      <<<dim3(HH0 / 128, MM / 128, 1), 256, 0, stream>>>(
      xh, xl, 0, HH1, upwh, upwl, 0, HH1, upb, z,
      (float*)d_out, nullptr, nullptr, 0, HH0, HH1, 0);
}

// Round 5
// 4406.013 us; speedup vs baseline: 1.2473x; 1.0017x over previous
//
#include <hip/hip_runtime.h>
#include <cstdint>

// ============================================================================
// Ladder transformer forward on MI355X (gfx950).  Round 5.
// Decision log:
//  - R4: 4413us, mlp1 @116us, MfmaUtil 38%, 8.4M LDS bank conflicts.
//    Analysis: ds_read pattern row*64B + kg*16B -> 8-way conflict per
//    quarter-wave; ds_read (560cy) > MFMA (233cy) per K-step -> LDS-bound.
//  - R5: XOR chunk swizzle, BOTH sides (rule #21): global source chunk
//    pre-swizzled (global_load_lds dest stays linear), read applies the
//    same XOR. jsw = j ^ ((row>>1)&3). 8-way -> 2-way (free). Bit-exact.
//  - Everything else identical to R4 (split-K, fused QKV, XCD swizzle).
// ============================================================================

typedef unsigned short u16;
typedef __attribute__((ext_vector_type(8))) __bf16 bf16x8;
typedef __attribute__((ext_vector_type(4))) float f32x4;

#define DI __device__ __forceinline__

constexpr int BB = 2, SSQ = 2048, HH0 = 2048, HH1 = 1024, NLAY = 8, HH4 = 4096;
constexpr int MM = BB * SSQ;  // 4096 token rows

DI float bf2f(u16 h) {
  union { uint32_t u; float f; } x; x.u = ((uint32_t)h) << 16; return x.f;
}
DI u16 f2bf(float f) {
  union { float f; uint32_t u; } x; x.f = f;
  uint32_t u = x.u;
  return (u16)((u + 0x7fffu + ((u >> 16) & 1u)) >> 16);  // RTNE
}

enum {
  FB_BIAS = 1, FB_RES = 2, FB_RELU = 4, FB_F32 = 8, FB_SPLIT = 16,
  FB_CSKIP = 32, FB_CKLOOP = 64
};

// ============================================================================
// Split GEMM: C[M,N] = sum_k A[m,k]*B[n,k], operands hi/lo bf16.
// acc += Ah*Bh + Ah*Bl + Al*Bh. 128x128 tile, BK=32, 4 waves, 4x4 frags.
// LDS chunk-swizzled (XOR (row>>1)&3) via pre-swizzled global source.
// KSP>1: K-range split over z; raw f32 partial written at ks*pstride.
// ============================================================================
template <int F, int KSP>
__global__ __launch_bounds__(256) void gemm_split(
    const u16* __restrict__ Ah, const u16* __restrict__ Al, long sAz, int lda,
    const u16* __restrict__ Bh, const u16* __restrict__ Bl, long sBz, int ldb,
    const float* __restrict__ bias, const float* __restrict__ resF,
    float* Cf, u16* Ch, u16* Cl, long sCz, int ldc, int K, long pstride) {
  // ---- bijective XCD swizzle over the full linear grid ----
  int gx = gridDim.x, gy = gridDim.y, gz = gridDim.z;
  long o = blockIdx.x + (long)gx * (blockIdx.y + (long)gy * blockIdx.z);
  long nwg = (long)gx * gy * gz;
  long cq = nwg >> 3, cr = nwg & 7;
  long xcd = o & 7, cidx = o >> 3;
  long sl = (xcd < cr ? xcd * (cq + 1) : cr * (cq + 1) + (xcd - cr) * cq) + cidx;
  int bx = (int)(sl % gx);
  long tt = sl / gx;
  int by = (int)(tt % gy);
  int bzf = (int)(tt / gy);
  int NB = gz / KSP;
  int bz = bzf % NB;
  int ks = bzf / NB;

  if ((F & FB_CSKIP) && bx > by) return;  // strictly-upper tile: never read

  __shared__ __align__(16) u16 Ash[128 * 32];
  __shared__ __align__(16) u16 Asl[128 * 32];
  __shared__ __align__(16) u16 Bsh[128 * 32];
  __shared__ __align__(16) u16 Bsl[128 * 32];

  int tid = threadIdx.x;
  int lane = tid & 63;
  int wave = tid >> 6;
  int wr = (wave >> 1) << 6;
  int wc = (wave & 1) << 6;
  int lrow = lane & 15;
  int kg = lane >> 4;
  // swizzled chunk offset for reads: chunk = kg ^ ((row>>1)&3); row bits
  // [1:2] == lrow bits [1:2] because wr+mi*16 is a multiple of 16.
  int kc8 = (kg ^ ((lrow >> 1) & 3)) << 3;

  const u16* Abh = Ah + (long)bz * sAz + ((long)(by << 7)) * lda;
  const u16* Abl = Al + (long)bz * sAz + ((long)(by << 7)) * lda;
  const u16* Bbh = Bh + (long)bz * sBz + ((long)(bx << 7)) * ldb;
  const u16* Bbl = Bl + (long)bz * sBz + ((long)(bx << 7)) * ldb;

  int nKtot = (F & FB_CKLOOP) ? ((by + 1) << 2) : (K >> 5);
  int kbeg = (KSP > 1) ? (ks * nKtot) / KSP : 0;
  int kend = (KSP > 1) ? ((ks + 1) * nKtot) / KSP : nKtot;

  f32x4 acc[4][4] = {};

  for (int kt = kbeg; kt < kend; ++kt) {
    __syncthreads();
    int k0 = kt << 5;
#pragma unroll
    for (int it = 0; it < 2; ++it) {
      int sidx = (it << 8) + tid;     // 0..511
      int r = sidx >> 2;              // tile row 0..127
      int jsw = (sidx & 3) ^ ((r >> 1) & 3);  // pre-swizzled source chunk
      long goff = (long)r * lda + (k0 + (jsw << 3));
      long gofB = (long)r * ldb + (k0 + (jsw << 3));
      int loff = sidx << 3;
      __builtin_amdgcn_global_load_lds(
          (__attribute__((address_space(1))) void*)(Abh + goff),
          (__attribute__((address_space(3))) void*)(&Ash[loff]), 16, 0, 0);
      __builtin_amdgcn_global_load_lds(
          (__attribute__((address_space(1))) void*)(Abl + goff),
          (__attribute__((address_space(3))) void*)(&Asl[loff]), 16, 0, 0);
      __builtin_amdgcn_global_load_lds(
          (__attribute__((address_space(1))) void*)(Bbh + gofB),
          (__attribute__((address_space(3))) void*)(&Bsh[loff]), 16, 0, 0);
      __builtin_amdgcn_global_load_lds(
          (__attribute__((address_space(1))) void*)(Bbl + gofB),
          (__attribute__((address_space(3))) void*)(&Bsl[loff]), 16, 0, 0);
    }
    __syncthreads();

    bf16x8 afh[4], bfh[4], bfl[4];
#pragma unroll
    for (int mi = 0; mi < 4; ++mi)
      afh[mi] = *(const bf16x8*)&Ash[((wr + (mi << 4) + lrow) << 5) + kc8];
#pragma unroll
    for (int ni = 0; ni < 4; ++ni) {
      bfh[ni] = *(const bf16x8*)&Bsh[((wc + (ni << 4) + lrow) << 5) + kc8];
      bfl[ni] = *(const bf16x8*)&Bsl[((wc + (ni << 4) + lrow) << 5) + kc8];
    }
#pragma unroll
    for (int mi = 0; mi < 4; ++mi)
#pragma unroll
      for (int ni = 0; ni < 4; ++ni) {
        acc[mi][ni] = __builtin_amdgcn_mfma_f32_16x16x32_bf16(
            afh[mi], bfh[ni], acc[mi][ni], 0, 0, 0);
        acc[mi][ni] = __builtin_amdgcn_mfma_f32_16x16x32_bf16(
            afh[mi], bfl[ni], acc[mi][ni], 0, 0, 0);
      }
    bf16x8 afl[4];
#pragma unroll
    for (int mi = 0; mi < 4; ++mi)
      afl[mi] = *(const bf16x8*)&Asl[((wr + (mi << 4) + lrow) << 5) + kc8];
#pragma unroll
    for (int mi = 0; mi < 4; ++mi)
#pragma unroll
      for (int ni = 0; ni < 4; ++ni)
        acc[mi][ni] = __builtin_amdgcn_mfma_f32_16x16x32_bf16(
            afl[mi], bfh[ni], acc[mi][ni], 0, 0, 0);
  }

  int m0 = (by << 7) + wr + (kg << 2);
  int n0 = (bx << 7) + wc;
#pragma unroll
  for (int mi = 0; mi < 4; ++mi) {
#pragma unroll
    for (int ni = 0; ni < 4; ++ni) {
      int col = n0 + (ni << 4) + lrow;
      float bv = 0.f;
      if ((KSP == 1) && (F & FB_BIAS)) bv = bias[col];
      int rb = m0 + (mi << 4);
#pragma unroll
      for (int r = 0; r < 4; ++r) {
        float v = acc[mi][ni][r];
        long ci = (long)bz * sCz + (long)(rb + r) * ldc + col;
        if constexpr (KSP > 1) {
          Cf[(long)ks * pstride + ci] = v;  // raw partial
        } else {
          v += bv;
          if (F & FB_RELU) v = fmaxf(v, 0.f);
          if (F & FB_RES) v += resF[ci];
          if (F & FB_F32) Cf[ci] = v;
          if (F & FB_SPLIT) {
            u16 h = f2bf(v);
            Ch[ci] = h;
            Cl[ci] = f2bf(v - bf2f(h));
          }
        }
      }
    }
  }
}

// ============================================================================
// reduce for split-K N=1024 GEMMs: v = p0+p1+bias (+rs); rs=v; x=split(v)
// ============================================================================
template <bool RES>
__global__ void reduce_split(const float* __restrict__ p,
                             const float* __restrict__ bias,
                             float* __restrict__ rs, u16* __restrict__ xh,
                             u16* __restrict__ xl) {
  long i = ((long)blockIdx.x * 256 + threadIdx.x) << 2;
  int col = (int)(i & 1023);
  float4 a = *(const float4*)(p + i);
  float4 b = *(const float4*)(p + i + (long)MM * HH1);
  float4 v;
  v.x = a.x + b.x + bias[col];
  v.y = a.y + b.y + bias[col + 1];
  v.z = a.z + b.z + bias[col + 2];
  v.w = a.w + b.w + bias[col + 3];
  if (RES) {
    float4 r0 = *(const float4*)(rs + i);
    v.x += r0.x; v.y += r0.y; v.z += r0.z; v.w += r0.w;
  }
  *(float4*)(rs + i) = v;
  ushort4 h, l;
  h.x = f2bf(v.x); l.x = f2bf(v.x - bf2f(h.x));
  h.y = f2bf(v.y); l.y = f2bf(v.y - bf2f(h.y));
  h.z = f2bf(v.z); l.z = f2bf(v.z - bf2f(h.z));
  h.w = f2bf(v.w); l.w = f2bf(v.w - bf2f(h.w));
  *(ushort4*)(xh + i) = h;
  *(ushort4*)(xl + i) = l;
}

// ============================================================================
// elementwise split: f32 -> (hi, lo) bf16
// ============================================================================
__global__ void split_kernel(const float* __restrict__ src, u16* __restrict__ hi,
                             u16* __restrict__ lo) {
  long i = ((long)blockIdx.x * 256 + threadIdx.x) << 2;
  float4 v = *(const float4*)(src + i);
  ushort4 h, l;
  h.x = f2bf(v.x); l.x = f2bf(v.x - bf2f(h.x));
  h.y = f2bf(v.y); l.y = f2bf(v.y - bf2f(h.y));
  h.z = f2bf(v.z); l.z = f2bf(v.z - bf2f(h.z));
  h.w = f2bf(v.w); l.w = f2bf(v.w - bf2f(h.w));
  *(ushort4*)(hi + i) = h;
  *(ushort4*)(lo + i) = l;
}

__global__ void concat_bias(const float* __restrict__ qb, const float* __restrict__ kb,
                            const float* __restrict__ vb, float* __restrict__ dst) {
  int j = blockIdx.x * 256 + threadIdx.x;  // 0..3071
  float v = (j < 1024) ? qb[j] : ((j < 2048) ? kb[j - 1024] : vb[j - 2048]);
  dst[j] = v;
}

__global__ void deg_kernel(const int* __restrict__ am, int* __restrict__ deg) {
  int i = blockIdx.x * 256 + threadIdx.x;
  int b = i >> 11, q = i & 2047;
  const int* a = am + b * SSQ;
  int any = 0;
  for (int k = 0; k <= q; ++k) any |= (a[k] != 0);
  deg[i] = !any;
}

// ============================================================================
// transpose: VT[b][n][k] = V[b*S+k][n], V has leading dim sld
// ============================================================================
__global__ void transpose_v(const u16* __restrict__ V, int sld, u16* __restrict__ VT) {
  __shared__ u16 t[64][68];
  int b = blockIdx.z;
  int c0 = blockIdx.x << 6;
  int r0 = blockIdx.y << 6;
  int tr = threadIdx.x >> 4, tc = threadIdx.x & 15;
  const u16* src = V + ((long)(b * SSQ + r0)) * sld + c0;
#pragma unroll
  for (int j = 0; j < 4; ++j) {
    int r = (j << 4) + tr;
    ushort4 u = *(const ushort4*)(src + (long)r * sld + (tc << 2));
    t[r][(tc << 2) + 0] = u.x; t[r][(tc << 2) + 1] = u.y;
    t[r][(tc << 2) + 2] = u.z; t[r][(tc << 2) + 3] = u.w;
  }
  __syncthreads();
  u16* dst = VT + ((long)b * HH1 + c0) * SSQ + r0;
#pragma unroll
  for (int j = 0; j < 4; ++j) {
    int c = (j << 4) + tr;
    ushort4 u;
    u.x = t[(tc << 2) + 0][c]; u.y = t[(tc << 2) + 1][c];
    u.z = t[(tc << 2) + 2][c]; u.w = t[(tc << 2) + 3][c];
    *(ushort4*)(dst + (long)c * SSQ + (tc << 2)) = u;
  }
}

// ============================================================================
// column mean of V (degenerate rows); V hi/lo with leading dim ld
// ============================================================================
__global__ void colmean_partial(const u16* __restrict__ Vh, const u16* __restrict__ Vl,
                                int ld, float* __restrict__ part) {
  int n = blockIdx.x * 256 + threadIdx.x;
  int b = blockIdx.y, kc = blockIdx.z;
  long base = ((long)(b * SSQ + kc * 256)) * ld + n;
  float s = 0.f;
  for (int k = 0; k < 256; ++k) {
    long o = base + (long)k * ld;
    s += bf2f(Vh[o]) + bf2f(Vl[o]);
  }
  part[((kc * BB) + b) * HH1 + n] = s;
}
__global__ void colmean_final(const float* __restrict__ part, float* __restrict__ mV) {
  int i = blockIdx.x * 256 + threadIdx.x;
  int b = i >> 10, n = i & 1023;
  float s = 0.f;
  for (int kc = 0; kc < 8; ++kc) s += part[((kc * BB) + b) * HH1 + n];
  mV[i] = s * (1.f / (float)SSQ);
}

// ============================================================================
// row softmax: reads two score partials (ks0+ks1) into LDS row cache.
// ============================================================================
__global__ void softmax_kernel(const float* __restrict__ sc, u16* __restrict__ Ph,
                               u16* __restrict__ Pl, const int* __restrict__ am,
                               const int* __restrict__ deg) {
  int q = blockIdx.x, b = blockIdx.y;
  int tid = threadIdx.x;
  long rowoff = ((long)b * SSQ + q) * SSQ;
  int qt_end = ((q >> 7) + 1) << 7;
  if (deg[b * SSQ + q]) {
    for (int k = tid; k < qt_end; k += 256) { Ph[rowoff + k] = 0; Pl[rowoff + k] = 0; }
    return;
  }
  const int* a = am + b * SSQ;
  const float scale = 0.03125f;  // 1/sqrt(1024)
  constexpr long PSTR = (long)BB * SSQ * SSQ;
  __shared__ float rowbuf[2048];
  __shared__ float sred[8];
  int w = tid >> 6, ln = tid & 63;

  for (int k = tid; k < qt_end; k += 256)
    rowbuf[k] = sc[rowoff + k] + sc[rowoff + k + PSTR];
  __syncthreads();

  float m = -1e30f;
  for (int k = tid; k <= q; k += 256)
    if (a[k]) m = fmaxf(m, rowbuf[k]);
#pragma unroll
  for (int o = 32; o; o >>= 1) m = fmaxf(m, __shfl_xor(m, o));
  if (!ln) sred[w] = m;
  __syncthreads();
  float M = fmaxf(fmaxf(sred[0], sred[1]), fmaxf(sred[2], sred[3]));

  float s = 0.f;
  for (int k = tid; k <= q; k += 256)
    if (a[k]) s += expf((rowbuf[k] - M) * scale);
#pragma unroll
  for (int o = 32; o; o >>= 1) s += __shfl_xor(s, o);
  if (!ln) sred[4 + w] = s;
  __syncthreads();
  float Ssum = sred[4] + sred[5] + sred[6] + sred[7];
  float inv = 1.f / Ssum;

  for (int k = tid; k < qt_end; k += 256) {
    float p = 0.f;
    if (k <= q && a[k]) p = expf((rowbuf[k] - M) * scale) * inv;
    u16 h = f2bf(p);
    Ph[rowoff + k] = h;
    Pl[rowoff + k] = f2bf(p - bf2f(h));
  }
}

// ============================================================================
// post-attention: rs += pv0+pv1 (+meanV for degenerate rows); x = split(rs)
// ============================================================================
__global__ void attn_post(float* __restrict__ rs, const float* __restrict__ pv,
                          u16* __restrict__ xh, u16* __restrict__ xl,
                          const int* __restrict__ deg, const float* __restrict__ mV) {
  long t = (long)blockIdx.x * 256 + threadIdx.x;
  long i = t << 2;
  int row = (int)(i >> 10);
  int col = (int)(i & 1023);
  int b = row >> 11;
  constexpr long PSTR = (long)BB * SSQ * HH1;
  float4 v = *(const float4*)(rs + i);
  float4 a = *(const float4*)(pv + i);
  float4 c = *(const float4*)(pv + i + PSTR);
  v.x += a.x + c.x; v.y += a.y + c.y; v.z += a.z + c.z; v.w += a.w + c.w;
  if (deg[row]) {
    const float* m = mV + (b << 10) + col;
    v.x += m[0]; v.y += m[1]; v.z += m[2]; v.w += m[3];
  }
  *(float4*)(rs + i) = v;
  ushort4 h, l;
  h.x = f2bf(v.x); l.x = f2bf(v.x - bf2f(h.x));
  h.y = f2bf(v.y); l.y = f2bf(v.y - bf2f(h.y));
  h.z = f2bf(v.z); l.z = f2bf(v.z - bf2f(h.z));
  h.w = f2bf(v.w); l.w = f2bf(v.w - bf2f(h.w));
  *(ushort4*)(xh + i) = h;
  *(ushort4*)(xl + i) = l;
}

// ============================================================================
// workspace layout (1 MB = 1<<20), ~221MB, lifetime-aliased (see header)
// ============================================================================
constexpr size_t MB = 1u << 20;
constexpr size_t OFF_RS    = 0;         // f32 [4096][1024]   16MB
constexpr size_t OFF_XH    = 16 * MB;   // bf16 [4096][1024]   8MB
constexpr size_t OFF_XL    = 24 * MB;
constexpr size_t OFF_QKVH  = 32 * MB;   // bf16 [4096][3072]  24MB   | Ph/Pl | mlp2/dproj partial
constexpr size_t OFF_QKVL  = 56 * MB;
constexpr size_t OFF_PH    = 32 * MB;   // bf16 [B][S][S]     16MB (alias)
constexpr size_t OFF_PL    = 48 * MB;
constexpr size_t OFF_RED   = 32 * MB;   // f32 [2][4096][1024] 32MB (alias)
constexpr size_t OFF_VTH   = 80 * MB;   // bf16 [B][H1][S]     8MB
constexpr size_t OFF_VTL   = 88 * MB;
constexpr size_t OFF_SC    = 96 * MB;   // f32 [2][B][S][S]   64MB   | act-split | h
constexpr size_t OFF_ACTH  = 96 * MB;   // bf16 [4096][2048]  16MB (alias)
constexpr size_t OFF_ACTL  = 112 * MB;
constexpr size_t OFF_HH    = 96 * MB;   // bf16 [4096][4096]  32MB (alias)
constexpr size_t OFF_HL    = 128 * MB;
constexpr size_t OFF_PVP   = 128 * MB;  // f32 [2][B][S][H1]  32MB (alias, dead before h-upper)
constexpr size_t OFF_DPWH  = 160 * MB;  // dproj w hi/lo, 4MB each
constexpr size_t OFF_DPWL  = 164 * MB;
constexpr size_t OFF_UPWH  = 168 * MB;
constexpr size_t OFF_UPWL  = 172 * MB;
constexpr size_t OFF_WQKVH = 176 * MB;  // [3072][1024] 6MB each
constexpr size_t OFF_WQKVL = 182 * MB;
constexpr size_t OFF_M1H   = 188 * MB;  // 8MB each
constexpr size_t OFF_M1L   = 196 * MB;
constexpr size_t OFF_M2H   = 204 * MB;
constexpr size_t OFF_M2L   = 212 * MB;
constexpr size_t OFF_QKVB  = 220 * MB;              // f32 [3072]
constexpr size_t OFF_MV    = OFF_QKVB + 16 * 1024;  // f32 [B][H1]
constexpr size_t OFF_PART  = OFF_MV + 16 * 1024;    // f32 [8][B][H1]
constexpr size_t OFF_DEG   = OFF_PART + 128 * 1024; // i32 [B][S]

extern "C" void kernel_launch(void* const* d_in, const int* in_sizes, int n_in,
                              void* d_out, int out_size, void* d_ws, size_t ws_size,
                              hipStream_t stream) {
  (void)in_sizes; (void)n_in; (void)out_size; (void)ws_size;

  const float* z    = (const float*)d_in[0];
  const float* act0 = (const float*)d_in[1];
  const float* act1 = (const float*)d_in[2];
  const int* amask  = (const int*)d_in[3];
  const float* dpw  = (const float*)d_in[4];
  const float* dpb  = (const float*)d_in[5];
  const float* upw  = (const float*)d_in[6];
  const float* upb  = (const float*)d_in[7];
  const float* wqw  = (const float*)d_in[8];
  const float* wqb  = (const float*)d_in[9];
  const float* wkw  = (const float*)d_in[10];
  const float* wkb  = (const float*)d_in[11];
  const float* wvw  = (const float*)d_in[12];
  const float* wvb  = (const float*)d_in[13];
  const float* m1w  = (const float*)d_in[14];
  const float* m1b  = (const float*)d_in[15];
  const float* m2w  = (const float*)d_in[16];
  const float* m2b  = (const float*)d_in[17];

  char* ws = (char*)d_ws;
  float* rs    = (float*)(ws + OFF_RS);
  u16* xh      = (u16*)(ws + OFF_XH);    u16* xl    = (u16*)(ws + OFF_XL);
  u16* qkvh    = (u16*)(ws + OFF_QKVH);  u16* qkvl  = (u16*)(ws + OFF_QKVL);
  u16* Ph      = (u16*)(ws + OFF_PH);    u16* Pl    = (u16*)(ws + OFF_PL);
  float* redp  = (float*)(ws + OFF_RED);
  u16* VTh     = (u16*)(ws + OFF_VTH);   u16* VTl   = (u16*)(ws + OFF_VTL);
  float* scb   = (float*)(ws + OFF_SC);
  u16* acth    = (u16*)(ws + OFF_ACTH);  u16* actl  = (u16*)(ws + OFF_ACTL);
  u16* hh      = (u16*)(ws + OFF_HH);    u16* hl    = (u16*)(ws + OFF_HL);
  float* pvp   = (float*)(ws + OFF_PVP);
  u16* dpwh    = (u16*)(ws + OFF_DPWH);  u16* dpwl  = (u16*)(ws + OFF_DPWL);
  u16* upwh    = (u16*)(ws + OFF_UPWH);  u16* upwl  = (u16*)(ws + OFF_UPWL);
  u16* wqkvh   = (u16*)(ws + OFF_WQKVH); u16* wqkvl = (u16*)(ws + OFF_WQKVL);
  u16* m1h     = (u16*)(ws + OFF_M1H);   u16* m1l   = (u16*)(ws + OFF_M1L);
  u16* m2h     = (u16*)(ws + OFF_M2H);   u16* m2l   = (u16*)(ws + OFF_M2L);
  float* qkvb  = (float*)(ws + OFF_QKVB);
  float* mV    = (float*)(ws + OFF_MV);
  float* part  = (float*)(ws + OFF_PART);
  int* deg     = (int*)(ws + OFF_DEG);

  deg_kernel<<<dim3((BB * SSQ) / 256), 256, 0, stream>>>(amask, deg);
  split_kernel<<<dim3((HH1 * HH0) / 1024), 256, 0, stream>>>(dpw, dpwh, dpwl);
  split_kernel<<<dim3((HH0 * HH1) / 1024), 256, 0, stream>>>(upw, upwh, upwl);

  // rs = dproj(act0) + b ; x = split(rs)   [split-K=2 + reduce]
  split_kernel<<<dim3((MM * HH0) / 1024), 256, 0, stream>>>(act0, acth, actl);
  gemm_split<0, 2><<<dim3(HH1 / 128, MM / 128, 2), 256, 0, stream>>>(
      acth, actl, 0, HH0, dpwh, dpwl, 0, HH0, nullptr, nullptr,
      redp, nullptr, nullptr, 0, HH1, HH0, (long)MM * HH1);
  reduce_split<false><<<dim3(MM * HH1 / 1024), 256, 0, stream>>>(redp, dpb, rs, xh, xl);

  for (int i = 0; i < NLAY; ++i) {
    // per-layer weight splits + bias concat
    split_kernel<<<dim3((HH1 * HH1) / 1024), 256, 0, stream>>>(
        wqw + (size_t)i * HH1 * HH1, wqkvh, wqkvl);
    split_kernel<<<dim3((HH1 * HH1) / 1024), 256, 0, stream>>>(
        wkw + (size_t)i * HH1 * HH1, wqkvh + HH1 * HH1, wqkvl + HH1 * HH1);
    split_kernel<<<dim3((HH1 * HH1) / 1024), 256, 0, stream>>>(
        wvw + (size_t)i * HH1 * HH1, wqkvh + 2 * HH1 * HH1, wqkvl + 2 * HH1 * HH1);
    concat_bias<<<dim3(12), 256, 0, stream>>>(wqb + i * HH1, wkb + i * HH1,
                                              wvb + i * HH1, qkvb);
    split_kernel<<<dim3((HH4 * HH1) / 1024), 256, 0, stream>>>(
        m1w + (size_t)i * HH4 * HH1, m1h, m1l);
    split_kernel<<<dim3((HH1 * HH4) / 1024), 256, 0, stream>>>(
        m2w + (size_t)i * HH1 * HH4, m2h, m2l);

    if (i == 1) {
      split_kernel<<<dim3((MM * HH0) / 1024), 256, 0, stream>>>(act1, acth, actl);
      gemm_split<0, 2><<<dim3(HH1 / 128, MM / 128, 2), 256, 0, stream>>>(
          acth, actl, 0, HH0, dpwh, dpwl, 0, HH0, nullptr, nullptr,
          redp, nullptr, nullptr, 0, HH1, HH0, (long)MM * HH1);
      reduce_split<true><<<dim3(MM * HH1 / 1024), 256, 0, stream>>>(redp, dpb, rs, xh, xl);
    }

    // ---- attention ----
    // fused QKV: [4096][3072] = x @ [wq;wk;wv]^T
    gemm_split<FB_BIAS | FB_SPLIT, 1><<<dim3(3072 / 128, MM / 128, 1), 256, 0, stream>>>(
        xh, xl, 0, HH1, wqkvh, wqkvl, 0, HH1, qkvb, nullptr,
        nullptr, qkvh, qkvl, 0, 3072, HH1, 0);

    transpose_v<<<dim3(HH1 / 64, SSQ / 64, BB), 256, 0, stream>>>(qkvh + 2048, 3072, VTh);
    transpose_v<<<dim3(HH1 / 64, SSQ / 64, BB), 256, 0, stream>>>(qkvl + 2048, 3072, VTl);
    colmean_partial<<<dim3(HH1 / 256, BB, 8), 256, 0, stream>>>(
        qkvh + 2048, qkvl + 2048, 3072, part);
    colmean_final<<<dim3((BB * HH1) / 256), 256, 0, stream>>>(part, mV);

    // scores = Q K^T, causal tile skip, split-K=2 -> partials in scb
    gemm_split<FB_CSKIP, 2><<<dim3(SSQ / 128, SSQ / 128, BB * 2), 256, 0, stream>>>(
        qkvh, qkvl, (long)SSQ * 3072, 3072, qkvh + 1024, qkvl + 1024,
        (long)SSQ * 3072, 3072, nullptr, nullptr,
        scb, nullptr, nullptr, (long)SSQ * SSQ, SSQ, HH1, (long)BB * SSQ * SSQ);

    softmax_kernel<<<dim3(SSQ, BB), 256, 0, stream>>>(scb, Ph, Pl, amask, deg);

    // PV: split-K=2 over causal-truncated K loop -> partials in pvp
    gemm_split<FB_CKLOOP, 2><<<dim3(HH1 / 128, SSQ / 128, BB * 2), 256, 0, stream>>>(
        Ph, Pl, (long)SSQ * SSQ, SSQ, VTh, VTl, (long)HH1 * SSQ, SSQ, nullptr, nullptr,
        pvp, nullptr, nullptr, (long)SSQ * HH1, HH1, SSQ, (long)BB * SSQ * HH1);

    attn_post<<<dim3((MM * HH1 / 4) / 256), 256, 0, stream>>>(rs, pvp, xh, xl, deg, mV);

    // ---- mlp ----
    gemm_split<FB_BIAS | FB_RELU | FB_SPLIT, 1>
        <<<dim3(HH4 / 128, MM / 128, 1), 256, 0, stream>>>(
        xh, xl, 0, HH1, m1h, m1l, 0, HH1, m1b + i * HH4, nullptr,
        nullptr, hh, hl, 0, HH4, HH1, 0);
    gemm_split<0, 2><<<dim3(HH1 / 128, MM / 128, 2), 256, 0, stream>>>(
        hh, hl, 0, HH4, m2h, m2l, 0, HH4, nullptr, nullptr,
        redp, nullptr, nullptr, 0, HH1, HH4, (long)MM * HH1);
    reduce_split<true><<<dim3(MM * HH1 / 1024), 256, 0, stream>>>(
        redp, m2b + i * HH1, rs, xh, xl);
  }

  // out = uproj(x) + b + z
  gemm_split<FB_BIAS | FB_RES | FB_F32, 1>
      <<<dim3(HH0 / 128, MM / 128, 1), 256, 0, stream>>>(
      xh, xl, 0, HH1, upwh, upwl, 0, HH1, upb, z,
      (float*)d_out, nullptr, nullptr, 0, HH0, HH1, 0);
}

// Round 6
// 4121.143 us; speedup vs baseline: 1.3335x; 1.0691x over previous
//
#include <hip/hip_runtime.h>
#include <cstdint>

// ============================================================================
// Ladder transformer forward on MI355X (gfx950).  Round 6.
// Decision log:
//  - R5: swizzle killed bank conflicts (8.4M->0) but dur unchanged ->
//    T2 regime gate (m252): 2-barrier structure hides LDS conflicts behind
//    stage+vmcnt(0)+barrier. Measured ~2175 cyc/K-step vs ~800 compute ->
//    ~1300 cyc exposed global-load latency per K-step.
//  - R6: LDS double-buffer (T3 minimal 2-phase): per K-step issue
//    STAGE(buf^1,t+1) FIRST, compute buf[cur], ONE __syncthreads() (its
//    vmcnt(0) drain now waits on loads issued a full compute-phase ago).
//    1 barrier/K-step (was 2). LDS 32->64KB. Bit-identical arithmetic.
//  - Unchanged: split-bf16 hi/lo 3-term MFMA, split-K, fused QKV, XCD
//    swizzle, chunk swizzle (conflict-free reads).
// ============================================================================

typedef unsigned short u16;
typedef __attribute__((ext_vector_type(8))) __bf16 bf16x8;
typedef __attribute__((ext_vector_type(4))) float f32x4;

#define DI __device__ __forceinline__

constexpr int BB = 2, SSQ = 2048, HH0 = 2048, HH1 = 1024, NLAY = 8, HH4 = 4096;
constexpr int MM = BB * SSQ;  // 4096 token rows

DI float bf2f(u16 h) {
  union { uint32_t u; float f; } x; x.u = ((uint32_t)h) << 16; return x.f;
}
DI u16 f2bf(float f) {
  union { float f; uint32_t u; } x; x.f = f;
  uint32_t u = x.u;
  return (u16)((u + 0x7fffu + ((u >> 16) & 1u)) >> 16);  // RTNE
}

enum {
  FB_BIAS = 1, FB_RES = 2, FB_RELU = 4, FB_F32 = 8, FB_SPLIT = 16,
  FB_CSKIP = 32, FB_CKLOOP = 64
};

// ============================================================================
// Split GEMM: C[M,N] = sum_k A[m,k]*B[n,k], operands hi/lo bf16.
// acc += Ah*Bh + Ah*Bl + Al*Bh. 128x128 tile, BK=32, 4 waves, 4x4 frags.
// Double-buffered LDS, 1 barrier/K-step, stage-issued-early (T3 2-phase).
// Chunk swizzle (XOR (row>>1)&3) via pre-swizzled global source.
// KSP>1: K-range split over z; raw f32 partial written at ks*pstride.
// ============================================================================
template <int F, int KSP>
__global__ __launch_bounds__(256) void gemm_split(
    const u16* __restrict__ Ah, const u16* __restrict__ Al, long sAz, int lda,
    const u16* __restrict__ Bh, const u16* __restrict__ Bl, long sBz, int ldb,
    const float* __restrict__ bias, const float* __restrict__ resF,
    float* Cf, u16* Ch, u16* Cl, long sCz, int ldc, int K, long pstride) {
  // ---- bijective XCD swizzle over the full linear grid ----
  int gx = gridDim.x, gy = gridDim.y, gz = gridDim.z;
  long o = blockIdx.x + (long)gx * (blockIdx.y + (long)gy * blockIdx.z);
  long nwg = (long)gx * gy * gz;
  long cq = nwg >> 3, cr = nwg & 7;
  long xcd = o & 7, cidx = o >> 3;
  long sl = (xcd < cr ? xcd * (cq + 1) : cr * (cq + 1) + (xcd - cr) * cq) + cidx;
  int bx = (int)(sl % gx);
  long tt = sl / gx;
  int by = (int)(tt % gy);
  int bzf = (int)(tt / gy);
  int NB = gz / KSP;
  int bz = bzf % NB;
  int ks = bzf / NB;

  if ((F & FB_CSKIP) && bx > by) return;  // strictly-upper tile: never read

  // [dbuf][stream: Ah,Al,Bh,Bl][128*32]
  __shared__ __align__(16) u16 Sbuf[2][4][128 * 32];

  int tid = threadIdx.x;
  int lane = tid & 63;
  int wave = tid >> 6;
  int wr = (wave >> 1) << 6;
  int wc = (wave & 1) << 6;
  int lrow = lane & 15;
  int kg = lane >> 4;
  // swizzled chunk offset for reads (row bits [1:2] == lrow bits [1:2])
  int kc8 = (kg ^ ((lrow >> 1) & 3)) << 3;

  const u16* Abh = Ah + (long)bz * sAz + ((long)(by << 7)) * lda;
  const u16* Abl = Al + (long)bz * sAz + ((long)(by << 7)) * lda;
  const u16* Bbh = Bh + (long)bz * sBz + ((long)(bx << 7)) * ldb;
  const u16* Bbl = Bl + (long)bz * sBz + ((long)(bx << 7)) * ldb;

  int nKtot = (F & FB_CKLOOP) ? ((by + 1) << 2) : (K >> 5);
  int kbeg = (KSP > 1) ? (ks * nKtot) / KSP : 0;
  int kend = (KSP > 1) ? ((ks + 1) * nKtot) / KSP : nKtot;

  f32x4 acc[4][4] = {};

  auto STAGE = [&](int buf, int kt) {
    int k0 = kt << 5;
#pragma unroll
    for (int it = 0; it < 2; ++it) {
      int sidx = (it << 8) + tid;     // 0..511
      int r = sidx >> 2;              // tile row 0..127
      int jsw = (sidx & 3) ^ ((r >> 1) & 3);  // pre-swizzled source chunk
      long goff = (long)r * lda + (k0 + (jsw << 3));
      long gofB = (long)r * ldb + (k0 + (jsw << 3));
      int loff = sidx << 3;
      __builtin_amdgcn_global_load_lds(
          (__attribute__((address_space(1))) void*)(Abh + goff),
          (__attribute__((address_space(3))) void*)(&Sbuf[buf][0][loff]), 16, 0, 0);
      __builtin_amdgcn_global_load_lds(
          (__attribute__((address_space(1))) void*)(Abl + goff),
          (__attribute__((address_space(3))) void*)(&Sbuf[buf][1][loff]), 16, 0, 0);
      __builtin_amdgcn_global_load_lds(
          (__attribute__((address_space(1))) void*)(Bbh + gofB),
          (__attribute__((address_space(3))) void*)(&Sbuf[buf][2][loff]), 16, 0, 0);
      __builtin_amdgcn_global_load_lds(
          (__attribute__((address_space(1))) void*)(Bbl + gofB),
          (__attribute__((address_space(3))) void*)(&Sbuf[buf][3][loff]), 16, 0, 0);
    }
  };

  auto COMPUTE = [&](int buf) {
    bf16x8 afh[4], bfh[4], bfl[4];
#pragma unroll
    for (int mi = 0; mi < 4; ++mi)
      afh[mi] = *(const bf16x8*)&Sbuf[buf][0][((wr + (mi << 4) + lrow) << 5) + kc8];
#pragma unroll
    for (int ni = 0; ni < 4; ++ni) {
      bfh[ni] = *(const bf16x8*)&Sbuf[buf][2][((wc + (ni << 4) + lrow) << 5) + kc8];
      bfl[ni] = *(const bf16x8*)&Sbuf[buf][3][((wc + (ni << 4) + lrow) << 5) + kc8];
    }
#pragma unroll
    for (int mi = 0; mi < 4; ++mi)
#pragma unroll
      for (int ni = 0; ni < 4; ++ni) {
        acc[mi][ni] = __builtin_amdgcn_mfma_f32_16x16x32_bf16(
            afh[mi], bfh[ni], acc[mi][ni], 0, 0, 0);
        acc[mi][ni] = __builtin_amdgcn_mfma_f32_16x16x32_bf16(
            afh[mi], bfl[ni], acc[mi][ni], 0, 0, 0);
      }
    bf16x8 afl[4];
#pragma unroll
    for (int mi = 0; mi < 4; ++mi)
      afl[mi] = *(const bf16x8*)&Sbuf[buf][1][((wr + (mi << 4) + lrow) << 5) + kc8];
#pragma unroll
    for (int mi = 0; mi < 4; ++mi)
#pragma unroll
      for (int ni = 0; ni < 4; ++ni)
        acc[mi][ni] = __builtin_amdgcn_mfma_f32_16x16x32_bf16(
            afl[mi], bfh[ni], acc[mi][ni], 0, 0, 0);
  };

  // prologue: fill buf0, then one barrier (drains vmcnt)
  int cur = 0;
  STAGE(0, kbeg);
  __syncthreads();
  // steady state: issue next stage FIRST, compute current, single barrier.
  for (int kt = kbeg; kt < kend - 1; ++kt) {
    STAGE(cur ^ 1, kt + 1);
    COMPUTE(cur);
    __syncthreads();  // vmcnt(0): waits on loads issued a compute-phase ago
    cur ^= 1;
  }
  COMPUTE(cur);  // last tile, no prefetch

  int m0 = (by << 7) + wr + (kg << 2);
  int n0 = (bx << 7) + wc;
#pragma unroll
  for (int mi = 0; mi < 4; ++mi) {
#pragma unroll
    for (int ni = 0; ni < 4; ++ni) {
      int col = n0 + (ni << 4) + lrow;
      float bv = 0.f;
      if ((KSP == 1) && (F & FB_BIAS)) bv = bias[col];
      int rb = m0 + (mi << 4);
#pragma unroll
      for (int r = 0; r < 4; ++r) {
        float v = acc[mi][ni][r];
        long ci = (long)bz * sCz + (long)(rb + r) * ldc + col;
        if constexpr (KSP > 1) {
          Cf[(long)ks * pstride + ci] = v;  // raw partial
        } else {
          v += bv;
          if (F & FB_RELU) v = fmaxf(v, 0.f);
          if (F & FB_RES) v += resF[ci];
          if (F & FB_F32) Cf[ci] = v;
          if (F & FB_SPLIT) {
            u16 h = f2bf(v);
            Ch[ci] = h;
            Cl[ci] = f2bf(v - bf2f(h));
          }
        }
      }
    }
  }
}

// ============================================================================
// reduce for split-K N=1024 GEMMs: v = p0+p1+bias (+rs); rs=v; x=split(v)
// ============================================================================
template <bool RES>
__global__ void reduce_split(const float* __restrict__ p,
                             const float* __restrict__ bias,
                             float* __restrict__ rs, u16* __restrict__ xh,
                             u16* __restrict__ xl) {
  long i = ((long)blockIdx.x * 256 + threadIdx.x) << 2;
  int col = (int)(i & 1023);
  float4 a = *(const float4*)(p + i);
  float4 b = *(const float4*)(p + i + (long)MM * HH1);
  float4 v;
  v.x = a.x + b.x + bias[col];
  v.y = a.y + b.y + bias[col + 1];
  v.z = a.z + b.z + bias[col + 2];
  v.w = a.w + b.w + bias[col + 3];
  if (RES) {
    float4 r0 = *(const float4*)(rs + i);
    v.x += r0.x; v.y += r0.y; v.z += r0.z; v.w += r0.w;
  }
  *(float4*)(rs + i) = v;
  ushort4 h, l;
  h.x = f2bf(v.x); l.x = f2bf(v.x - bf2f(h.x));
  h.y = f2bf(v.y); l.y = f2bf(v.y - bf2f(h.y));
  h.z = f2bf(v.z); l.z = f2bf(v.z - bf2f(h.z));
  h.w = f2bf(v.w); l.w = f2bf(v.w - bf2f(h.w));
  *(ushort4*)(xh + i) = h;
  *(ushort4*)(xl + i) = l;
}

// ============================================================================
// elementwise split: f32 -> (hi, lo) bf16
// ============================================================================
__global__ void split_kernel(const float* __restrict__ src, u16* __restrict__ hi,
                             u16* __restrict__ lo) {
  long i = ((long)blockIdx.x * 256 + threadIdx.x) << 2;
  float4 v = *(const float4*)(src + i);
  ushort4 h, l;
  h.x = f2bf(v.x); l.x = f2bf(v.x - bf2f(h.x));
  h.y = f2bf(v.y); l.y = f2bf(v.y - bf2f(h.y));
  h.z = f2bf(v.z); l.z = f2bf(v.z - bf2f(h.z));
  h.w = f2bf(v.w); l.w = f2bf(v.w - bf2f(h.w));
  *(ushort4*)(hi + i) = h;
  *(ushort4*)(lo + i) = l;
}

__global__ void concat_bias(const float* __restrict__ qb, const float* __restrict__ kb,
                            const float* __restrict__ vb, float* __restrict__ dst) {
  int j = blockIdx.x * 256 + threadIdx.x;  // 0..3071
  float v = (j < 1024) ? qb[j] : ((j < 2048) ? kb[j - 1024] : vb[j - 2048]);
  dst[j] = v;
}

__global__ void deg_kernel(const int* __restrict__ am, int* __restrict__ deg) {
  int i = blockIdx.x * 256 + threadIdx.x;
  int b = i >> 11, q = i & 2047;
  const int* a = am + b * SSQ;
  int any = 0;
  for (int k = 0; k <= q; ++k) any |= (a[k] != 0);
  deg[i] = !any;
}

// ============================================================================
// transpose: VT[b][n][k] = V[b*S+k][n], V has leading dim sld
// ============================================================================
__global__ void transpose_v(const u16* __restrict__ V, int sld, u16* __restrict__ VT) {
  __shared__ u16 t[64][68];
  int b = blockIdx.z;
  int c0 = blockIdx.x << 6;
  int r0 = blockIdx.y << 6;
  int tr = threadIdx.x >> 4, tc = threadIdx.x & 15;
  const u16* src = V + ((long)(b * SSQ + r0)) * sld + c0;
#pragma unroll
  for (int j = 0; j < 4; ++j) {
    int r = (j << 4) + tr;
    ushort4 u = *(const ushort4*)(src + (long)r * sld + (tc << 2));
    t[r][(tc << 2) + 0] = u.x; t[r][(tc << 2) + 1] = u.y;
    t[r][(tc << 2) + 2] = u.z; t[r][(tc << 2) + 3] = u.w;
  }
  __syncthreads();
  u16* dst = VT + ((long)b * HH1 + c0) * SSQ + r0;
#pragma unroll
  for (int j = 0; j < 4; ++j) {
    int c = (j << 4) + tr;
    ushort4 u;
    u.x = t[(tc << 2) + 0][c]; u.y = t[(tc << 2) + 1][c];
    u.z = t[(tc << 2) + 2][c]; u.w = t[(tc << 2) + 3][c];
    *(ushort4*)(dst + (long)c * SSQ + (tc << 2)) = u;
  }
}

// ============================================================================
// column mean of V (degenerate rows); V hi/lo with leading dim ld
// ============================================================================
__global__ void colmean_partial(const u16* __restrict__ Vh, const u16* __restrict__ Vl,
                                int ld, float* __restrict__ part) {
  int n = blockIdx.x * 256 + threadIdx.x;
  int b = blockIdx.y, kc = blockIdx.z;
  long base = ((long)(b * SSQ + kc * 256)) * ld + n;
  float s = 0.f;
  for (int k = 0; k < 256; ++k) {
    long o = base + (long)k * ld;
    s += bf2f(Vh[o]) + bf2f(Vl[o]);
  }
  part[((kc * BB) + b) * HH1 + n] = s;
}
__global__ void colmean_final(const float* __restrict__ part, float* __restrict__ mV) {
  int i = blockIdx.x * 256 + threadIdx.x;
  int b = i >> 10, n = i & 1023;
  float s = 0.f;
  for (int kc = 0; kc < 8; ++kc) s += part[((kc * BB) + b) * HH1 + n];
  mV[i] = s * (1.f / (float)SSQ);
}

// ============================================================================
// row softmax: reads two score partials (ks0+ks1) into LDS row cache.
// ============================================================================
__global__ void softmax_kernel(const float* __restrict__ sc, u16* __restrict__ Ph,
                               u16* __restrict__ Pl, const int* __restrict__ am,
                               const int* __restrict__ deg) {
  int q = blockIdx.x, b = blockIdx.y;
  int tid = threadIdx.x;
  long rowoff = ((long)b * SSQ + q) * SSQ;
  int qt_end = ((q >> 7) + 1) << 7;
  if (deg[b * SSQ + q]) {
    for (int k = tid; k < qt_end; k += 256) { Ph[rowoff + k] = 0; Pl[rowoff + k] = 0; }
    return;
  }
  const int* a = am + b * SSQ;
  const float scale = 0.03125f;  // 1/sqrt(1024)
  constexpr long PSTR = (long)BB * SSQ * SSQ;
  __shared__ float rowbuf[2048];
  __shared__ float sred[8];
  int w = tid >> 6, ln = tid & 63;

  for (int k = tid; k < qt_end; k += 256)
    rowbuf[k] = sc[rowoff + k] + sc[rowoff + k + PSTR];
  __syncthreads();

  float m = -1e30f;
  for (int k = tid; k <= q; k += 256)
    if (a[k]) m = fmaxf(m, rowbuf[k]);
#pragma unroll
  for (int o = 32; o; o >>= 1) m = fmaxf(m, __shfl_xor(m, o));
  if (!ln) sred[w] = m;
  __syncthreads();
  float M = fmaxf(fmaxf(sred[0], sred[1]), fmaxf(sred[2], sred[3]));

  float s = 0.f;
  for (int k = tid; k <= q; k += 256)
    if (a[k]) s += expf((rowbuf[k] - M) * scale);
#pragma unroll
  for (int o = 32; o; o >>= 1) s += __shfl_xor(s, o);
  if (!ln) sred[4 + w] = s;
  __syncthreads();
  float Ssum = sred[4] + sred[5] + sred[6] + sred[7];
  float inv = 1.f / Ssum;

  for (int k = tid; k < qt_end; k += 256) {
    float p = 0.f;
    if (k <= q && a[k]) p = expf((rowbuf[k] - M) * scale) * inv;
    u16 h = f2bf(p);
    Ph[rowoff + k] = h;
    Pl[rowoff + k] = f2bf(p - bf2f(h));
  }
}

// ============================================================================
// post-attention: rs += pv0+pv1 (+meanV for degenerate rows); x = split(rs)
// ============================================================================
__global__ void attn_post(float* __restrict__ rs, const float* __restrict__ pv,
                          u16* __restrict__ xh, u16* __restrict__ xl,
                          const int* __restrict__ deg, const float* __restrict__ mV) {
  long t = (long)blockIdx.x * 256 + threadIdx.x;
  long i = t << 2;
  int row = (int)(i >> 10);
  int col = (int)(i & 1023);
  int b = row >> 11;
  constexpr long PSTR = (long)BB * SSQ * HH1;
  float4 v = *(const float4*)(rs + i);
  float4 a = *(const float4*)(pv + i);
  float4 c = *(const float4*)(pv + i + PSTR);
  v.x += a.x + c.x; v.y += a.y + c.y; v.z += a.z + c.z; v.w += a.w + c.w;
  if (deg[row]) {
    const float* m = mV + (b << 10) + col;
    v.x += m[0]; v.y += m[1]; v.z += m[2]; v.w += m[3];
  }
  *(float4*)(rs + i) = v;
  ushort4 h, l;
  h.x = f2bf(v.x); l.x = f2bf(v.x - bf2f(h.x));
  h.y = f2bf(v.y); l.y = f2bf(v.y - bf2f(h.y));
  h.z = f2bf(v.z); l.z = f2bf(v.z - bf2f(h.z));
  h.w = f2bf(v.w); l.w = f2bf(v.w - bf2f(h.w));
  *(ushort4*)(xh + i) = h;
  *(ushort4*)(xl + i) = l;
}

// ============================================================================
// workspace layout (1 MB = 1<<20), ~221MB, lifetime-aliased (see header)
// ============================================================================
constexpr size_t MB = 1u << 20;
constexpr size_t OFF_RS    = 0;         // f32 [4096][1024]   16MB
constexpr size_t OFF_XH    = 16 * MB;   // bf16 [4096][1024]   8MB
constexpr size_t OFF_XL    = 24 * MB;
constexpr size_t OFF_QKVH  = 32 * MB;   // bf16 [4096][3072]  24MB   | Ph/Pl | mlp2/dproj partial
constexpr size_t OFF_QKVL  = 56 * MB;
constexpr size_t OFF_PH    = 32 * MB;   // bf16 [B][S][S]     16MB (alias)
constexpr size_t OFF_PL    = 48 * MB;
constexpr size_t OFF_RED   = 32 * MB;   // f32 [2][4096][1024] 32MB (alias)
constexpr size_t OFF_VTH   = 80 * MB;   // bf16 [B][H1][S]     8MB
constexpr size_t OFF_VTL   = 88 * MB;
constexpr size_t OFF_SC    = 96 * MB;   // f32 [2][B][S][S]   64MB   | act-split | h
constexpr size_t OFF_ACTH  = 96 * MB;   // bf16 [4096][2048]  16MB (alias)
constexpr size_t OFF_ACTL  = 112 * MB;
constexpr size_t OFF_HH    = 96 * MB;   // bf16 [4096][4096]  32MB (alias)
constexpr size_t OFF_HL    = 128 * MB;
constexpr size_t OFF_PVP   = 128 * MB;  // f32 [2][B][S][H1]  32MB (alias, dead before h-upper)
constexpr size_t OFF_DPWH  = 160 * MB;  // dproj w hi/lo, 4MB each
constexpr size_t OFF_DPWL  = 164 * MB;
constexpr size_t OFF_UPWH  = 168 * MB;
constexpr size_t OFF_UPWL  = 172 * MB;
constexpr size_t OFF_WQKVH = 176 * MB;  // [3072][1024] 6MB each
constexpr size_t OFF_WQKVL = 182 * MB;
constexpr size_t OFF_M1H   = 188 * MB;  // 8MB each
constexpr size_t OFF_M1L   = 196 * MB;
constexpr size_t OFF_M2H   = 204 * MB;
constexpr size_t OFF_M2L   = 212 * MB;
constexpr size_t OFF_QKVB  = 220 * MB;              // f32 [3072]
constexpr size_t OFF_MV    = OFF_QKVB + 16 * 1024;  // f32 [B][H1]
constexpr size_t OFF_PART  = OFF_MV + 16 * 1024;    // f32 [8][B][H1]
constexpr size_t OFF_DEG   = OFF_PART + 128 * 1024; // i32 [B][S]

extern "C" void kernel_launch(void* const* d_in, const int* in_sizes, int n_in,
                              void* d_out, int out_size, void* d_ws, size_t ws_size,
                              hipStream_t stream) {
  (void)in_sizes; (void)n_in; (void)out_size; (void)ws_size;

  const float* z    = (const float*)d_in[0];
  const float* act0 = (const float*)d_in[1];
  const float* act1 = (const float*)d_in[2];
  const int* amask  = (const int*)d_in[3];
  const float* dpw  = (const float*)d_in[4];
  const float* dpb  = (const float*)d_in[5];
  const float* upw  = (const float*)d_in[6];
  const float* upb  = (const float*)d_in[7];
  const float* wqw  = (const float*)d_in[8];
  const float* wqb  = (const float*)d_in[9];
  const float* wkw  = (const float*)d_in[10];
  const float* wkb  = (const float*)d_in[11];
  const float* wvw  = (const float*)d_in[12];
  const float* wvb  = (const float*)d_in[13];
  const float* m1w  = (const float*)d_in[14];
  const float* m1b  = (const float*)d_in[15];
  const float* m2w  = (const float*)d_in[16];
  const float* m2b  = (const float*)d_in[17];

  char* ws = (char*)d_ws;
  float* rs    = (float*)(ws + OFF_RS);
  u16* xh      = (u16*)(ws + OFF_XH);    u16* xl    = (u16*)(ws + OFF_XL);
  u16* qkvh    = (u16*)(ws + OFF_QKVH);  u16* qkvl  = (u16*)(ws + OFF_QKVL);
  u16* Ph      = (u16*)(ws + OFF_PH);    u16* Pl    = (u16*)(ws + OFF_PL);
  float* redp  = (float*)(ws + OFF_RED);
  u16* VTh     = (u16*)(ws + OFF_VTH);   u16* VTl   = (u16*)(ws + OFF_VTL);
  float* scb   = (float*)(ws + OFF_SC);
  u16* acth    = (u16*)(ws + OFF_ACTH);  u16* actl  = (u16*)(ws + OFF_ACTL);
  u16* hh      = (u16*)(ws + OFF_HH);    u16* hl    = (u16*)(ws + OFF_HL);
  float* pvp   = (float*)(ws + OFF_PVP);
  u16* dpwh    = (u16*)(ws + OFF_DPWH);  u16* dpwl  = (u16*)(ws + OFF_DPWL);
  u16* upwh    = (u16*)(ws + OFF_UPWH);  u16* upwl  = (u16*)(ws + OFF_UPWL);
  u16* wqkvh   = (u16*)(ws + OFF_WQKVH); u16* wqkvl = (u16*)(ws + OFF_WQKVL);
  u16* m1h     = (u16*)(ws + OFF_M1H);   u16* m1l   = (u16*)(ws + OFF_M1L);
  u16* m2h     = (u16*)(ws + OFF_M2H);   u16* m2l   = (u16*)(ws + OFF_M2L);
  float* qkvb  = (float*)(ws + OFF_QKVB);
  float* mV    = (float*)(ws + OFF_MV);
  float* part  = (float*)(ws + OFF_PART);
  int* deg     = (int*)(ws + OFF_DEG);

  deg_kernel<<<dim3((BB * SSQ) / 256), 256, 0, stream>>>(amask, deg);
  split_kernel<<<dim3((HH1 * HH0) / 1024), 256, 0, stream>>>(dpw, dpwh, dpwl);
  split_kernel<<<dim3((HH0 * HH1) / 1024), 256, 0, stream>>>(upw, upwh, upwl);

  // rs = dproj(act0) + b ; x = split(rs)   [split-K=2 + reduce]
  split_kernel<<<dim3((MM * HH0) / 1024), 256, 0, stream>>>(act0, acth, actl);
  gemm_split<0, 2><<<dim3(HH1 / 128, MM / 128, 2), 256, 0, stream>>>(
      acth, actl, 0, HH0, dpwh, dpwl, 0, HH0, nullptr, nullptr,
      redp, nullptr, nullptr, 0, HH1, HH0, (long)MM * HH1);
  reduce_split<false><<<dim3(MM * HH1 / 1024), 256, 0, stream>>>(redp, dpb, rs, xh, xl);

  for (int i = 0; i < NLAY; ++i) {
    // per-layer weight splits + bias concat
    split_kernel<<<dim3((HH1 * HH1) / 1024), 256, 0, stream>>>(
        wqw + (size_t)i * HH1 * HH1, wqkvh, wqkvl);
    split_kernel<<<dim3((HH1 * HH1) / 1024), 256, 0, stream>>>(
        wkw + (size_t)i * HH1 * HH1, wqkvh + HH1 * HH1, wqkvl + HH1 * HH1);
    split_kernel<<<dim3((HH1 * HH1) / 1024), 256, 0, stream>>>(
        wvw + (size_t)i * HH1 * HH1, wqkvh + 2 * HH1 * HH1, wqkvl + 2 * HH1 * HH1);
    concat_bias<<<dim3(12), 256, 0, stream>>>(wqb + i * HH1, wkb + i * HH1,
                                              wvb + i * HH1, qkvb);
    split_kernel<<<dim3((HH4 * HH1) / 1024), 256, 0, stream>>>(
        m1w + (size_t)i * HH4 * HH1, m1h, m1l);
    split_kernel<<<dim3((HH1 * HH4) / 1024), 256, 0, stream>>>(
        m2w + (size_t)i * HH1 * HH4, m2h, m2l);

    if (i == 1) {
      split_kernel<<<dim3((MM * HH0) / 1024), 256, 0, stream>>>(act1, acth, actl);
      gemm_split<0, 2><<<dim3(HH1 / 128, MM / 128, 2), 256, 0, stream>>>(
          acth, actl, 0, HH0, dpwh, dpwl, 0, HH0, nullptr, nullptr,
          redp, nullptr, nullptr, 0, HH1, HH0, (long)MM * HH1);
      reduce_split<true><<<dim3(MM * HH1 / 1024), 256, 0, stream>>>(redp, dpb, rs, xh, xl);
    }

    // ---- attention ----
    // fused QKV: [4096][3072] = x @ [wq;wk;wv]^T
    gemm_split<FB_BIAS | FB_SPLIT, 1><<<dim3(3072 / 128, MM / 128, 1), 256, 0, stream>>>(
        xh, xl, 0, HH1, wqkvh, wqkvl, 0, HH1, qkvb, nullptr,
        nullptr, qkvh, qkvl, 0, 3072, HH1, 0);

    transpose_v<<<dim3(HH1 / 64, SSQ / 64, BB), 256, 0, stream>>>(qkvh + 2048, 3072, VTh);
    transpose_v<<<dim3(HH1 / 64, SSQ / 64, BB), 256, 0, stream>>>(qkvl + 2048, 3072, VTl);
    colmean_partial<<<dim3(HH1 / 256, BB, 8), 256, 0, stream>>>(
        qkvh + 2048, qkvl + 2048, 3072, part);
    colmean_final<<<dim3((BB * HH1) / 256), 256, 0, stream>>>(part, mV);

    // scores = Q K^T, causal tile skip, split-K=2 -> partials in scb
    gemm_split<FB_CSKIP, 2><<<dim3(SSQ / 128, SSQ / 128, BB * 2), 256, 0, stream>>>(
        qkvh, qkvl, (long)SSQ * 3072, 3072, qkvh + 1024, qkvl + 1024,
        (long)SSQ * 3072, 3072, nullptr, nullptr,
        scb, nullptr, nullptr, (long)SSQ * SSQ, SSQ, HH1, (long)BB * SSQ * SSQ);

    softmax_kernel<<<dim3(SSQ, BB), 256, 0, stream>>>(scb, Ph, Pl, amask, deg);

    // PV: split-K=2 over causal-truncated K loop -> partials in pvp
    gemm_split<FB_CKLOOP, 2><<<dim3(HH1 / 128, SSQ / 128, BB * 2), 256, 0, stream>>>(
        Ph, Pl, (long)SSQ * SSQ, SSQ, VTh, VTl, (long)HH1 * SSQ, SSQ, nullptr, nullptr,
        pvp, nullptr, nullptr, (long)SSQ * HH1, HH1, SSQ, (long)BB * SSQ * HH1);

    attn_post<<<dim3((MM * HH1 / 4) / 256), 256, 0, stream>>>(rs, pvp, xh, xl, deg, mV);

    // ---- mlp ----
    gemm_split<FB_BIAS | FB_RELU | FB_SPLIT, 1>
        <<<dim3(HH4 / 128, MM / 128, 1), 256, 0, stream>>>(
        xh, xl, 0, HH1, m1h, m1l, 0, HH1, m1b + i * HH4, nullptr,
        nullptr, hh, hl, 0, HH4, HH1, 0);
    gemm_split<0, 2><<<dim3(HH1 / 128, MM / 128, 2), 256, 0, stream>>>(
        hh, hl, 0, HH4, m2h, m2l, 0, HH4, nullptr, nullptr,
        redp, nullptr, nullptr, 0, HH1, HH4, (long)MM * HH1);
    reduce_split<true><<<dim3(MM * HH1 / 1024), 256, 0, stream>>>(
        redp, m2b + i * HH1, rs, xh, xl);
  }

  // out = uproj(x) + b + z
  gemm_split<FB_BIAS | FB_RES | FB_F32, 1>
      <<<dim3(HH0 / 128, MM / 128, 1), 256, 0, stream>>>(
      xh, xl, 0, HH1, upwh, upwl, 0, HH1, upb, z,
      (float*)d_out, nullptr, nullptr, 0, HH0, HH1, 0);
}

// Round 7
// 4053.218 us; speedup vs baseline: 1.3558x; 1.0168x over previous
//
#include <hip/hip_runtime.h>
#include <cstdint>

// ============================================================================
// Ladder transformer forward on MI355X (gfx950).  Round 7.
// Decision log:
//  - R6 (+7%): 1-barrier dbuf helped; but __syncthreads still drains
//    vmcnt(0) of the loads issued THE SAME iteration -> latency only
//    partially hidden. T4 (m218): the gain IS the counted vmcnt.
//  - R7: raw s_barrier + s_waitcnt vmcnt(8): cur buffer's loads were
//    issued a FULL iteration ago; next buffer's 8 loads stay in flight
//    across the barrier and compute. No vmcnt(0) in the main loop.
//    Barriers bracketed by asm memory fences (no LDS op crosses).
//  - Fused hi/lo V transpose into one kernel.
//  - Unchanged: split-bf16 3-term MFMA, split-K, fused QKV, XCD swizzle,
//    chunk swizzle. Bit-identical arithmetic (absmax stays 0.125).
// ============================================================================

typedef unsigned short u16;
typedef __attribute__((ext_vector_type(8))) __bf16 bf16x8;
typedef __attribute__((ext_vector_type(4))) float f32x4;

#define DI __device__ __forceinline__

constexpr int BB = 2, SSQ = 2048, HH0 = 2048, HH1 = 1024, NLAY = 8, HH4 = 4096;
constexpr int MM = BB * SSQ;  // 4096 token rows

DI float bf2f(u16 h) {
  union { uint32_t u; float f; } x; x.u = ((uint32_t)h) << 16; return x.f;
}
DI u16 f2bf(float f) {
  union { float f; uint32_t u; } x; x.f = f;
  uint32_t u = x.u;
  return (u16)((u + 0x7fffu + ((u >> 16) & 1u)) >> 16);  // RTNE
}

enum {
  FB_BIAS = 1, FB_RES = 2, FB_RELU = 4, FB_F32 = 8, FB_SPLIT = 16,
  FB_CSKIP = 32, FB_CKLOOP = 64
};

// ============================================================================
// Split GEMM: C[M,N] = sum_k A[m,k]*B[n,k], operands hi/lo bf16.
// acc += Ah*Bh + Ah*Bl + Al*Bh. 128x128 tile, BK=32, 4 waves, 4x4 frags.
// Double-buffered LDS + counted vmcnt(8) + raw barriers (T4): next tile's
// 8 global_load_lds stay in flight across barrier & compute.
// Chunk swizzle (XOR (row>>1)&3) via pre-swizzled global source.
// KSP>1: K-range split over z; raw f32 partial written at ks*pstride.
// ============================================================================
template <int F, int KSP>
__global__ __launch_bounds__(256) void gemm_split(
    const u16* __restrict__ Ah, const u16* __restrict__ Al, long sAz, int lda,
    const u16* __restrict__ Bh, const u16* __restrict__ Bl, long sBz, int ldb,
    const float* __restrict__ bias, const float* __restrict__ resF,
    float* Cf, u16* Ch, u16* Cl, long sCz, int ldc, int K, long pstride) {
  // ---- bijective XCD swizzle over the full linear grid ----
  int gx = gridDim.x, gy = gridDim.y, gz = gridDim.z;
  long o = blockIdx.x + (long)gx * (blockIdx.y + (long)gy * blockIdx.z);
  long nwg = (long)gx * gy * gz;
  long cq = nwg >> 3, cr = nwg & 7;
  long xcd = o & 7, cidx = o >> 3;
  long sl = (xcd < cr ? xcd * (cq + 1) : cr * (cq + 1) + (xcd - cr) * cq) + cidx;
  int bx = (int)(sl % gx);
  long tt = sl / gx;
  int by = (int)(tt % gy);
  int bzf = (int)(tt / gy);
  int NB = gz / KSP;
  int bz = bzf % NB;
  int ks = bzf / NB;

  if ((F & FB_CSKIP) && bx > by) return;  // strictly-upper tile: never read

  // [dbuf][stream: Ah,Al,Bh,Bl][128*32]
  __shared__ __align__(16) u16 Sbuf[2][4][128 * 32];

  int tid = threadIdx.x;
  int lane = tid & 63;
  int wave = tid >> 6;
  int wr = (wave >> 1) << 6;
  int wc = (wave & 1) << 6;
  int lrow = lane & 15;
  int kg = lane >> 4;
  // swizzled chunk offset for reads (row bits [1:2] == lrow bits [1:2])
  int kc8 = (kg ^ ((lrow >> 1) & 3)) << 3;

  const u16* Abh = Ah + (long)bz * sAz + ((long)(by << 7)) * lda;
  const u16* Abl = Al + (long)bz * sAz + ((long)(by << 7)) * lda;
  const u16* Bbh = Bh + (long)bz * sBz + ((long)(bx << 7)) * ldb;
  const u16* Bbl = Bl + (long)bz * sBz + ((long)(bx << 7)) * ldb;

  int nKtot = (F & FB_CKLOOP) ? ((by + 1) << 2) : (K >> 5);
  int kbeg = (KSP > 1) ? (ks * nKtot) / KSP : 0;
  int kend = (KSP > 1) ? ((ks + 1) * nKtot) / KSP : nKtot;

  f32x4 acc[4][4] = {};

  auto STAGE = [&](int buf, int kt) {
    int k0 = kt << 5;
#pragma unroll
    for (int it = 0; it < 2; ++it) {
      int sidx = (it << 8) + tid;     // 0..511
      int r = sidx >> 2;              // tile row 0..127
      int jsw = (sidx & 3) ^ ((r >> 1) & 3);  // pre-swizzled source chunk
      long goff = (long)r * lda + (k0 + (jsw << 3));
      long gofB = (long)r * ldb + (k0 + (jsw << 3));
      int loff = sidx << 3;
      __builtin_amdgcn_global_load_lds(
          (__attribute__((address_space(1))) void*)(Abh + goff),
          (__attribute__((address_space(3))) void*)(&Sbuf[buf][0][loff]), 16, 0, 0);
      __builtin_amdgcn_global_load_lds(
          (__attribute__((address_space(1))) void*)(Abl + goff),
          (__attribute__((address_space(3))) void*)(&Sbuf[buf][1][loff]), 16, 0, 0);
      __builtin_amdgcn_global_load_lds(
          (__attribute__((address_space(1))) void*)(Bbh + gofB),
          (__attribute__((address_space(3))) void*)(&Sbuf[buf][2][loff]), 16, 0, 0);
      __builtin_amdgcn_global_load_lds(
          (__attribute__((address_space(1))) void*)(Bbl + gofB),
          (__attribute__((address_space(3))) void*)(&Sbuf[buf][3][loff]), 16, 0, 0);
    }
  };

  auto COMPUTE = [&](int buf) {
    bf16x8 afh[4], bfh[4], bfl[4];
#pragma unroll
    for (int mi = 0; mi < 4; ++mi)
      afh[mi] = *(const bf16x8*)&Sbuf[buf][0][((wr + (mi << 4) + lrow) << 5) + kc8];
#pragma unroll
    for (int ni = 0; ni < 4; ++ni) {
      bfh[ni] = *(const bf16x8*)&Sbuf[buf][2][((wc + (ni << 4) + lrow) << 5) + kc8];
      bfl[ni] = *(const bf16x8*)&Sbuf[buf][3][((wc + (ni << 4) + lrow) << 5) + kc8];
    }
#pragma unroll
    for (int mi = 0; mi < 4; ++mi)
#pragma unroll
      for (int ni = 0; ni < 4; ++ni) {
        acc[mi][ni] = __builtin_amdgcn_mfma_f32_16x16x32_bf16(
            afh[mi], bfh[ni], acc[mi][ni], 0, 0, 0);
        acc[mi][ni] = __builtin_amdgcn_mfma_f32_16x16x32_bf16(
            afh[mi], bfl[ni], acc[mi][ni], 0, 0, 0);
      }
    bf16x8 afl[4];
#pragma unroll
    for (int mi = 0; mi < 4; ++mi)
      afl[mi] = *(const bf16x8*)&Sbuf[buf][1][((wr + (mi << 4) + lrow) << 5) + kc8];
#pragma unroll
    for (int mi = 0; mi < 4; ++mi)
#pragma unroll
      for (int ni = 0; ni < 4; ++ni)
        acc[mi][ni] = __builtin_amdgcn_mfma_f32_16x16x32_bf16(
            afl[mi], bfh[ni], acc[mi][ni], 0, 0, 0);
  };

  // prologue: fill buf0 (8 loads in flight)
  STAGE(0, kbeg);
  int cur = 0;
  for (int kt = kbeg; kt < kend; ++kt) {
    bool more = (kt + 1 < kend);
    if (more) STAGE(cur ^ 1, kt + 1);  // 16 in flight
    // wait ONLY for cur's 8 loads (issued a full iteration ago);
    // next's 8 remain in flight across barrier + compute.
    if (more) asm volatile("s_waitcnt vmcnt(8)" ::: "memory");
    else      asm volatile("s_waitcnt vmcnt(0)" ::: "memory");
    __builtin_amdgcn_s_barrier();
    asm volatile("" ::: "memory");
    COMPUTE(cur);
    asm volatile("" ::: "memory");
    __builtin_amdgcn_s_barrier();   // readers done before buf overwritten
    asm volatile("" ::: "memory");
    cur ^= 1;
  }

  int m0 = (by << 7) + wr + (kg << 2);
  int n0 = (bx << 7) + wc;
#pragma unroll
  for (int mi = 0; mi < 4; ++mi) {
#pragma unroll
    for (int ni = 0; ni < 4; ++ni) {
      int col = n0 + (ni << 4) + lrow;
      float bv = 0.f;
      if ((KSP == 1) && (F & FB_BIAS)) bv = bias[col];
      int rb = m0 + (mi << 4);
#pragma unroll
      for (int r = 0; r < 4; ++r) {
        float v = acc[mi][ni][r];
        long ci = (long)bz * sCz + (long)(rb + r) * ldc + col;
        if constexpr (KSP > 1) {
          Cf[(long)ks * pstride + ci] = v;  // raw partial
        } else {
          v += bv;
          if (F & FB_RELU) v = fmaxf(v, 0.f);
          if (F & FB_RES) v += resF[ci];
          if (F & FB_F32) Cf[ci] = v;
          if (F & FB_SPLIT) {
            u16 h = f2bf(v);
            Ch[ci] = h;
            Cl[ci] = f2bf(v - bf2f(h));
          }
        }
      }
    }
  }
}

// ============================================================================
// reduce for split-K N=1024 GEMMs: v = p0+p1+bias (+rs); rs=v; x=split(v)
// ============================================================================
template <bool RES>
__global__ void reduce_split(const float* __restrict__ p,
                             const float* __restrict__ bias,
                             float* __restrict__ rs, u16* __restrict__ xh,
                             u16* __restrict__ xl) {
  long i = ((long)blockIdx.x * 256 + threadIdx.x) << 2;
  int col = (int)(i & 1023);
  float4 a = *(const float4*)(p + i);
  float4 b = *(const float4*)(p + i + (long)MM * HH1);
  float4 v;
  v.x = a.x + b.x + bias[col];
  v.y = a.y + b.y + bias[col + 1];
  v.z = a.z + b.z + bias[col + 2];
  v.w = a.w + b.w + bias[col + 3];
  if (RES) {
    float4 r0 = *(const float4*)(rs + i);
    v.x += r0.x; v.y += r0.y; v.z += r0.z; v.w += r0.w;
  }
  *(float4*)(rs + i) = v;
  ushort4 h, l;
  h.x = f2bf(v.x); l.x = f2bf(v.x - bf2f(h.x));
  h.y = f2bf(v.y); l.y = f2bf(v.y - bf2f(h.y));
  h.z = f2bf(v.z); l.z = f2bf(v.z - bf2f(h.z));
  h.w = f2bf(v.w); l.w = f2bf(v.w - bf2f(h.w));
  *(ushort4*)(xh + i) = h;
  *(ushort4*)(xl + i) = l;
}

// ============================================================================
// elementwise split: f32 -> (hi, lo) bf16
// ============================================================================
__global__ void split_kernel(const float* __restrict__ src, u16* __restrict__ hi,
                             u16* __restrict__ lo) {
  long i = ((long)blockIdx.x * 256 + threadIdx.x) << 2;
  float4 v = *(const float4*)(src + i);
  ushort4 h, l;
  h.x = f2bf(v.x); l.x = f2bf(v.x - bf2f(h.x));
  h.y = f2bf(v.y); l.y = f2bf(v.y - bf2f(h.y));
  h.z = f2bf(v.z); l.z = f2bf(v.z - bf2f(h.z));
  h.w = f2bf(v.w); l.w = f2bf(v.w - bf2f(h.w));
  *(ushort4*)(hi + i) = h;
  *(ushort4*)(lo + i) = l;
}

__global__ void concat_bias(const float* __restrict__ qb, const float* __restrict__ kb,
                            const float* __restrict__ vb, float* __restrict__ dst) {
  int j = blockIdx.x * 256 + threadIdx.x;  // 0..3071
  float v = (j < 1024) ? qb[j] : ((j < 2048) ? kb[j - 1024] : vb[j - 2048]);
  dst[j] = v;
}

__global__ void deg_kernel(const int* __restrict__ am, int* __restrict__ deg) {
  int i = blockIdx.x * 256 + threadIdx.x;
  int b = i >> 11, q = i & 2047;
  const int* a = am + b * SSQ;
  int any = 0;
  for (int k = 0; k <= q; ++k) any |= (a[k] != 0);
  deg[i] = !any;
}

// ============================================================================
// fused hi/lo transpose: VT[b][n][k] = V[b*S+k][n], V leading dim sld
// ============================================================================
__global__ void transpose_v2(const u16* __restrict__ Vh, const u16* __restrict__ Vl,
                             int sld, u16* __restrict__ VTh, u16* __restrict__ VTl) {
  __shared__ u16 th[64][68];
  __shared__ u16 tl[64][68];
  int b = blockIdx.z;
  int c0 = blockIdx.x << 6;
  int r0 = blockIdx.y << 6;
  int tr = threadIdx.x >> 4, tc = threadIdx.x & 15;
  long sbase = ((long)(b * SSQ + r0)) * sld + c0;
#pragma unroll
  for (int j = 0; j < 4; ++j) {
    int r = (j << 4) + tr;
    ushort4 uh = *(const ushort4*)(Vh + sbase + (long)r * sld + (tc << 2));
    ushort4 ul = *(const ushort4*)(Vl + sbase + (long)r * sld + (tc << 2));
    th[r][(tc << 2) + 0] = uh.x; th[r][(tc << 2) + 1] = uh.y;
    th[r][(tc << 2) + 2] = uh.z; th[r][(tc << 2) + 3] = uh.w;
    tl[r][(tc << 2) + 0] = ul.x; tl[r][(tc << 2) + 1] = ul.y;
    tl[r][(tc << 2) + 2] = ul.z; tl[r][(tc << 2) + 3] = ul.w;
  }
  __syncthreads();
  long dbase = ((long)b * HH1 + c0) * SSQ + r0;
#pragma unroll
  for (int j = 0; j < 4; ++j) {
    int c = (j << 4) + tr;
    ushort4 uh, ul;
    uh.x = th[(tc << 2) + 0][c]; uh.y = th[(tc << 2) + 1][c];
    uh.z = th[(tc << 2) + 2][c]; uh.w = th[(tc << 2) + 3][c];
    ul.x = tl[(tc << 2) + 0][c]; ul.y = tl[(tc << 2) + 1][c];
    ul.z = tl[(tc << 2) + 2][c]; ul.w = tl[(tc << 2) + 3][c];
    *(ushort4*)(VTh + dbase + (long)c * SSQ + (tc << 2)) = uh;
    *(ushort4*)(VTl + dbase + (long)c * SSQ + (tc << 2)) = ul;
  }
}

// ============================================================================
// column mean of V (degenerate rows); V hi/lo with leading dim ld
// ============================================================================
__global__ void colmean_partial(const u16* __restrict__ Vh, const u16* __restrict__ Vl,
                                int ld, float* __restrict__ part) {
  int n = blockIdx.x * 256 + threadIdx.x;
  int b = blockIdx.y, kc = blockIdx.z;
  long base = ((long)(b * SSQ + kc * 256)) * ld + n;
  float s = 0.f;
  for (int k = 0; k < 256; ++k) {
    long o = base + (long)k * ld;
    s += bf2f(Vh[o]) + bf2f(Vl[o]);
  }
  part[((kc * BB) + b) * HH1 + n] = s;
}
__global__ void colmean_final(const float* __restrict__ part, float* __restrict__ mV) {
  int i = blockIdx.x * 256 + threadIdx.x;
  int b = i >> 10, n = i & 1023;
  float s = 0.f;
  for (int kc = 0; kc < 8; ++kc) s += part[((kc * BB) + b) * HH1 + n];
  mV[i] = s * (1.f / (float)SSQ);
}

// ============================================================================
// row softmax: reads two score partials (ks0+ks1) into LDS row cache.
// ============================================================================
__global__ void softmax_kernel(const float* __restrict__ sc, u16* __restrict__ Ph,
                               u16* __restrict__ Pl, const int* __restrict__ am,
                               const int* __restrict__ deg) {
  int q = blockIdx.x, b = blockIdx.y;
  int tid = threadIdx.x;
  long rowoff = ((long)b * SSQ + q) * SSQ;
  int qt_end = ((q >> 7) + 1) << 7;
  if (deg[b * SSQ + q]) {
    for (int k = tid; k < qt_end; k += 256) { Ph[rowoff + k] = 0; Pl[rowoff + k] = 0; }
    return;
  }
  const int* a = am + b * SSQ;
  const float scale = 0.03125f;  // 1/sqrt(1024)
  constexpr long PSTR = (long)BB * SSQ * SSQ;
  __shared__ float rowbuf[2048];
  __shared__ float sred[8];
  int w = tid >> 6, ln = tid & 63;

  for (int k = tid; k < qt_end; k += 256)
    rowbuf[k] = sc[rowoff + k] + sc[rowoff + k + PSTR];
  __syncthreads();

  float m = -1e30f;
  for (int k = tid; k <= q; k += 256)
    if (a[k]) m = fmaxf(m, rowbuf[k]);
#pragma unroll
  for (int o = 32; o; o >>= 1) m = fmaxf(m, __shfl_xor(m, o));
  if (!ln) sred[w] = m;
  __syncthreads();
  float M = fmaxf(fmaxf(sred[0], sred[1]), fmaxf(sred[2], sred[3]));

  float s = 0.f;
  for (int k = tid; k <= q; k += 256)
    if (a[k]) s += expf((rowbuf[k] - M) * scale);
#pragma unroll
  for (int o = 32; o; o >>= 1) s += __shfl_xor(s, o);
  if (!ln) sred[4 + w] = s;
  __syncthreads();
  float Ssum = sred[4] + sred[5] + sred[6] + sred[7];
  float inv = 1.f / Ssum;

  for (int k = tid; k < qt_end; k += 256) {
    float p = 0.f;
    if (k <= q && a[k]) p = expf((rowbuf[k] - M) * scale) * inv;
    u16 h = f2bf(p);
    Ph[rowoff + k] = h;
    Pl[rowoff + k] = f2bf(p - bf2f(h));
  }
}

// ============================================================================
// post-attention: rs += pv0+pv1 (+meanV for degenerate rows); x = split(rs)
// ============================================================================
__global__ void attn_post(float* __restrict__ rs, const float* __restrict__ pv,
                          u16* __restrict__ xh, u16* __restrict__ xl,
                          const int* __restrict__ deg, const float* __restrict__ mV) {
  long t = (long)blockIdx.x * 256 + threadIdx.x;
  long i = t << 2;
  int row = (int)(i >> 10);
  int col = (int)(i & 1023);
  int b = row >> 11;
  constexpr long PSTR = (long)BB * SSQ * HH1;
  float4 v = *(const float4*)(rs + i);
  float4 a = *(const float4*)(pv + i);
  float4 c = *(const float4*)(pv + i + PSTR);
  v.x += a.x + c.x; v.y += a.y + c.y; v.z += a.z + c.z; v.w += a.w + c.w;
  if (deg[row]) {
    const float* m = mV + (b << 10) + col;
    v.x += m[0]; v.y += m[1]; v.z += m[2]; v.w += m[3];
  }
  *(float4*)(rs + i) = v;
  ushort4 h, l;
  h.x = f2bf(v.x); l.x = f2bf(v.x - bf2f(h.x));
  h.y = f2bf(v.y); l.y = f2bf(v.y - bf2f(h.y));
  h.z = f2bf(v.z); l.z = f2bf(v.z - bf2f(h.z));
  h.w = f2bf(v.w); l.w = f2bf(v.w - bf2f(h.w));
  *(ushort4*)(xh + i) = h;
  *(ushort4*)(xl + i) = l;
}

// ============================================================================
// workspace layout (1 MB = 1<<20), ~221MB, lifetime-aliased (see header)
// ============================================================================
constexpr size_t MB = 1u << 20;
constexpr size_t OFF_RS    = 0;         // f32 [4096][1024]   16MB
constexpr size_t OFF_XH    = 16 * MB;   // bf16 [4096][1024]   8MB
constexpr size_t OFF_XL    = 24 * MB;
constexpr size_t OFF_QKVH  = 32 * MB;   // bf16 [4096][3072]  24MB   | Ph/Pl | mlp2/dproj partial
constexpr size_t OFF_QKVL  = 56 * MB;
constexpr size_t OFF_PH    = 32 * MB;   // bf16 [B][S][S]     16MB (alias)
constexpr size_t OFF_PL    = 48 * MB;
constexpr size_t OFF_RED   = 32 * MB;   // f32 [2][4096][1024] 32MB (alias)
constexpr size_t OFF_VTH   = 80 * MB;   // bf16 [B][H1][S]     8MB
constexpr size_t OFF_VTL   = 88 * MB;
constexpr size_t OFF_SC    = 96 * MB;   // f32 [2][B][S][S]   64MB   | act-split | h
constexpr size_t OFF_ACTH  = 96 * MB;   // bf16 [4096][2048]  16MB (alias)
constexpr size_t OFF_ACTL  = 112 * MB;
constexpr size_t OFF_HH    = 96 * MB;   // bf16 [4096][4096]  32MB (alias)
constexpr size_t OFF_HL    = 128 * MB;
constexpr size_t OFF_PVP   = 128 * MB;  // f32 [2][B][S][H1]  32MB (alias, dead before h-upper)
constexpr size_t OFF_DPWH  = 160 * MB;  // dproj w hi/lo, 4MB each
constexpr size_t OFF_DPWL  = 164 * MB;
constexpr size_t OFF_UPWH  = 168 * MB;
constexpr size_t OFF_UPWL  = 172 * MB;
constexpr size_t OFF_WQKVH = 176 * MB;  // [3072][1024] 6MB each
constexpr size_t OFF_WQKVL = 182 * MB;
constexpr size_t OFF_M1H   = 188 * MB;  // 8MB each
constexpr size_t OFF_M1L   = 196 * MB;
constexpr size_t OFF_M2H   = 204 * MB;
constexpr size_t OFF_M2L   = 212 * MB;
constexpr size_t OFF_QKVB  = 220 * MB;              // f32 [3072]
constexpr size_t OFF_MV    = OFF_QKVB + 16 * 1024;  // f32 [B][H1]
constexpr size_t OFF_PART  = OFF_MV + 16 * 1024;    // f32 [8][B][H1]
constexpr size_t OFF_DEG   = OFF_PART + 128 * 1024; // i32 [B][S]

extern "C" void kernel_launch(void* const* d_in, const int* in_sizes, int n_in,
                              void* d_out, int out_size, void* d_ws, size_t ws_size,
                              hipStream_t stream) {
  (void)in_sizes; (void)n_in; (void)out_size; (void)ws_size;

  const float* z    = (const float*)d_in[0];
  const float* act0 = (const float*)d_in[1];
  const float* act1 = (const float*)d_in[2];
  const int* amask  = (const int*)d_in[3];
  const float* dpw  = (const float*)d_in[4];
  const float* dpb  = (const float*)d_in[5];
  const float* upw  = (const float*)d_in[6];
  const float* upb  = (const float*)d_in[7];
  const float* wqw  = (const float*)d_in[8];
  const float* wqb  = (const float*)d_in[9];
  const float* wkw  = (const float*)d_in[10];
  const float* wkb  = (const float*)d_in[11];
  const float* wvw  = (const float*)d_in[12];
  const float* wvb  = (const float*)d_in[13];
  const float* m1w  = (const float*)d_in[14];
  const float* m1b  = (const float*)d_in[15];
  const float* m2w  = (const float*)d_in[16];
  const float* m2b  = (const float*)d_in[17];

  char* ws = (char*)d_ws;
  float* rs    = (float*)(ws + OFF_RS);
  u16* xh      = (u16*)(ws + OFF_XH);    u16* xl    = (u16*)(ws + OFF_XL);
  u16* qkvh    = (u16*)(ws + OFF_QKVH);  u16* qkvl  = (u16*)(ws + OFF_QKVL);
  u16* Ph      = (u16*)(ws + OFF_PH);    u16* Pl    = (u16*)(ws + OFF_PL);
  float* redp  = (float*)(ws + OFF_RED);
  u16* VTh     = (u16*)(ws + OFF_VTH);   u16* VTl   = (u16*)(ws + OFF_VTL);
  float* scb   = (float*)(ws + OFF_SC);
  u16* acth    = (u16*)(ws + OFF_ACTH);  u16* actl  = (u16*)(ws + OFF_ACTL);
  u16* hh      = (u16*)(ws + OFF_HH);    u16* hl    = (u16*)(ws + OFF_HL);
  float* pvp   = (float*)(ws + OFF_PVP);
  u16* dpwh    = (u16*)(ws + OFF_DPWH);  u16* dpwl  = (u16*)(ws + OFF_DPWL);
  u16* upwh    = (u16*)(ws + OFF_UPWH);  u16* upwl  = (u16*)(ws + OFF_UPWL);
  u16* wqkvh   = (u16*)(ws + OFF_WQKVH); u16* wqkvl = (u16*)(ws + OFF_WQKVL);
  u16* m1h     = (u16*)(ws + OFF_M1H);   u16* m1l   = (u16*)(ws + OFF_M1L);
  u16* m2h     = (u16*)(ws + OFF_M2H);   u16* m2l   = (u16*)(ws + OFF_M2L);
  float* qkvb  = (float*)(ws + OFF_QKVB);
  float* mV    = (float*)(ws + OFF_MV);
  float* part  = (float*)(ws + OFF_PART);
  int* deg     = (int*)(ws + OFF_DEG);

  deg_kernel<<<dim3((BB * SSQ) / 256), 256, 0, stream>>>(amask, deg);
  split_kernel<<<dim3((HH1 * HH0) / 1024), 256, 0, stream>>>(dpw, dpwh, dpwl);
  split_kernel<<<dim3((HH0 * HH1) / 1024), 256, 0, stream>>>(upw, upwh, upwl);

  // rs = dproj(act0) + b ; x = split(rs)   [split-K=2 + reduce]
  split_kernel<<<dim3((MM * HH0) / 1024), 256, 0, stream>>>(act0, acth, actl);
  gemm_split<0, 2><<<dim3(HH1 / 128, MM / 128, 2), 256, 0, stream>>>(
      acth, actl, 0, HH0, dpwh, dpwl, 0, HH0, nullptr, nullptr,
      redp, nullptr, nullptr, 0, HH1, HH0, (long)MM * HH1);
  reduce_split<false><<<dim3(MM * HH1 / 1024), 256, 0, stream>>>(redp, dpb, rs, xh, xl);

  for (int i = 0; i < NLAY; ++i) {
    // per-layer weight splits + bias concat
    split_kernel<<<dim3((HH1 * HH1) / 1024), 256, 0, stream>>>(
        wqw + (size_t)i * HH1 * HH1, wqkvh, wqkvl);
    split_kernel<<<dim3((HH1 * HH1) / 1024), 256, 0, stream>>>(
        wkw + (size_t)i * HH1 * HH1, wqkvh + HH1 * HH1, wqkvl + HH1 * HH1);
    split_kernel<<<dim3((HH1 * HH1) / 1024), 256, 0, stream>>>(
        wvw + (size_t)i * HH1 * HH1, wqkvh + 2 * HH1 * HH1, wqkvl + 2 * HH1 * HH1);
    concat_bias<<<dim3(12), 256, 0, stream>>>(wqb + i * HH1, wkb + i * HH1,
                                              wvb + i * HH1, qkvb);
    split_kernel<<<dim3((HH4 * HH1) / 1024), 256, 0, stream>>>(
        m1w + (size_t)i * HH4 * HH1, m1h, m1l);
    split_kernel<<<dim3((HH1 * HH4) / 1024), 256, 0, stream>>>(
        m2w + (size_t)i * HH1 * HH4, m2h, m2l);

    if (i == 1) {
      split_kernel<<<dim3((MM * HH0) / 1024), 256, 0, stream>>>(act1, acth, actl);
      gemm_split<0, 2><<<dim3(HH1 / 128, MM / 128, 2), 256, 0, stream>>>(
          acth, actl, 0, HH0, dpwh, dpwl, 0, HH0, nullptr, nullptr,
          redp, nullptr, nullptr, 0, HH1, HH0, (long)MM * HH1);
      reduce_split<true><<<dim3(MM * HH1 / 1024), 256, 0, stream>>>(redp, dpb, rs, xh, xl);
    }

    // ---- attention ----
    // fused QKV: [4096][3072] = x @ [wq;wk;wv]^T
    gemm_split<FB_BIAS | FB_SPLIT, 1><<<dim3(3072 / 128, MM / 128, 1), 256, 0, stream>>>(
        xh, xl, 0, HH1, wqkvh, wqkvl, 0, HH1, qkvb, nullptr,
        nullptr, qkvh, qkvl, 0, 3072, HH1, 0);

    transpose_v2<<<dim3(HH1 / 64, SSQ / 64, BB), 256, 0, stream>>>(
        qkvh + 2048, qkvl + 2048, 3072, VTh, VTl);
    colmean_partial<<<dim3(HH1 / 256, BB, 8), 256, 0, stream>>>(
        qkvh + 2048, qkvl + 2048, 3072, part);
    colmean_final<<<dim3((BB * HH1) / 256), 256, 0, stream>>>(part, mV);

    // scores = Q K^T, causal tile skip, split-K=2 -> partials in scb
    gemm_split<FB_CSKIP, 2><<<dim3(SSQ / 128, SSQ / 128, BB * 2), 256, 0, stream>>>(
        qkvh, qkvl, (long)SSQ * 3072, 3072, qkvh + 1024, qkvl + 1024,
        (long)SSQ * 3072, 3072, nullptr, nullptr,
        scb, nullptr, nullptr, (long)SSQ * SSQ, SSQ, HH1, (long)BB * SSQ * SSQ);

    softmax_kernel<<<dim3(SSQ, BB), 256, 0, stream>>>(scb, Ph, Pl, amask, deg);

    // PV: split-K=2 over causal-truncated K loop -> partials in pvp
    gemm_split<FB_CKLOOP, 2><<<dim3(HH1 / 128, SSQ / 128, BB * 2), 256, 0, stream>>>(
        Ph, Pl, (long)SSQ * SSQ, SSQ, VTh, VTl, (long)HH1 * SSQ, SSQ, nullptr, nullptr,
        pvp, nullptr, nullptr, (long)SSQ * HH1, HH1, SSQ, (long)BB * SSQ * HH1);

    attn_post<<<dim3((MM * HH1 / 4) / 256), 256, 0, stream>>>(rs, pvp, xh, xl, deg, mV);

    // ---- mlp ----
    gemm_split<FB_BIAS | FB_RELU | FB_SPLIT, 1>
        <<<dim3(HH4 / 128, MM / 128, 1), 256, 0, stream>>>(
        xh, xl, 0, HH1, m1h, m1l, 0, HH1, m1b + i * HH4, nullptr,
        nullptr, hh, hl, 0, HH4, HH1, 0);
    gemm_split<0, 2><<<dim3(HH1 / 128, MM / 128, 2), 256, 0, stream>>>(
        hh, hl, 0, HH4, m2h, m2l, 0, HH4, nullptr, nullptr,
        redp, nullptr, nullptr, 0, HH1, HH4, (long)MM * HH1);
    reduce_split<true><<<dim3(MM * HH1 / 1024), 256, 0, stream>>>(
        redp, m2b + i * HH1, rs, xh, xl);
  }

  // out = uproj(x) + b + z
  gemm_split<FB_BIAS | FB_RES | FB_F32, 1>
      <<<dim3(HH0 / 128, MM / 128, 1), 256, 0, stream>>>(
      xh, xl, 0, HH1, upwh, upwl, 0, HH1, upb, z,
      (float*)d_out, nullptr, nullptr, 0, HH0, HH1, 0);
}

// Round 8
// 3921.750 us; speedup vs baseline: 1.4013x; 1.0335x over previous
//
#include <hip/hip_runtime.h>
#include <cstdint>

// ============================================================================
// Ladder transformer forward on MI355X (gfx950).  Round 8.
// Decision log:
//  - R7: 4053us. mlp1 111us, MfmaUtil 40%, HBM 37%. LDS traffic (~2300cyc)
//    vs MFMA (~1860cyc) per CU-K-step -> 128^2 tile is LDS-bw co-limited.
//  - R8: 256x256 8-wave BK=32 kernel (gemm_big), same R7 dbuf+vmcnt(8)
//    schedule (8 loads/thread/tile unchanged), 128KB LDS, wave tile 128x64.
//    Routed: mlp1 (KSP1, full epilogue), mlp2+dproj (KSP4 + reduce<4>).
//    QKV/scores/PV/uproj stay on the 128^2 kernel.
//  - Per-accumulator MFMA order preserved (hh,hl,lh) -> numerics unchanged
//    except KSP4 reduce order (f32, negligible).
// ============================================================================

typedef unsigned short u16;
typedef __attribute__((ext_vector_type(8))) __bf16 bf16x8;
typedef __attribute__((ext_vector_type(4))) float f32x4;

#define DI __device__ __forceinline__

constexpr int BB = 2, SSQ = 2048, HH0 = 2048, HH1 = 1024, NLAY = 8, HH4 = 4096;
constexpr int MM = BB * SSQ;  // 4096 token rows

DI float bf2f(u16 h) {
  union { uint32_t u; float f; } x; x.u = ((uint32_t)h) << 16; return x.f;
}
DI u16 f2bf(float f) {
  union { float f; uint32_t u; } x; x.f = f;
  uint32_t u = x.u;
  return (u16)((u + 0x7fffu + ((u >> 16) & 1u)) >> 16);  // RTNE
}

enum {
  FB_BIAS = 1, FB_RES = 2, FB_RELU = 4, FB_F32 = 8, FB_SPLIT = 16,
  FB_CSKIP = 32, FB_CKLOOP = 64
};

// ============================================================================
// 128x128 split GEMM (4 waves) — R7 structure. Used for QKV/scores/PV/uproj.
// ============================================================================
template <int F, int KSP>
__global__ __launch_bounds__(256) void gemm_split(
    const u16* __restrict__ Ah, const u16* __restrict__ Al, long sAz, int lda,
    const u16* __restrict__ Bh, const u16* __restrict__ Bl, long sBz, int ldb,
    const float* __restrict__ bias, const float* __restrict__ resF,
    float* Cf, u16* Ch, u16* Cl, long sCz, int ldc, int K, long pstride) {
  int gx = gridDim.x, gy = gridDim.y, gz = gridDim.z;
  long o = blockIdx.x + (long)gx * (blockIdx.y + (long)gy * blockIdx.z);
  long nwg = (long)gx * gy * gz;
  long cq = nwg >> 3, cr = nwg & 7;
  long xcd = o & 7, cidx = o >> 3;
  long sl = (xcd < cr ? xcd * (cq + 1) : cr * (cq + 1) + (xcd - cr) * cq) + cidx;
  int bx = (int)(sl % gx);
  long tt = sl / gx;
  int by = (int)(tt % gy);
  int bzf = (int)(tt / gy);
  int NB = gz / KSP;
  int bz = bzf % NB;
  int ks = bzf / NB;

  if ((F & FB_CSKIP) && bx > by) return;

  __shared__ __align__(16) u16 Sbuf[2][4][128 * 32];

  int tid = threadIdx.x;
  int lane = tid & 63;
  int wave = tid >> 6;
  int wr = (wave >> 1) << 6;
  int wc = (wave & 1) << 6;
  int lrow = lane & 15;
  int kg = lane >> 4;
  int kc8 = (kg ^ ((lrow >> 1) & 3)) << 3;

  const u16* Abh = Ah + (long)bz * sAz + ((long)(by << 7)) * lda;
  const u16* Abl = Al + (long)bz * sAz + ((long)(by << 7)) * lda;
  const u16* Bbh = Bh + (long)bz * sBz + ((long)(bx << 7)) * ldb;
  const u16* Bbl = Bl + (long)bz * sBz + ((long)(bx << 7)) * ldb;

  int nKtot = (F & FB_CKLOOP) ? ((by + 1) << 2) : (K >> 5);
  int kbeg = (KSP > 1) ? (ks * nKtot) / KSP : 0;
  int kend = (KSP > 1) ? ((ks + 1) * nKtot) / KSP : nKtot;

  f32x4 acc[4][4] = {};

  auto STAGE = [&](int buf, int kt) {
    int k0 = kt << 5;
#pragma unroll
    for (int it = 0; it < 2; ++it) {
      int sidx = (it << 8) + tid;
      int r = sidx >> 2;
      int jsw = (sidx & 3) ^ ((r >> 1) & 3);
      long goff = (long)r * lda + (k0 + (jsw << 3));
      long gofB = (long)r * ldb + (k0 + (jsw << 3));
      int loff = sidx << 3;
      __builtin_amdgcn_global_load_lds(
          (__attribute__((address_space(1))) void*)(Abh + goff),
          (__attribute__((address_space(3))) void*)(&Sbuf[buf][0][loff]), 16, 0, 0);
      __builtin_amdgcn_global_load_lds(
          (__attribute__((address_space(1))) void*)(Abl + goff),
          (__attribute__((address_space(3))) void*)(&Sbuf[buf][1][loff]), 16, 0, 0);
      __builtin_amdgcn_global_load_lds(
          (__attribute__((address_space(1))) void*)(Bbh + gofB),
          (__attribute__((address_space(3))) void*)(&Sbuf[buf][2][loff]), 16, 0, 0);
      __builtin_amdgcn_global_load_lds(
          (__attribute__((address_space(1))) void*)(Bbl + gofB),
          (__attribute__((address_space(3))) void*)(&Sbuf[buf][3][loff]), 16, 0, 0);
    }
  };

  auto COMPUTE = [&](int buf) {
    bf16x8 afh[4], bfh[4], bfl[4];
#pragma unroll
    for (int mi = 0; mi < 4; ++mi)
      afh[mi] = *(const bf16x8*)&Sbuf[buf][0][((wr + (mi << 4) + lrow) << 5) + kc8];
#pragma unroll
    for (int ni = 0; ni < 4; ++ni) {
      bfh[ni] = *(const bf16x8*)&Sbuf[buf][2][((wc + (ni << 4) + lrow) << 5) + kc8];
      bfl[ni] = *(const bf16x8*)&Sbuf[buf][3][((wc + (ni << 4) + lrow) << 5) + kc8];
    }
#pragma unroll
    for (int mi = 0; mi < 4; ++mi)
#pragma unroll
      for (int ni = 0; ni < 4; ++ni) {
        acc[mi][ni] = __builtin_amdgcn_mfma_f32_16x16x32_bf16(
            afh[mi], bfh[ni], acc[mi][ni], 0, 0, 0);
        acc[mi][ni] = __builtin_amdgcn_mfma_f32_16x16x32_bf16(
            afh[mi], bfl[ni], acc[mi][ni], 0, 0, 0);
      }
    bf16x8 afl[4];
#pragma unroll
    for (int mi = 0; mi < 4; ++mi)
      afl[mi] = *(const bf16x8*)&Sbuf[buf][1][((wr + (mi << 4) + lrow) << 5) + kc8];
#pragma unroll
    for (int mi = 0; mi < 4; ++mi)
#pragma unroll
      for (int ni = 0; ni < 4; ++ni)
        acc[mi][ni] = __builtin_amdgcn_mfma_f32_16x16x32_bf16(
            afl[mi], bfh[ni], acc[mi][ni], 0, 0, 0);
  };

  STAGE(0, kbeg);
  int cur = 0;
  for (int kt = kbeg; kt < kend; ++kt) {
    bool more = (kt + 1 < kend);
    if (more) STAGE(cur ^ 1, kt + 1);
    if (more) asm volatile("s_waitcnt vmcnt(8)" ::: "memory");
    else      asm volatile("s_waitcnt vmcnt(0)" ::: "memory");
    __builtin_amdgcn_s_barrier();
    asm volatile("" ::: "memory");
    COMPUTE(cur);
    asm volatile("" ::: "memory");
    __builtin_amdgcn_s_barrier();
    asm volatile("" ::: "memory");
    cur ^= 1;
  }

  int m0 = (by << 7) + wr + (kg << 2);
  int n0 = (bx << 7) + wc;
#pragma unroll
  for (int mi = 0; mi < 4; ++mi) {
#pragma unroll
    for (int ni = 0; ni < 4; ++ni) {
      int col = n0 + (ni << 4) + lrow;
      float bv = 0.f;
      if ((KSP == 1) && (F & FB_BIAS)) bv = bias[col];
      int rb = m0 + (mi << 4);
#pragma unroll
      for (int r = 0; r < 4; ++r) {
        float v = acc[mi][ni][r];
        long ci = (long)bz * sCz + (long)(rb + r) * ldc + col;
        if constexpr (KSP > 1) {
          Cf[(long)ks * pstride + ci] = v;
        } else {
          v += bv;
          if (F & FB_RELU) v = fmaxf(v, 0.f);
          if (F & FB_RES) v += resF[ci];
          if (F & FB_F32) Cf[ci] = v;
          if (F & FB_SPLIT) {
            u16 h = f2bf(v);
            Ch[ci] = h;
            Cl[ci] = f2bf(v - bf2f(h));
          }
        }
      }
    }
  }
}

// ============================================================================
// 256x256 split GEMM, 8 waves (512 thr), BK=32, 128KB LDS, same dbuf+vmcnt(8)
// schedule. Wave tile 128x64 (wave grid 2M x 4N). No batching (bz=0).
// ============================================================================
template <int F, int KSP>
__global__ __launch_bounds__(512, 2) void gemm_big(
    const u16* __restrict__ Ah, const u16* __restrict__ Al, int lda,
    const u16* __restrict__ Bh, const u16* __restrict__ Bl, int ldb,
    const float* __restrict__ bias,
    float* Cf, u16* Ch, u16* Cl, int ldc, int K, long pstride) {
  int gx = gridDim.x, gy = gridDim.y, gz = gridDim.z;
  long o = blockIdx.x + (long)gx * (blockIdx.y + (long)gy * blockIdx.z);
  long nwg = (long)gx * gy * gz;
  long cq = nwg >> 3, cr = nwg & 7;
  long xcd = o & 7, cidx = o >> 3;
  long sl = (xcd < cr ? xcd * (cq + 1) : cr * (cq + 1) + (xcd - cr) * cq) + cidx;
  int bx = (int)(sl % gx);
  long tt = sl / gx;
  int by = (int)(tt % gy);
  int ks = (int)(tt / gy);  // gz == KSP

  __shared__ __align__(16) u16 Sbuf[2][4][256 * 32];  // 128 KB

  int tid = threadIdx.x;
  int lane = tid & 63;
  int wave = tid >> 6;         // 0..7
  int wm = (wave >> 2) << 7;   // 0 / 128
  int wn = (wave & 3) << 6;    // 0/64/128/192
  int lrow = lane & 15;
  int kg = lane >> 4;
  int kc8 = (kg ^ ((lrow >> 1) & 3)) << 3;

  const u16* Abh = Ah + ((long)(by << 8)) * lda;
  const u16* Abl = Al + ((long)(by << 8)) * lda;
  const u16* Bbh = Bh + ((long)(bx << 8)) * ldb;
  const u16* Bbl = Bl + ((long)(bx << 8)) * ldb;

  int nKtot = K >> 5;
  int kbeg = (KSP > 1) ? (ks * nKtot) / KSP : 0;
  int kend = (KSP > 1) ? ((ks + 1) * nKtot) / KSP : nKtot;

  f32x4 acc[8][4] = {};

  auto STAGE = [&](int buf, int kt) {
    int k0 = kt << 5;
#pragma unroll
    for (int it = 0; it < 2; ++it) {
      int sidx = (it << 9) + tid;   // 0..1023
      int r = sidx >> 2;            // tile row 0..255
      int jsw = (sidx & 3) ^ ((r >> 1) & 3);
      long goff = (long)r * lda + (k0 + (jsw << 3));
      long gofB = (long)r * ldb + (k0 + (jsw << 3));
      int loff = sidx << 3;
      __builtin_amdgcn_global_load_lds(
          (__attribute__((address_space(1))) void*)(Abh + goff),
          (__attribute__((address_space(3))) void*)(&Sbuf[buf][0][loff]), 16, 0, 0);
      __builtin_amdgcn_global_load_lds(
          (__attribute__((address_space(1))) void*)(Abl + goff),
          (__attribute__((address_space(3))) void*)(&Sbuf[buf][1][loff]), 16, 0, 0);
      __builtin_amdgcn_global_load_lds(
          (__attribute__((address_space(1))) void*)(Bbh + gofB),
          (__attribute__((address_space(3))) void*)(&Sbuf[buf][2][loff]), 16, 0, 0);
      __builtin_amdgcn_global_load_lds(
          (__attribute__((address_space(1))) void*)(Bbl + gofB),
          (__attribute__((address_space(3))) void*)(&Sbuf[buf][3][loff]), 16, 0, 0);
    }
  };

  auto COMPUTE = [&](int buf) {
    bf16x8 bfh[4], bfl[4];
#pragma unroll
    for (int ni = 0; ni < 4; ++ni) {
      int brow = wn + (ni << 4) + lrow;
      bfh[ni] = *(const bf16x8*)&Sbuf[buf][2][(brow << 5) + kc8];
      bfl[ni] = *(const bf16x8*)&Sbuf[buf][3][(brow << 5) + kc8];
    }
#pragma unroll
    for (int mi = 0; mi < 8; ++mi) {
      int arow = wm + (mi << 4) + lrow;
      bf16x8 ah = *(const bf16x8*)&Sbuf[buf][0][(arow << 5) + kc8];
      bf16x8 al = *(const bf16x8*)&Sbuf[buf][1][(arow << 5) + kc8];
#pragma unroll
      for (int ni = 0; ni < 4; ++ni) {
        acc[mi][ni] = __builtin_amdgcn_mfma_f32_16x16x32_bf16(
            ah, bfh[ni], acc[mi][ni], 0, 0, 0);
        acc[mi][ni] = __builtin_amdgcn_mfma_f32_16x16x32_bf16(
            ah, bfl[ni], acc[mi][ni], 0, 0, 0);
        acc[mi][ni] = __builtin_amdgcn_mfma_f32_16x16x32_bf16(
            al, bfh[ni], acc[mi][ni], 0, 0, 0);
      }
    }
  };

  STAGE(0, kbeg);
  int cur = 0;
  for (int kt = kbeg; kt < kend; ++kt) {
    bool more = (kt + 1 < kend);
    if (more) STAGE(cur ^ 1, kt + 1);  // 8 more loads -> 16 in flight
    if (more) asm volatile("s_waitcnt vmcnt(8)" ::: "memory");
    else      asm volatile("s_waitcnt vmcnt(0)" ::: "memory");
    __builtin_amdgcn_s_barrier();
    asm volatile("" ::: "memory");
    COMPUTE(cur);
    asm volatile("" ::: "memory");
    __builtin_amdgcn_s_barrier();
    asm volatile("" ::: "memory");
    cur ^= 1;
  }

  int m0 = (by << 8) + wm + (kg << 2);
  int n0 = (bx << 8) + wn;
#pragma unroll
  for (int mi = 0; mi < 8; ++mi) {
#pragma unroll
    for (int ni = 0; ni < 4; ++ni) {
      int col = n0 + (ni << 4) + lrow;
      float bv = 0.f;
      if ((KSP == 1) && (F & FB_BIAS)) bv = bias[col];
      int rb = m0 + (mi << 4);
#pragma unroll
      for (int r = 0; r < 4; ++r) {
        float v = acc[mi][ni][r];
        long ci = (long)(rb + r) * ldc + col;
        if constexpr (KSP > 1) {
          Cf[(long)ks * pstride + ci] = v;
        } else {
          v += bv;
          if (F & FB_RELU) v = fmaxf(v, 0.f);
          if (F & FB_F32) Cf[ci] = v;
          if (F & FB_SPLIT) {
            u16 h = f2bf(v);
            Ch[ci] = h;
            Cl[ci] = f2bf(v - bf2f(h));
          }
        }
      }
    }
  }
}

// ============================================================================
// reduce for split-K N=1024 GEMMs: v = sum_j p_j + bias (+rs); rs=v; x=split
// ============================================================================
template <int KSP, bool RES>
__global__ void reduce_split(const float* __restrict__ p,
                             const float* __restrict__ bias,
                             float* __restrict__ rs, u16* __restrict__ xh,
                             u16* __restrict__ xl) {
  long i = ((long)blockIdx.x * 256 + threadIdx.x) << 2;
  int col = (int)(i & 1023);
  constexpr long PSTR = (long)MM * HH1;
  float4 v;
  v.x = bias[col]; v.y = bias[col + 1]; v.z = bias[col + 2]; v.w = bias[col + 3];
#pragma unroll
  for (int j = 0; j < KSP; ++j) {
    float4 a = *(const float4*)(p + i + j * PSTR);
    v.x += a.x; v.y += a.y; v.z += a.z; v.w += a.w;
  }
  if (RES) {
    float4 r0 = *(const float4*)(rs + i);
    v.x += r0.x; v.y += r0.y; v.z += r0.z; v.w += r0.w;
  }
  *(float4*)(rs + i) = v;
  ushort4 h, l;
  h.x = f2bf(v.x); l.x = f2bf(v.x - bf2f(h.x));
  h.y = f2bf(v.y); l.y = f2bf(v.y - bf2f(h.y));
  h.z = f2bf(v.z); l.z = f2bf(v.z - bf2f(h.z));
  h.w = f2bf(v.w); l.w = f2bf(v.w - bf2f(h.w));
  *(ushort4*)(xh + i) = h;
  *(ushort4*)(xl + i) = l;
}

// ============================================================================
// elementwise split: f32 -> (hi, lo) bf16
// ============================================================================
__global__ void split_kernel(const float* __restrict__ src, u16* __restrict__ hi,
                             u16* __restrict__ lo) {
  long i = ((long)blockIdx.x * 256 + threadIdx.x) << 2;
  float4 v = *(const float4*)(src + i);
  ushort4 h, l;
  h.x = f2bf(v.x); l.x = f2bf(v.x - bf2f(h.x));
  h.y = f2bf(v.y); l.y = f2bf(v.y - bf2f(h.y));
  h.z = f2bf(v.z); l.z = f2bf(v.z - bf2f(h.z));
  h.w = f2bf(v.w); l.w = f2bf(v.w - bf2f(h.w));
  *(ushort4*)(hi + i) = h;
  *(ushort4*)(lo + i) = l;
}

__global__ void concat_bias(const float* __restrict__ qb, const float* __restrict__ kb,
                            const float* __restrict__ vb, float* __restrict__ dst) {
  int j = blockIdx.x * 256 + threadIdx.x;
  float v = (j < 1024) ? qb[j] : ((j < 2048) ? kb[j - 1024] : vb[j - 2048]);
  dst[j] = v;
}

__global__ void deg_kernel(const int* __restrict__ am, int* __restrict__ deg) {
  int i = blockIdx.x * 256 + threadIdx.x;
  int b = i >> 11, q = i & 2047;
  const int* a = am + b * SSQ;
  int any = 0;
  for (int k = 0; k <= q; ++k) any |= (a[k] != 0);
  deg[i] = !any;
}

// ============================================================================
// fused hi/lo transpose: VT[b][n][k] = V[b*S+k][n], V leading dim sld
// ============================================================================
__global__ void transpose_v2(const u16* __restrict__ Vh, const u16* __restrict__ Vl,
                             int sld, u16* __restrict__ VTh, u16* __restrict__ VTl) {
  __shared__ u16 th[64][68];
  __shared__ u16 tl[64][68];
  int b = blockIdx.z;
  int c0 = blockIdx.x << 6;
  int r0 = blockIdx.y << 6;
  int tr = threadIdx.x >> 4, tc = threadIdx.x & 15;
  long sbase = ((long)(b * SSQ + r0)) * sld + c0;
#pragma unroll
  for (int j = 0; j < 4; ++j) {
    int r = (j << 4) + tr;
    ushort4 uh = *(const ushort4*)(Vh + sbase + (long)r * sld + (tc << 2));
    ushort4 ul = *(const ushort4*)(Vl + sbase + (long)r * sld + (tc << 2));
    th[r][(tc << 2) + 0] = uh.x; th[r][(tc << 2) + 1] = uh.y;
    th[r][(tc << 2) + 2] = uh.z; th[r][(tc << 2) + 3] = uh.w;
    tl[r][(tc << 2) + 0] = ul.x; tl[r][(tc << 2) + 1] = ul.y;
    tl[r][(tc << 2) + 2] = ul.z; tl[r][(tc << 2) + 3] = ul.w;
  }
  __syncthreads();
  long dbase = ((long)b * HH1 + c0) * SSQ + r0;
#pragma unroll
  for (int j = 0; j < 4; ++j) {
    int c = (j << 4) + tr;
    ushort4 uh, ul;
    uh.x = th[(tc << 2) + 0][c]; uh.y = th[(tc << 2) + 1][c];
    uh.z = th[(tc << 2) + 2][c]; uh.w = th[(tc << 2) + 3][c];
    ul.x = tl[(tc << 2) + 0][c]; ul.y = tl[(tc << 2) + 1][c];
    ul.z = tl[(tc << 2) + 2][c]; ul.w = tl[(tc << 2) + 3][c];
    *(ushort4*)(VTh + dbase + (long)c * SSQ + (tc << 2)) = uh;
    *(ushort4*)(VTl + dbase + (long)c * SSQ + (tc << 2)) = ul;
  }
}

// ============================================================================
// column mean of V (degenerate rows); V hi/lo with leading dim ld
// ============================================================================
__global__ void colmean_partial(const u16* __restrict__ Vh, const u16* __restrict__ Vl,
                                int ld, float* __restrict__ part) {
  int n = blockIdx.x * 256 + threadIdx.x;
  int b = blockIdx.y, kc = blockIdx.z;
  long base = ((long)(b * SSQ + kc * 256)) * ld + n;
  float s = 0.f;
  for (int k = 0; k < 256; ++k) {
    long o = base + (long)k * ld;
    s += bf2f(Vh[o]) + bf2f(Vl[o]);
  }
  part[((kc * BB) + b) * HH1 + n] = s;
}
__global__ void colmean_final(const float* __restrict__ part, float* __restrict__ mV) {
  int i = blockIdx.x * 256 + threadIdx.x;
  int b = i >> 10, n = i & 1023;
  float s = 0.f;
  for (int kc = 0; kc < 8; ++kc) s += part[((kc * BB) + b) * HH1 + n];
  mV[i] = s * (1.f / (float)SSQ);
}

// ============================================================================
// row softmax: reads two score partials (ks0+ks1) into LDS row cache.
// ============================================================================
__global__ void softmax_kernel(const float* __restrict__ sc, u16* __restrict__ Ph,
                               u16* __restrict__ Pl, const int* __restrict__ am,
                               const int* __restrict__ deg) {
  int q = blockIdx.x, b = blockIdx.y;
  int tid = threadIdx.x;
  long rowoff = ((long)b * SSQ + q) * SSQ;
  int qt_end = ((q >> 7) + 1) << 7;
  if (deg[b * SSQ + q]) {
    for (int k = tid; k < qt_end; k += 256) { Ph[rowoff + k] = 0; Pl[rowoff + k] = 0; }
    return;
  }
  const int* a = am + b * SSQ;
  const float scale = 0.03125f;  // 1/sqrt(1024)
  constexpr long PSTR = (long)BB * SSQ * SSQ;
  __shared__ float rowbuf[2048];
  __shared__ float sred[8];
  int w = tid >> 6, ln = tid & 63;

  for (int k = tid; k < qt_end; k += 256)
    rowbuf[k] = sc[rowoff + k] + sc[rowoff + k + PSTR];
  __syncthreads();

  float m = -1e30f;
  for (int k = tid; k <= q; k += 256)
    if (a[k]) m = fmaxf(m, rowbuf[k]);
#pragma unroll
  for (int o = 32; o; o >>= 1) m = fmaxf(m, __shfl_xor(m, o));
  if (!ln) sred[w] = m;
  __syncthreads();
  float M = fmaxf(fmaxf(sred[0], sred[1]), fmaxf(sred[2], sred[3]));

  float s = 0.f;
  for (int k = tid; k <= q; k += 256)
    if (a[k]) s += expf((rowbuf[k] - M) * scale);
#pragma unroll
  for (int o = 32; o; o >>= 1) s += __shfl_xor(s, o);
  if (!ln) sred[4 + w] = s;
  __syncthreads();
  float Ssum = sred[4] + sred[5] + sred[6] + sred[7];
  float inv = 1.f / Ssum;

  for (int k = tid; k < qt_end; k += 256) {
    float p = 0.f;
    if (k <= q && a[k]) p = expf((rowbuf[k] - M) * scale) * inv;
    u16 h = f2bf(p);
    Ph[rowoff + k] = h;
    Pl[rowoff + k] = f2bf(p - bf2f(h));
  }
}

// ============================================================================
// post-attention: rs += pv0+pv1 (+meanV for degenerate rows); x = split(rs)
// ============================================================================
__global__ void attn_post(float* __restrict__ rs, const float* __restrict__ pv,
                          u16* __restrict__ xh, u16* __restrict__ xl,
                          const int* __restrict__ deg, const float* __restrict__ mV) {
  long t = (long)blockIdx.x * 256 + threadIdx.x;
  long i = t << 2;
  int row = (int)(i >> 10);
  int col = (int)(i & 1023);
  int b = row >> 11;
  constexpr long PSTR = (long)BB * SSQ * HH1;
  float4 v = *(const float4*)(rs + i);
  float4 a = *(const float4*)(pv + i);
  float4 c = *(const float4*)(pv + i + PSTR);
  v.x += a.x + c.x; v.y += a.y + c.y; v.z += a.z + c.z; v.w += a.w + c.w;
  if (deg[row]) {
    const float* m = mV + (b << 10) + col;
    v.x += m[0]; v.y += m[1]; v.z += m[2]; v.w += m[3];
  }
  *(float4*)(rs + i) = v;
  ushort4 h, l;
  h.x = f2bf(v.x); l.x = f2bf(v.x - bf2f(h.x));
  h.y = f2bf(v.y); l.y = f2bf(v.y - bf2f(h.y));
  h.z = f2bf(v.z); l.z = f2bf(v.z - bf2f(h.z));
  h.w = f2bf(v.w); l.w = f2bf(v.w - bf2f(h.w));
  *(ushort4*)(xh + i) = h;
  *(ushort4*)(xl + i) = l;
}

// ============================================================================
// workspace layout (1 MB = 1<<20), ~221MB, lifetime-aliased:
//   32-96MB : QKV(h+l)+VT | Ph/Pl | dproj/mlp2 partials[4]
//   96-160MB: act-split | scores partial[2] | h(h+l) ; PV partial @128-160
// ============================================================================
constexpr size_t MB = 1u << 20;
constexpr size_t OFF_RS    = 0;
constexpr size_t OFF_XH    = 16 * MB;
constexpr size_t OFF_XL    = 24 * MB;
constexpr size_t OFF_QKVH  = 32 * MB;
constexpr size_t OFF_QKVL  = 56 * MB;
constexpr size_t OFF_PH    = 32 * MB;   // alias
constexpr size_t OFF_PL    = 48 * MB;
constexpr size_t OFF_RED   = 32 * MB;   // f32 [4][4096][1024] 64MB (alias, 32-96)
constexpr size_t OFF_VTH   = 80 * MB;
constexpr size_t OFF_VTL   = 88 * MB;
constexpr size_t OFF_SC    = 96 * MB;   // f32 [2][B][S][S] 64MB | act | h
constexpr size_t OFF_ACTH  = 96 * MB;
constexpr size_t OFF_ACTL  = 112 * MB;
constexpr size_t OFF_HH    = 96 * MB;
constexpr size_t OFF_HL    = 128 * MB;
constexpr size_t OFF_PVP   = 128 * MB;
constexpr size_t OFF_DPWH  = 160 * MB;
constexpr size_t OFF_DPWL  = 164 * MB;
constexpr size_t OFF_UPWH  = 168 * MB;
constexpr size_t OFF_UPWL  = 172 * MB;
constexpr size_t OFF_WQKVH = 176 * MB;
constexpr size_t OFF_WQKVL = 182 * MB;
constexpr size_t OFF_M1H   = 188 * MB;
constexpr size_t OFF_M1L   = 196 * MB;
constexpr size_t OFF_M2H   = 204 * MB;
constexpr size_t OFF_M2L   = 212 * MB;
constexpr size_t OFF_QKVB  = 220 * MB;
constexpr size_t OFF_MV    = OFF_QKVB + 16 * 1024;
constexpr size_t OFF_PART  = OFF_MV + 16 * 1024;
constexpr size_t OFF_DEG   = OFF_PART + 128 * 1024;

extern "C" void kernel_launch(void* const* d_in, const int* in_sizes, int n_in,
                              void* d_out, int out_size, void* d_ws, size_t ws_size,
                              hipStream_t stream) {
  (void)in_sizes; (void)n_in; (void)out_size; (void)ws_size;

  const float* z    = (const float*)d_in[0];
  const float* act0 = (const float*)d_in[1];
  const float* act1 = (const float*)d_in[2];
  const int* amask  = (const int*)d_in[3];
  const float* dpw  = (const float*)d_in[4];
  const float* dpb  = (const float*)d_in[5];
  const float* upw  = (const float*)d_in[6];
  const float* upb  = (const float*)d_in[7];
  const float* wqw  = (const float*)d_in[8];
  const float* wqb  = (const float*)d_in[9];
  const float* wkw  = (const float*)d_in[10];
  const float* wkb  = (const float*)d_in[11];
  const float* wvw  = (const float*)d_in[12];
  const float* wvb  = (const float*)d_in[13];
  const float* m1w  = (const float*)d_in[14];
  const float* m1b  = (const float*)d_in[15];
  const float* m2w  = (const float*)d_in[16];
  const float* m2b  = (const float*)d_in[17];

  char* ws = (char*)d_ws;
  float* rs    = (float*)(ws + OFF_RS);
  u16* xh      = (u16*)(ws + OFF_XH);    u16* xl    = (u16*)(ws + OFF_XL);
  u16* qkvh    = (u16*)(ws + OFF_QKVH);  u16* qkvl  = (u16*)(ws + OFF_QKVL);
  u16* Ph      = (u16*)(ws + OFF_PH);    u16* Pl    = (u16*)(ws + OFF_PL);
  float* redp  = (float*)(ws + OFF_RED);
  u16* VTh     = (u16*)(ws + OFF_VTH);   u16* VTl   = (u16*)(ws + OFF_VTL);
  float* scb   = (float*)(ws + OFF_SC);
  u16* acth    = (u16*)(ws + OFF_ACTH);  u16* actl  = (u16*)(ws + OFF_ACTL);
  u16* hh      = (u16*)(ws + OFF_HH);    u16* hl    = (u16*)(ws + OFF_HL);
  float* pvp   = (float*)(ws + OFF_PVP);
  u16* dpwh    = (u16*)(ws + OFF_DPWH);  u16* dpwl  = (u16*)(ws + OFF_DPWL);
  u16* upwh    = (u16*)(ws + OFF_UPWH);  u16* upwl  = (u16*)(ws + OFF_UPWL);
  u16* wqkvh   = (u16*)(ws + OFF_WQKVH); u16* wqkvl = (u16*)(ws + OFF_WQKVL);
  u16* m1h     = (u16*)(ws + OFF_M1H);   u16* m1l   = (u16*)(ws + OFF_M1L);
  u16* m2h     = (u16*)(ws + OFF_M2H);   u16* m2l   = (u16*)(ws + OFF_M2L);
  float* qkvb  = (float*)(ws + OFF_QKVB);
  float* mV    = (float*)(ws + OFF_MV);
  float* part  = (float*)(ws + OFF_PART);
  int* deg     = (int*)(ws + OFF_DEG);

  constexpr long RPSTR = (long)MM * HH1;

  deg_kernel<<<dim3((BB * SSQ) / 256), 256, 0, stream>>>(amask, deg);
  split_kernel<<<dim3((HH1 * HH0) / 1024), 256, 0, stream>>>(dpw, dpwh, dpwl);
  split_kernel<<<dim3((HH0 * HH1) / 1024), 256, 0, stream>>>(upw, upwh, upwl);

  // rs = dproj(act0) + b ; x = split(rs)   [big 256^2, split-K=4 + reduce]
  split_kernel<<<dim3((MM * HH0) / 1024), 256, 0, stream>>>(act0, acth, actl);
  gemm_big<0, 4><<<dim3(HH1 / 256, MM / 256, 4), 512, 0, stream>>>(
      acth, actl, HH0, dpwh, dpwl, HH0, nullptr,
      redp, nullptr, nullptr, HH1, HH0, RPSTR);
  reduce_split<4, false><<<dim3(MM * HH1 / 1024), 256, 0, stream>>>(
      redp, dpb, rs, xh, xl);

  for (int i = 0; i < NLAY; ++i) {
    split_kernel<<<dim3((HH1 * HH1) / 1024), 256, 0, stream>>>(
        wqw + (size_t)i * HH1 * HH1, wqkvh, wqkvl);
    split_kernel<<<dim3((HH1 * HH1) / 1024), 256, 0, stream>>>(
        wkw + (size_t)i * HH1 * HH1, wqkvh + HH1 * HH1, wqkvl + HH1 * HH1);
    split_kernel<<<dim3((HH1 * HH1) / 1024), 256, 0, stream>>>(
        wvw + (size_t)i * HH1 * HH1, wqkvh + 2 * HH1 * HH1, wqkvl + 2 * HH1 * HH1);
    concat_bias<<<dim3(12), 256, 0, stream>>>(wqb + i * HH1, wkb + i * HH1,
                                              wvb + i * HH1, qkvb);
    split_kernel<<<dim3((HH4 * HH1) / 1024), 256, 0, stream>>>(
        m1w + (size_t)i * HH4 * HH1, m1h, m1l);
    split_kernel<<<dim3((HH1 * HH4) / 1024), 256, 0, stream>>>(
        m2w + (size_t)i * HH1 * HH4, m2h, m2l);

    if (i == 1) {
      split_kernel<<<dim3((MM * HH0) / 1024), 256, 0, stream>>>(act1, acth, actl);
      gemm_big<0, 4><<<dim3(HH1 / 256, MM / 256, 4), 512, 0, stream>>>(
          acth, actl, HH0, dpwh, dpwl, HH0, nullptr,
          redp, nullptr, nullptr, HH1, HH0, RPSTR);
      reduce_split<4, true><<<dim3(MM * HH1 / 1024), 256, 0, stream>>>(
          redp, dpb, rs, xh, xl);
    }

    // ---- attention ----
    gemm_split<FB_BIAS | FB_SPLIT, 1><<<dim3(3072 / 128, MM / 128, 1), 256, 0, stream>>>(
        xh, xl, 0, HH1, wqkvh, wqkvl, 0, HH1, qkvb, nullptr,
        nullptr, qkvh, qkvl, 0, 3072, HH1, 0);

    transpose_v2<<<dim3(HH1 / 64, SSQ / 64, BB), 256, 0, stream>>>(
        qkvh + 2048, qkvl + 2048, 3072, VTh, VTl);
    colmean_partial<<<dim3(HH1 / 256, BB, 8), 256, 0, stream>>>(
        qkvh + 2048, qkvl + 2048, 3072, part);
    colmean_final<<<dim3((BB * HH1) / 256), 256, 0, stream>>>(part, mV);

    gemm_split<FB_CSKIP, 2><<<dim3(SSQ / 128, SSQ / 128, BB * 2), 256, 0, stream>>>(
        qkvh, qkvl, (long)SSQ * 3072, 3072, qkvh + 1024, qkvl + 1024,
        (long)SSQ * 3072, 3072, nullptr, nullptr,
        scb, nullptr, nullptr, (long)SSQ * SSQ, SSQ, HH1, (long)BB * SSQ * SSQ);

    softmax_kernel<<<dim3(SSQ, BB), 256, 0, stream>>>(scb, Ph, Pl, amask, deg);

    gemm_split<FB_CKLOOP, 2><<<dim3(HH1 / 128, SSQ / 128, BB * 2), 256, 0, stream>>>(
        Ph, Pl, (long)SSQ * SSQ, SSQ, VTh, VTl, (long)HH1 * SSQ, SSQ, nullptr, nullptr,
        pvp, nullptr, nullptr, (long)SSQ * HH1, HH1, SSQ, (long)BB * SSQ * HH1);

    attn_post<<<dim3((MM * HH1 / 4) / 256), 256, 0, stream>>>(rs, pvp, xh, xl, deg, mV);

    // ---- mlp (big 256^2 kernel) ----
    gemm_big<FB_BIAS | FB_RELU | FB_SPLIT, 1>
        <<<dim3(HH4 / 256, MM / 256, 1), 512, 0, stream>>>(
        xh, xl, HH1, m1h, m1l, HH1, m1b + i * HH4,
        nullptr, hh, hl, HH4, HH1, 0);
    gemm_big<0, 4><<<dim3(HH1 / 256, MM / 256, 4), 512, 0, stream>>>(
        hh, hl, HH4, m2h, m2l, HH4, nullptr,
        redp, nullptr, nullptr, HH1, HH4, RPSTR);
    reduce_split<4, true><<<dim3(MM * HH1 / 1024), 256, 0, stream>>>(
        redp, m2b + i * HH1, rs, xh, xl);
  }

  // out = uproj(x) + b + z   (128^2 kernel, direct epilogue)
  gemm_split<FB_BIAS | FB_RES | FB_F32, 1>
      <<<dim3(HH0 / 128, MM / 128, 1), 256, 0, stream>>>(
      xh, xl, 0, HH1, upwh, upwl, 0, HH1, upb, z,
      (float*)d_out, nullptr, nullptr, 0, HH0, HH1, 0);
}

// Round 9
// 3752.831 us; speedup vs baseline: 1.4644x; 1.0450x over previous
//
#include <hip/hip_runtime.h>
#include <cstdint>

// ============================================================================
// Ladder transformer forward on MI355X (gfx950).  Round 9.
// Decision log:
//  - R8: 3922us; 256^2 big kernel worked (mlp <100us). Top dispatch is now
//    deg_kernel (101us, O(S^2) serial scan).
//  - R9: (1) deg via first-nonzero reduce (~3us). (2) gemm_big K-step split
//    into 4 phases {2 stage-loads || ds_read A-pair -> setprio(1) -> 24 MFMA
//    -> setprio(0) -> barrier}, vmcnt(2) at phase0 only (m248v2: 8ph/2ph =
//    1.10x; T5 pays once phases create role-split). Per-acc MFMA order
//    unchanged -> bit-identical. (3) setprio in 128^2 kernel. (4) softmax
//    exp-once.
// ============================================================================

typedef unsigned short u16;
typedef __attribute__((ext_vector_type(8))) __bf16 bf16x8;
typedef __attribute__((ext_vector_type(4))) float f32x4;

#define DI __device__ __forceinline__

constexpr int BB = 2, SSQ = 2048, HH0 = 2048, HH1 = 1024, NLAY = 8, HH4 = 4096;
constexpr int MM = BB * SSQ;  // 4096 token rows

DI float bf2f(u16 h) {
  union { uint32_t u; float f; } x; x.u = ((uint32_t)h) << 16; return x.f;
}
DI u16 f2bf(float f) {
  union { float f; uint32_t u; } x; x.f = f;
  uint32_t u = x.u;
  return (u16)((u + 0x7fffu + ((u >> 16) & 1u)) >> 16);  // RTNE
}

enum {
  FB_BIAS = 1, FB_RES = 2, FB_RELU = 4, FB_F32 = 8, FB_SPLIT = 16,
  FB_CSKIP = 32, FB_CKLOOP = 64
};

#define MFMA_BF16 __builtin_amdgcn_mfma_f32_16x16x32_bf16

// ============================================================================
// 128x128 split GEMM (4 waves) — R7 structure + setprio. QKV/scores/PV/uproj.
// ============================================================================
template <int F, int KSP>
__global__ __launch_bounds__(256) void gemm_split(
    const u16* __restrict__ Ah, const u16* __restrict__ Al, long sAz, int lda,
    const u16* __restrict__ Bh, const u16* __restrict__ Bl, long sBz, int ldb,
    const float* __restrict__ bias, const float* __restrict__ resF,
    float* Cf, u16* Ch, u16* Cl, long sCz, int ldc, int K, long pstride) {
  int gx = gridDim.x, gy = gridDim.y, gz = gridDim.z;
  long o = blockIdx.x + (long)gx * (blockIdx.y + (long)gy * blockIdx.z);
  long nwg = (long)gx * gy * gz;
  long cq = nwg >> 3, cr = nwg & 7;
  long xcd = o & 7, cidx = o >> 3;
  long sl = (xcd < cr ? xcd * (cq + 1) : cr * (cq + 1) + (xcd - cr) * cq) + cidx;
  int bx = (int)(sl % gx);
  long tt = sl / gx;
  int by = (int)(tt % gy);
  int bzf = (int)(tt / gy);
  int NB = gz / KSP;
  int bz = bzf % NB;
  int ks = bzf / NB;

  if ((F & FB_CSKIP) && bx > by) return;

  __shared__ __align__(16) u16 Sbuf[2][4][128 * 32];

  int tid = threadIdx.x;
  int lane = tid & 63;
  int wave = tid >> 6;
  int wr = (wave >> 1) << 6;
  int wc = (wave & 1) << 6;
  int lrow = lane & 15;
  int kg = lane >> 4;
  int kc8 = (kg ^ ((lrow >> 1) & 3)) << 3;

  const u16* Abh = Ah + (long)bz * sAz + ((long)(by << 7)) * lda;
  const u16* Abl = Al + (long)bz * sAz + ((long)(by << 7)) * lda;
  const u16* Bbh = Bh + (long)bz * sBz + ((long)(bx << 7)) * ldb;
  const u16* Bbl = Bl + (long)bz * sBz + ((long)(bx << 7)) * ldb;

  int nKtot = (F & FB_CKLOOP) ? ((by + 1) << 2) : (K >> 5);
  int kbeg = (KSP > 1) ? (ks * nKtot) / KSP : 0;
  int kend = (KSP > 1) ? ((ks + 1) * nKtot) / KSP : nKtot;

  f32x4 acc[4][4] = {};

  auto STAGE = [&](int buf, int kt) {
    int k0 = kt << 5;
#pragma unroll
    for (int it = 0; it < 2; ++it) {
      int sidx = (it << 8) + tid;
      int r = sidx >> 2;
      int jsw = (sidx & 3) ^ ((r >> 1) & 3);
      long goff = (long)r * lda + (k0 + (jsw << 3));
      long gofB = (long)r * ldb + (k0 + (jsw << 3));
      int loff = sidx << 3;
      __builtin_amdgcn_global_load_lds(
          (__attribute__((address_space(1))) void*)(Abh + goff),
          (__attribute__((address_space(3))) void*)(&Sbuf[buf][0][loff]), 16, 0, 0);
      __builtin_amdgcn_global_load_lds(
          (__attribute__((address_space(1))) void*)(Abl + goff),
          (__attribute__((address_space(3))) void*)(&Sbuf[buf][1][loff]), 16, 0, 0);
      __builtin_amdgcn_global_load_lds(
          (__attribute__((address_space(1))) void*)(Bbh + gofB),
          (__attribute__((address_space(3))) void*)(&Sbuf[buf][2][loff]), 16, 0, 0);
      __builtin_amdgcn_global_load_lds(
          (__attribute__((address_space(1))) void*)(Bbl + gofB),
          (__attribute__((address_space(3))) void*)(&Sbuf[buf][3][loff]), 16, 0, 0);
    }
  };

  auto COMPUTE = [&](int buf) {
    bf16x8 afh[4], bfh[4], bfl[4];
#pragma unroll
    for (int mi = 0; mi < 4; ++mi)
      afh[mi] = *(const bf16x8*)&Sbuf[buf][0][((wr + (mi << 4) + lrow) << 5) + kc8];
#pragma unroll
    for (int ni = 0; ni < 4; ++ni) {
      bfh[ni] = *(const bf16x8*)&Sbuf[buf][2][((wc + (ni << 4) + lrow) << 5) + kc8];
      bfl[ni] = *(const bf16x8*)&Sbuf[buf][3][((wc + (ni << 4) + lrow) << 5) + kc8];
    }
    __builtin_amdgcn_s_setprio(1);
#pragma unroll
    for (int mi = 0; mi < 4; ++mi)
#pragma unroll
      for (int ni = 0; ni < 4; ++ni) {
        acc[mi][ni] = MFMA_BF16(afh[mi], bfh[ni], acc[mi][ni], 0, 0, 0);
        acc[mi][ni] = MFMA_BF16(afh[mi], bfl[ni], acc[mi][ni], 0, 0, 0);
      }
    __builtin_amdgcn_s_setprio(0);
    bf16x8 afl[4];
#pragma unroll
    for (int mi = 0; mi < 4; ++mi)
      afl[mi] = *(const bf16x8*)&Sbuf[buf][1][((wr + (mi << 4) + lrow) << 5) + kc8];
    __builtin_amdgcn_s_setprio(1);
#pragma unroll
    for (int mi = 0; mi < 4; ++mi)
#pragma unroll
      for (int ni = 0; ni < 4; ++ni)
        acc[mi][ni] = MFMA_BF16(afl[mi], bfh[ni], acc[mi][ni], 0, 0, 0);
    __builtin_amdgcn_s_setprio(0);
  };

  STAGE(0, kbeg);
  int cur = 0;
  for (int kt = kbeg; kt < kend; ++kt) {
    bool more = (kt + 1 < kend);
    if (more) STAGE(cur ^ 1, kt + 1);
    if (more) asm volatile("s_waitcnt vmcnt(8)" ::: "memory");
    else      asm volatile("s_waitcnt vmcnt(0)" ::: "memory");
    __builtin_amdgcn_s_barrier();
    asm volatile("" ::: "memory");
    COMPUTE(cur);
    asm volatile("" ::: "memory");
    __builtin_amdgcn_s_barrier();
    asm volatile("" ::: "memory");
    cur ^= 1;
  }

  int m0 = (by << 7) + wr + (kg << 2);
  int n0 = (bx << 7) + wc;
#pragma unroll
  for (int mi = 0; mi < 4; ++mi) {
#pragma unroll
    for (int ni = 0; ni < 4; ++ni) {
      int col = n0 + (ni << 4) + lrow;
      float bv = 0.f;
      if ((KSP == 1) && (F & FB_BIAS)) bv = bias[col];
      int rb = m0 + (mi << 4);
#pragma unroll
      for (int r = 0; r < 4; ++r) {
        float v = acc[mi][ni][r];
        long ci = (long)bz * sCz + (long)(rb + r) * ldc + col;
        if constexpr (KSP > 1) {
          Cf[(long)ks * pstride + ci] = v;
        } else {
          v += bv;
          if (F & FB_RELU) v = fmaxf(v, 0.f);
          if (F & FB_RES) v += resF[ci];
          if (F & FB_F32) Cf[ci] = v;
          if (F & FB_SPLIT) {
            u16 h = f2bf(v);
            Ch[ci] = h;
            Cl[ci] = f2bf(v - bf2f(h));
          }
        }
      }
    }
  }
}

// ============================================================================
// 256x256 split GEMM, 8 waves, BK=32, 128KB LDS. 4-phase K-step:
//   per phase: 2 stage-loads || ds_read A-pair -> prio1 -> 24 MFMA -> prio0
//   -> barrier. vmcnt(2) at phase0 (prev tile's 8 loads only). B in regs.
// ============================================================================
template <int F, int KSP>
__global__ __launch_bounds__(512, 2) void gemm_big(
    const u16* __restrict__ Ah, const u16* __restrict__ Al, int lda,
    const u16* __restrict__ Bh, const u16* __restrict__ Bl, int ldb,
    const float* __restrict__ bias,
    float* Cf, u16* Ch, u16* Cl, int ldc, int K, long pstride) {
  int gx = gridDim.x, gy = gridDim.y, gz = gridDim.z;
  long o = blockIdx.x + (long)gx * (blockIdx.y + (long)gy * blockIdx.z);
  long nwg = (long)gx * gy * gz;
  long cq = nwg >> 3, cr = nwg & 7;
  long xcd = o & 7, cidx = o >> 3;
  long sl = (xcd < cr ? xcd * (cq + 1) : cr * (cq + 1) + (xcd - cr) * cq) + cidx;
  int bx = (int)(sl % gx);
  long tt = sl / gx;
  int by = (int)(tt % gy);
  int ks = (int)(tt / gy);  // gz == KSP

  __shared__ __align__(16) u16 Sbuf[2][4][256 * 32];  // 128 KB

  int tid = threadIdx.x;
  int lane = tid & 63;
  int wave = tid >> 6;
  int wm = (wave >> 2) << 7;
  int wn = (wave & 3) << 6;
  int lrow = lane & 15;
  int kg = lane >> 4;
  int kc8 = (kg ^ ((lrow >> 1) & 3)) << 3;

  const u16* Abh = Ah + ((long)(by << 8)) * lda;
  const u16* Abl = Al + ((long)(by << 8)) * lda;
  const u16* Bbh = Bh + ((long)(bx << 8)) * ldb;
  const u16* Bbl = Bl + ((long)(bx << 8)) * ldb;

  int nKtot = K >> 5;
  int kbeg = (KSP > 1) ? (ks * nKtot) / KSP : 0;
  int kend = (KSP > 1) ? ((ks + 1) * nKtot) / KSP : nKtot;

  f32x4 acc[8][4] = {};

// one global_load_lds: IT = half (0/1), ST = stream, BASE/LD literal per call
#define LOAD1(BUF, KT, IT, ST, BASE, LD) do {                                  \
    int sidx_ = ((IT) << 9) + tid;                                             \
    int r_ = sidx_ >> 2;                                                       \
    int jsw_ = (sidx_ & 3) ^ ((r_ >> 1) & 3);                                  \
    long off_ = (long)r_ * (LD) + (((KT) << 5) + (jsw_ << 3));                 \
    __builtin_amdgcn_global_load_lds(                                          \
        (__attribute__((address_space(1))) void*)((BASE) + off_),              \
        (__attribute__((address_space(3))) void*)(&Sbuf[BUF][ST][sidx_ << 3]), \
        16, 0, 0);                                                             \
  } while (0)

// MFMA phase: mi pair {MI0, MI0+1} x 4 ni x 3 terms (per-acc order hh,hl,lh)
#define PHASE_MFMA(BUF, MI0) do {                                              \
    int a0r_ = ((wm + ((MI0) << 4) + lrow) << 5) + kc8;                        \
    int a1r_ = ((wm + (((MI0) + 1) << 4) + lrow) << 5) + kc8;                  \
    bf16x8 a0h_ = *(const bf16x8*)&Sbuf[BUF][0][a0r_];                         \
    bf16x8 a0l_ = *(const bf16x8*)&Sbuf[BUF][1][a0r_];                         \
    bf16x8 a1h_ = *(const bf16x8*)&Sbuf[BUF][0][a1r_];                         \
    bf16x8 a1l_ = *(const bf16x8*)&Sbuf[BUF][1][a1r_];                         \
    __builtin_amdgcn_s_setprio(1);                                             \
    _Pragma("unroll")                                                          \
    for (int ni = 0; ni < 4; ++ni) {                                           \
      acc[MI0][ni]     = MFMA_BF16(a0h_, bfh[ni], acc[MI0][ni], 0, 0, 0);      \
      acc[MI0][ni]     = MFMA_BF16(a0h_, bfl[ni], acc[MI0][ni], 0, 0, 0);      \
      acc[MI0][ni]     = MFMA_BF16(a0l_, bfh[ni], acc[MI0][ni], 0, 0, 0);      \
      acc[MI0 + 1][ni] = MFMA_BF16(a1h_, bfh[ni], acc[MI0 + 1][ni], 0, 0, 0);  \
      acc[MI0 + 1][ni] = MFMA_BF16(a1h_, bfl[ni], acc[MI0 + 1][ni], 0, 0, 0);  \
      acc[MI0 + 1][ni] = MFMA_BF16(a1l_, bfh[ni], acc[MI0 + 1][ni], 0, 0, 0);  \
    }                                                                          \
    __builtin_amdgcn_s_setprio(0);                                             \
  } while (0)

#define BAR() do {                                                             \
    asm volatile("" ::: "memory");                                             \
    __builtin_amdgcn_s_barrier();                                              \
    asm volatile("" ::: "memory");                                             \
  } while (0)

  // prologue: 8 loads for first tile
  {
    LOAD1(0, kbeg, 0, 0, Abh, lda); LOAD1(0, kbeg, 0, 1, Abl, lda);
    LOAD1(0, kbeg, 0, 2, Bbh, ldb); LOAD1(0, kbeg, 0, 3, Bbl, ldb);
    LOAD1(0, kbeg, 1, 0, Abh, lda); LOAD1(0, kbeg, 1, 1, Abl, lda);
    LOAD1(0, kbeg, 1, 2, Bbh, ldb); LOAD1(0, kbeg, 1, 3, Bbl, ldb);
  }
  int cur = 0;
  for (int kt = kbeg; kt < kend; ++kt) {
    bool more = (kt + 1 < kend);
    int nb = cur ^ 1, kt1 = kt + 1;
    bf16x8 bfh[4], bfl[4];
    // ---- phase 0 ----
    if (more) { LOAD1(nb, kt1, 0, 0, Abh, lda); LOAD1(nb, kt1, 0, 1, Abl, lda); }
    if (more) asm volatile("s_waitcnt vmcnt(2)" ::: "memory");
    else      asm volatile("s_waitcnt vmcnt(0)" ::: "memory");
    BAR();
#pragma unroll
    for (int ni = 0; ni < 4; ++ni) {
      int brow = (wn + (ni << 4) + lrow) << 5;
      bfh[ni] = *(const bf16x8*)&Sbuf[cur][2][brow + kc8];
      bfl[ni] = *(const bf16x8*)&Sbuf[cur][3][brow + kc8];
    }
    PHASE_MFMA(cur, 0);
    BAR();
    // ---- phase 1 ----
    if (more) { LOAD1(nb, kt1, 0, 2, Bbh, ldb); LOAD1(nb, kt1, 0, 3, Bbl, ldb); }
    PHASE_MFMA(cur, 2);
    BAR();
    // ---- phase 2 ----
    if (more) { LOAD1(nb, kt1, 1, 0, Abh, lda); LOAD1(nb, kt1, 1, 1, Abl, lda); }
    PHASE_MFMA(cur, 4);
    BAR();
    // ---- phase 3 ----
    if (more) { LOAD1(nb, kt1, 1, 2, Bbh, ldb); LOAD1(nb, kt1, 1, 3, Bbl, ldb); }
    PHASE_MFMA(cur, 6);
    BAR();
    cur ^= 1;
  }
#undef LOAD1
#undef PHASE_MFMA
#undef BAR

  int m0 = (by << 8) + wm + (kg << 2);
  int n0 = (bx << 8) + wn;
#pragma unroll
  for (int mi = 0; mi < 8; ++mi) {
#pragma unroll
    for (int ni = 0; ni < 4; ++ni) {
      int col = n0 + (ni << 4) + lrow;
      float bv = 0.f;
      if ((KSP == 1) && (F & FB_BIAS)) bv = bias[col];
      int rb = m0 + (mi << 4);
#pragma unroll
      for (int r = 0; r < 4; ++r) {
        float v = acc[mi][ni][r];
        long ci = (long)(rb + r) * ldc + col;
        if constexpr (KSP > 1) {
          Cf[(long)ks * pstride + ci] = v;
        } else {
          v += bv;
          if (F & FB_RELU) v = fmaxf(v, 0.f);
          if (F & FB_F32) Cf[ci] = v;
          if (F & FB_SPLIT) {
            u16 h = f2bf(v);
            Ch[ci] = h;
            Cl[ci] = f2bf(v - bf2f(h));
          }
        }
      }
    }
  }
}

// ============================================================================
// reduce for split-K N=1024 GEMMs: v = sum_j p_j + bias (+rs); rs=v; x=split
// ============================================================================
template <int KSP, bool RES>
__global__ void reduce_split(const float* __restrict__ p,
                             const float* __restrict__ bias,
                             float* __restrict__ rs, u16* __restrict__ xh,
                             u16* __restrict__ xl) {
  long i = ((long)blockIdx.x * 256 + threadIdx.x) << 2;
  int col = (int)(i & 1023);
  constexpr long PSTR = (long)MM * HH1;
  float4 v;
  v.x = bias[col]; v.y = bias[col + 1]; v.z = bias[col + 2]; v.w = bias[col + 3];
#pragma unroll
  for (int j = 0; j < KSP; ++j) {
    float4 a = *(const float4*)(p + i + j * PSTR);
    v.x += a.x; v.y += a.y; v.z += a.z; v.w += a.w;
  }
  if (RES) {
    float4 r0 = *(const float4*)(rs + i);
    v.x += r0.x; v.y += r0.y; v.z += r0.z; v.w += r0.w;
  }
  *(float4*)(rs + i) = v;
  ushort4 h, l;
  h.x = f2bf(v.x); l.x = f2bf(v.x - bf2f(h.x));
  h.y = f2bf(v.y); l.y = f2bf(v.y - bf2f(h.y));
  h.z = f2bf(v.z); l.z = f2bf(v.z - bf2f(h.z));
  h.w = f2bf(v.w); l.w = f2bf(v.w - bf2f(h.w));
  *(ushort4*)(xh + i) = h;
  *(ushort4*)(xl + i) = l;
}

// ============================================================================
// elementwise split: f32 -> (hi, lo) bf16
// ============================================================================
__global__ void split_kernel(const float* __restrict__ src, u16* __restrict__ hi,
                             u16* __restrict__ lo) {
  long i = ((long)blockIdx.x * 256 + threadIdx.x) << 2;
  float4 v = *(const float4*)(src + i);
  ushort4 h, l;
  h.x = f2bf(v.x); l.x = f2bf(v.x - bf2f(h.x));
  h.y = f2bf(v.y); l.y = f2bf(v.y - bf2f(h.y));
  h.z = f2bf(v.z); l.z = f2bf(v.z - bf2f(h.z));
  h.w = f2bf(v.w); l.w = f2bf(v.w - bf2f(h.w));
  *(ushort4*)(hi + i) = h;
  *(ushort4*)(lo + i) = l;
}

__global__ void concat_bias(const float* __restrict__ qb, const float* __restrict__ kb,
                            const float* __restrict__ vb, float* __restrict__ dst) {
  int j = blockIdx.x * 256 + threadIdx.x;
  float v = (j < 1024) ? qb[j] : ((j < 2048) ? kb[j - 1024] : vb[j - 2048]);
  dst[j] = v;
}

// ============================================================================
// deg: deg[b][q] = 1 iff q < (first k with attmask[b][k]!=0).
// One block per batch: parallel min-index reduce, broadcast write.
// ============================================================================
__global__ void deg_kernel(const int* __restrict__ am, int* __restrict__ deg) {
  int b = blockIdx.x;
  const int* a = am + b * SSQ;
  int tid = threadIdx.x;
  int fz = SSQ;
  for (int k = tid; k < SSQ; k += 256)
    if (a[k] != 0) fz = min(fz, k);
#pragma unroll
  for (int o = 32; o; o >>= 1) fz = min(fz, __shfl_xor(fz, o));
  __shared__ int red[4];
  if ((tid & 63) == 0) red[tid >> 6] = fz;
  __syncthreads();
  int f = min(min(red[0], red[1]), min(red[2], red[3]));
  for (int q = tid; q < SSQ; q += 256) deg[b * SSQ + q] = (q < f) ? 1 : 0;
}

// ============================================================================
// fused hi/lo transpose: VT[b][n][k] = V[b*S+k][n], V leading dim sld
// ============================================================================
__global__ void transpose_v2(const u16* __restrict__ Vh, const u16* __restrict__ Vl,
                             int sld, u16* __restrict__ VTh, u16* __restrict__ VTl) {
  __shared__ u16 th[64][68];
  __shared__ u16 tl[64][68];
  int b = blockIdx.z;
  int c0 = blockIdx.x << 6;
  int r0 = blockIdx.y << 6;
  int tr = threadIdx.x >> 4, tc = threadIdx.x & 15;
  long sbase = ((long)(b * SSQ + r0)) * sld + c0;
#pragma unroll
  for (int j = 0; j < 4; ++j) {
    int r = (j << 4) + tr;
    ushort4 uh = *(const ushort4*)(Vh + sbase + (long)r * sld + (tc << 2));
    ushort4 ul = *(const ushort4*)(Vl + sbase + (long)r * sld + (tc << 2));
    th[r][(tc << 2) + 0] = uh.x; th[r][(tc << 2) + 1] = uh.y;
    th[r][(tc << 2) + 2] = uh.z; th[r][(tc << 2) + 3] = uh.w;
    tl[r][(tc << 2) + 0] = ul.x; tl[r][(tc << 2) + 1] = ul.y;
    tl[r][(tc << 2) + 2] = ul.z; tl[r][(tc << 2) + 3] = ul.w;
  }
  __syncthreads();
  long dbase = ((long)b * HH1 + c0) * SSQ + r0;
#pragma unroll
  for (int j = 0; j < 4; ++j) {
    int c = (j << 4) + tr;
    ushort4 uh, ul;
    uh.x = th[(tc << 2) + 0][c]; uh.y = th[(tc << 2) + 1][c];
    uh.z = th[(tc << 2) + 2][c]; uh.w = th[(tc << 2) + 3][c];
    ul.x = tl[(tc << 2) + 0][c]; ul.y = tl[(tc << 2) + 1][c];
    ul.z = tl[(tc << 2) + 2][c]; ul.w = tl[(tc << 2) + 3][c];
    *(ushort4*)(VTh + dbase + (long)c * SSQ + (tc << 2)) = uh;
    *(ushort4*)(VTl + dbase + (long)c * SSQ + (tc << 2)) = ul;
  }
}

// ============================================================================
// column mean of V (degenerate rows); V hi/lo with leading dim ld
// ============================================================================
__global__ void colmean_partial(const u16* __restrict__ Vh, const u16* __restrict__ Vl,
                                int ld, float* __restrict__ part) {
  int n = blockIdx.x * 256 + threadIdx.x;
  int b = blockIdx.y, kc = blockIdx.z;
  long base = ((long)(b * SSQ + kc * 256)) * ld + n;
  float s = 0.f;
  for (int k = 0; k < 256; ++k) {
    long o = base + (long)k * ld;
    s += bf2f(Vh[o]) + bf2f(Vl[o]);
  }
  part[((kc * BB) + b) * HH1 + n] = s;
}
__global__ void colmean_final(const float* __restrict__ part, float* __restrict__ mV) {
  int i = blockIdx.x * 256 + threadIdx.x;
  int b = i >> 10, n = i & 1023;
  float s = 0.f;
  for (int kc = 0; kc < 8; ++kc) s += part[((kc * BB) + b) * HH1 + n];
  mV[i] = s * (1.f / (float)SSQ);
}

// ============================================================================
// row softmax: sums two score partials into LDS, exp computed once (stored
// back into rowbuf; each thread touches only its own slots).
// ============================================================================
__global__ void softmax_kernel(const float* __restrict__ sc, u16* __restrict__ Ph,
                               u16* __restrict__ Pl, const int* __restrict__ am,
                               const int* __restrict__ deg) {
  int q = blockIdx.x, b = blockIdx.y;
  int tid = threadIdx.x;
  long rowoff = ((long)b * SSQ + q) * SSQ;
  int qt_end = ((q >> 7) + 1) << 7;
  if (deg[b * SSQ + q]) {
    for (int k = tid; k < qt_end; k += 256) { Ph[rowoff + k] = 0; Pl[rowoff + k] = 0; }
    return;
  }
  const int* a = am + b * SSQ;
  const float scale = 0.03125f;  // 1/sqrt(1024)
  constexpr long PSTR = (long)BB * SSQ * SSQ;
  __shared__ float rowbuf[2048];
  __shared__ float sred[8];
  int w = tid >> 6, ln = tid & 63;

  for (int k = tid; k < qt_end; k += 256)
    rowbuf[k] = sc[rowoff + k] + sc[rowoff + k + PSTR];
  __syncthreads();

  float m = -1e30f;
  for (int k = tid; k <= q; k += 256)
    if (a[k]) m = fmaxf(m, rowbuf[k]);
#pragma unroll
  for (int o = 32; o; o >>= 1) m = fmaxf(m, __shfl_xor(m, o));
  if (!ln) sred[w] = m;
  __syncthreads();
  float M = fmaxf(fmaxf(sred[0], sred[1]), fmaxf(sred[2], sred[3]));

  float s = 0.f;
  for (int k = tid; k < qt_end; k += 256) {
    float p = 0.f;
    if (k <= q && a[k]) p = expf((rowbuf[k] - M) * scale);
    rowbuf[k] = p;  // own slots only
    s += p;
  }
#pragma unroll
  for (int o = 32; o; o >>= 1) s += __shfl_xor(s, o);
  if (!ln) sred[4 + w] = s;
  __syncthreads();
  float Ssum = sred[4] + sred[5] + sred[6] + sred[7];
  float inv = 1.f / Ssum;

  for (int k = tid; k < qt_end; k += 256) {
    float p = rowbuf[k] * inv;
    u16 h = f2bf(p);
    Ph[rowoff + k] = h;
    Pl[rowoff + k] = f2bf(p - bf2f(h));
  }
}

// ============================================================================
// post-attention: rs += pv0+pv1 (+meanV for degenerate rows); x = split(rs)
// ============================================================================
__global__ void attn_post(float* __restrict__ rs, const float* __restrict__ pv,
                          u16* __restrict__ xh, u16* __restrict__ xl,
                          const int* __restrict__ deg, const float* __restrict__ mV) {
  long t = (long)blockIdx.x * 256 + threadIdx.x;
  long i = t << 2;
  int row = (int)(i >> 10);
  int col = (int)(i & 1023);
  int b = row >> 11;
  constexpr long PSTR = (long)BB * SSQ * HH1;
  float4 v = *(const float4*)(rs + i);
  float4 a = *(const float4*)(pv + i);
  float4 c = *(const float4*)(pv + i + PSTR);
  v.x += a.x + c.x; v.y += a.y + c.y; v.z += a.z + c.z; v.w += a.w + c.w;
  if (deg[row]) {
    const float* m = mV + (b << 10) + col;
    v.x += m[0]; v.y += m[1]; v.z += m[2]; v.w += m[3];
  }
  *(float4*)(rs + i) = v;
  ushort4 h, l;
  h.x = f2bf(v.x); l.x = f2bf(v.x - bf2f(h.x));
  h.y = f2bf(v.y); l.y = f2bf(v.y - bf2f(h.y));
  h.z = f2bf(v.z); l.z = f2bf(v.z - bf2f(h.z));
  h.w = f2bf(v.w); l.w = f2bf(v.w - bf2f(h.w));
  *(ushort4*)(xh + i) = h;
  *(ushort4*)(xl + i) = l;
}

// ============================================================================
// workspace layout (1 MB = 1<<20), ~221MB, lifetime-aliased (see R4-R8 logs)
// ============================================================================
constexpr size_t MB = 1u << 20;
constexpr size_t OFF_RS    = 0;
constexpr size_t OFF_XH    = 16 * MB;
constexpr size_t OFF_XL    = 24 * MB;
constexpr size_t OFF_QKVH  = 32 * MB;
constexpr size_t OFF_QKVL  = 56 * MB;
constexpr size_t OFF_PH    = 32 * MB;   // alias
constexpr size_t OFF_PL    = 48 * MB;
constexpr size_t OFF_RED   = 32 * MB;   // f32 [4][4096][1024] 64MB (alias)
constexpr size_t OFF_VTH   = 80 * MB;
constexpr size_t OFF_VTL   = 88 * MB;
constexpr size_t OFF_SC    = 96 * MB;   // f32 [2][B][S][S] | act | h
constexpr size_t OFF_ACTH  = 96 * MB;
constexpr size_t OFF_ACTL  = 112 * MB;
constexpr size_t OFF_HH    = 96 * MB;
constexpr size_t OFF_HL    = 128 * MB;
constexpr size_t OFF_PVP   = 128 * MB;
constexpr size_t OFF_DPWH  = 160 * MB;
constexpr size_t OFF_DPWL  = 164 * MB;
constexpr size_t OFF_UPWH  = 168 * MB;
constexpr size_t OFF_UPWL  = 172 * MB;
constexpr size_t OFF_WQKVH = 176 * MB;
constexpr size_t OFF_WQKVL = 182 * MB;
constexpr size_t OFF_M1H   = 188 * MB;
constexpr size_t OFF_M1L   = 196 * MB;
constexpr size_t OFF_M2H   = 204 * MB;
constexpr size_t OFF_M2L   = 212 * MB;
constexpr size_t OFF_QKVB  = 220 * MB;
constexpr size_t OFF_MV    = OFF_QKVB + 16 * 1024;
constexpr size_t OFF_PART  = OFF_MV + 16 * 1024;
constexpr size_t OFF_DEG   = OFF_PART + 128 * 1024;

extern "C" void kernel_launch(void* const* d_in, const int* in_sizes, int n_in,
                              void* d_out, int out_size, void* d_ws, size_t ws_size,
                              hipStream_t stream) {
  (void)in_sizes; (void)n_in; (void)out_size; (void)ws_size;

  const float* z    = (const float*)d_in[0];
  const float* act0 = (const float*)d_in[1];
  const float* act1 = (const float*)d_in[2];
  const int* amask  = (const int*)d_in[3];
  const float* dpw  = (const float*)d_in[4];
  const float* dpb  = (const float*)d_in[5];
  const float* upw  = (const float*)d_in[6];
  const float* upb  = (const float*)d_in[7];
  const float* wqw  = (const float*)d_in[8];
  const float* wqb  = (const float*)d_in[9];
  const float* wkw  = (const float*)d_in[10];
  const float* wkb  = (const float*)d_in[11];
  const float* wvw  = (const float*)d_in[12];
  const float* wvb  = (const float*)d_in[13];
  const float* m1w  = (const float*)d_in[14];
  const float* m1b  = (const float*)d_in[15];
  const float* m2w  = (const float*)d_in[16];
  const float* m2b  = (const float*)d_in[17];

  char* ws = (char*)d_ws;
  float* rs    = (float*)(ws + OFF_RS);
  u16* xh      = (u16*)(ws + OFF_XH);    u16* xl    = (u16*)(ws + OFF_XL);
  u16* qkvh    = (u16*)(ws + OFF_QKVH);  u16* qkvl  = (u16*)(ws + OFF_QKVL);
  u16* Ph      = (u16*)(ws + OFF_PH);    u16* Pl    = (u16*)(ws + OFF_PL);
  float* redp  = (float*)(ws + OFF_RED);
  u16* VTh     = (u16*)(ws + OFF_VTH);   u16* VTl   = (u16*)(ws + OFF_VTL);
  float* scb   = (float*)(ws + OFF_SC);
  u16* acth    = (u16*)(ws + OFF_ACTH);  u16* actl  = (u16*)(ws + OFF_ACTL);
  u16* hh      = (u16*)(ws + OFF_HH);    u16* hl    = (u16*)(ws + OFF_HL);
  float* pvp   = (float*)(ws + OFF_PVP);
  u16* dpwh    = (u16*)(ws + OFF_DPWH);  u16* dpwl  = (u16*)(ws + OFF_DPWL);
  u16* upwh    = (u16*)(ws + OFF_UPWH);  u16* upwl  = (u16*)(ws + OFF_UPWL);
  u16* wqkvh   = (u16*)(ws + OFF_WQKVH); u16* wqkvl = (u16*)(ws + OFF_WQKVL);
  u16* m1h     = (u16*)(ws + OFF_M1H);   u16* m1l   = (u16*)(ws + OFF_M1L);
  u16* m2h     = (u16*)(ws + OFF_M2H);   u16* m2l   = (u16*)(ws + OFF_M2L);
  float* qkvb  = (float*)(ws + OFF_QKVB);
  float* mV    = (float*)(ws + OFF_MV);
  float* part  = (float*)(ws + OFF_PART);
  int* deg     = (int*)(ws + OFF_DEG);

  constexpr long RPSTR = (long)MM * HH1;

  deg_kernel<<<dim3(BB), 256, 0, stream>>>(amask, deg);
  split_kernel<<<dim3((HH1 * HH0) / 1024), 256, 0, stream>>>(dpw, dpwh, dpwl);
  split_kernel<<<dim3((HH0 * HH1) / 1024), 256, 0, stream>>>(upw, upwh, upwl);

  // rs = dproj(act0) + b ; x = split(rs)   [big 256^2, split-K=4 + reduce]
  split_kernel<<<dim3((MM * HH0) / 1024), 256, 0, stream>>>(act0, acth, actl);
  gemm_big<0, 4><<<dim3(HH1 / 256, MM / 256, 4), 512, 0, stream>>>(
      acth, actl, HH0, dpwh, dpwl, HH0, nullptr,
      redp, nullptr, nullptr, HH1, HH0, RPSTR);
  reduce_split<4, false><<<dim3(MM * HH1 / 1024), 256, 0, stream>>>(
      redp, dpb, rs, xh, xl);

  for (int i = 0; i < NLAY; ++i) {
    split_kernel<<<dim3((HH1 * HH1) / 1024), 256, 0, stream>>>(
        wqw + (size_t)i * HH1 * HH1, wqkvh, wqkvl);
    split_kernel<<<dim3((HH1 * HH1) / 1024), 256, 0, stream>>>(
        wkw + (size_t)i * HH1 * HH1, wqkvh + HH1 * HH1, wqkvl + HH1 * HH1);
    split_kernel<<<dim3((HH1 * HH1) / 1024), 256, 0, stream>>>(
        wvw + (size_t)i * HH1 * HH1, wqkvh + 2 * HH1 * HH1, wqkvl + 2 * HH1 * HH1);
    concat_bias<<<dim3(12), 256, 0, stream>>>(wqb + i * HH1, wkb + i * HH1,
                                              wvb + i * HH1, qkvb);
    split_kernel<<<dim3((HH4 * HH1) / 1024), 256, 0, stream>>>(
        m1w + (size_t)i * HH4 * HH1, m1h, m1l);
    split_kernel<<<dim3((HH1 * HH4) / 1024), 256, 0, stream>>>(
        m2w + (size_t)i * HH1 * HH4, m2h, m2l);

    if (i == 1) {
      split_kernel<<<dim3((MM * HH0) / 1024), 256, 0, stream>>>(act1, acth, actl);
      gemm_big<0, 4><<<dim3(HH1 / 256, MM / 256, 4), 512, 0, stream>>>(
          acth, actl, HH0, dpwh, dpwl, HH0, nullptr,
          redp, nullptr, nullptr, HH1, HH0, RPSTR);
      reduce_split<4, true><<<dim3(MM * HH1 / 1024), 256, 0, stream>>>(
          redp, dpb, rs, xh, xl);
    }

    // ---- attention ----
    gemm_split<FB_BIAS | FB_SPLIT, 1><<<dim3(3072 / 128, MM / 128, 1), 256, 0, stream>>>(
        xh, xl, 0, HH1, wqkvh, wqkvl, 0, HH1, qkvb, nullptr,
        nullptr, qkvh, qkvl, 0, 3072, HH1, 0);

    transpose_v2<<<dim3(HH1 / 64, SSQ / 64, BB), 256, 0, stream>>>(
        qkvh + 2048, qkvl + 2048, 3072, VTh, VTl);
    colmean_partial<<<dim3(HH1 / 256, BB, 8), 256, 0, stream>>>(
        qkvh + 2048, qkvl + 2048, 3072, part);
    colmean_final<<<dim3((BB * HH1) / 256), 256, 0, stream>>>(part, mV);

    gemm_split<FB_CSKIP, 2><<<dim3(SSQ / 128, SSQ / 128, BB * 2), 256, 0, stream>>>(
        qkvh, qkvl, (long)SSQ * 3072, 3072, qkvh + 1024, qkvl + 1024,
        (long)SSQ * 3072, 3072, nullptr, nullptr,
        scb, nullptr, nullptr, (long)SSQ * SSQ, SSQ, HH1, (long)BB * SSQ * SSQ);

    softmax_kernel<<<dim3(SSQ, BB), 256, 0, stream>>>(scb, Ph, Pl, amask, deg);

    gemm_split<FB_CKLOOP, 2><<<dim3(HH1 / 128, SSQ / 128, BB * 2), 256, 0, stream>>>(
        Ph, Pl, (long)SSQ * SSQ, SSQ, VTh, VTl, (long)HH1 * SSQ, SSQ, nullptr, nullptr,
        pvp, nullptr, nullptr, (long)SSQ * HH1, HH1, SSQ, (long)BB * SSQ * HH1);

    attn_post<<<dim3((MM * HH1 / 4) / 256), 256, 0, stream>>>(rs, pvp, xh, xl, deg, mV);

    // ---- mlp (big 256^2 kernel) ----
    gemm_big<FB_BIAS | FB_RELU | FB_SPLIT, 1>
        <<<dim3(HH4 / 256, MM / 256, 1), 512, 0, stream>>>(
        xh, xl, HH1, m1h, m1l, HH1, m1b + i * HH4,
        nullptr, hh, hl, HH4, HH1, 0);
    gemm_big<0, 4><<<dim3(HH1 / 256, MM / 256, 4), 512, 0, stream>>>(
        hh, hl, HH4, m2h, m2l, HH4, nullptr,
        redp, nullptr, nullptr, HH1, HH4, RPSTR);
    reduce_split<4, true><<<dim3(MM * HH1 / 1024), 256, 0, stream>>>(
        redp, m2b + i * HH1, rs, xh, xl);
  }

  // out = uproj(x) + b + z   (128^2 kernel, direct epilogue)
  gemm_split<FB_BIAS | FB_RES | FB_F32, 1>
      <<<dim3(HH0 / 128, MM / 128, 1), 256, 0, stream>>>(
      xh, xl, 0, HH1, upwh, upwl, 0, HH1, upb, z,
      (float*)d_out, nullptr, nullptr, 0, HH0, HH1, 0);
}

// Round 12
// 3677.775 us; speedup vs baseline: 1.4943x; 1.0204x over previous
//
#include <hip/hip_runtime.h>
#include <cstdint>

// ============================================================================
// Ladder transformer forward on MI355X (gfx950).  Round 12.
// Decision log:
//  - R10/R11 FAILED: P-single + h-single inject ~0.83 absmax (softmax
//    amplifies residual noise ~2x/layer; any >=2^-9-relative cut on the
//    residual path fails). REVERT to full R9 numerics: 3-term everywhere,
//    P hi/lo, h hi/lo. Guaranteed absmax 0.125.
//  - Perf (zero numerics risk): fuse per-layer weight splits+bias concat
//    (6 dispatches) into ONE layer_split kernel; fuse init splits. Removes
//    41 dispatches (~100us).
//  - GEMM paths identical to R9's measured binaries (AS=BS=true).
// ============================================================================

typedef unsigned short u16;
typedef __attribute__((ext_vector_type(8))) __bf16 bf16x8;
typedef __attribute__((ext_vector_type(4))) float f32x4;

#define DI __device__ __forceinline__

constexpr int BB = 2, SSQ = 2048, HH0 = 2048, HH1 = 1024, NLAY = 8, HH4 = 4096;
constexpr int MM = BB * SSQ;  // 4096 token rows

DI float bf2f(u16 h) {
  union { uint32_t u; float f; } x; x.u = ((uint32_t)h) << 16; return x.f;
}
DI u16 f2bf(float f) {
  union { float f; uint32_t u; } x; x.f = f;
  uint32_t u = x.u;
  return (u16)((u + 0x7fffu + ((u >> 16) & 1u)) >> 16);  // RTNE
}

enum {
  FB_BIAS = 1, FB_RES = 2, FB_RELU = 4, FB_F32 = 8, FB_SPLIT = 16,
  FB_CSKIP = 32, FB_CKLOOP = 64
};

#define MFMA_BF16 __builtin_amdgcn_mfma_f32_16x16x32_bf16

// ============================================================================
// 128x128 split GEMM (4 waves). AS/BS: A/B operand has a lo stream.
// Terms per acc (order fixed): Ah*Bh, [Ah*Bl if BS], [Al*Bh if AS].
// dbuf + counted vmcnt + raw barriers (R7 schedule).
// ============================================================================
template <int F, int KSP, bool AS, bool BS>
__global__ __launch_bounds__(256) void gemm_split(
    const u16* __restrict__ Ah, const u16* __restrict__ Al, long sAz, int lda,
    const u16* __restrict__ Bh, const u16* __restrict__ Bl, long sBz, int ldb,
    const float* __restrict__ bias, const float* __restrict__ resF,
    float* Cf, u16* Ch, u16* Cl, long sCz, int ldc, int K, long pstride) {
  int gx = gridDim.x, gy = gridDim.y, gz = gridDim.z;
  long o = blockIdx.x + (long)gx * (blockIdx.y + (long)gy * blockIdx.z);
  long nwg = (long)gx * gy * gz;
  long cq = nwg >> 3, cr = nwg & 7;
  long xcd = o & 7, cidx = o >> 3;
  long sl = (xcd < cr ? xcd * (cq + 1) : cr * (cq + 1) + (xcd - cr) * cq) + cidx;
  int bx = (int)(sl % gx);
  long tt = sl / gx;
  int by = (int)(tt % gy);
  int bzf = (int)(tt / gy);
  int NB = gz / KSP;
  int bz = bzf % NB;
  int ks = bzf / NB;

  if ((F & FB_CSKIP) && bx > by) return;

  constexpr int SAH = 0;
  constexpr int SAL = 1;                // valid if AS
  constexpr int SBH = 1 + (AS ? 1 : 0);
  constexpr int SBL = SBH + 1;          // valid if BS
  constexpr int NST = 2 + (AS ? 1 : 0) + (BS ? 1 : 0);

  __shared__ __align__(16) u16 Sbuf[2][NST][128 * 32];

  int tid = threadIdx.x;
  int lane = tid & 63;
  int wave = tid >> 6;
  int wr = (wave >> 1) << 6;
  int wc = (wave & 1) << 6;
  int lrow = lane & 15;
  int kg = lane >> 4;
  int kc8 = (kg ^ ((lrow >> 1) & 3)) << 3;

  const u16* Abh = Ah + (long)bz * sAz + ((long)(by << 7)) * lda;
  const u16* Abl = AS ? (Al + (long)bz * sAz + ((long)(by << 7)) * lda) : nullptr;
  const u16* Bbh = Bh + (long)bz * sBz + ((long)(bx << 7)) * ldb;
  const u16* Bbl = BS ? (Bl + (long)bz * sBz + ((long)(bx << 7)) * ldb) : nullptr;

  int nKtot = (F & FB_CKLOOP) ? ((by + 1) << 2) : (K >> 5);
  int kbeg = (KSP > 1) ? (ks * nKtot) / KSP : 0;
  int kend = (KSP > 1) ? ((ks + 1) * nKtot) / KSP : nKtot;

  f32x4 acc[4][4] = {};

  auto STAGE = [&](int buf, int kt) {
    int k0 = kt << 5;
#pragma unroll
    for (int it = 0; it < 2; ++it) {
      int sidx = (it << 8) + tid;
      int r = sidx >> 2;
      int jsw = (sidx & 3) ^ ((r >> 1) & 3);
      long goff = (long)r * lda + (k0 + (jsw << 3));
      long gofB = (long)r * ldb + (k0 + (jsw << 3));
      int loff = sidx << 3;
      __builtin_amdgcn_global_load_lds(
          (__attribute__((address_space(1))) void*)(Abh + goff),
          (__attribute__((address_space(3))) void*)(&Sbuf[buf][SAH][loff]), 16, 0, 0);
      if constexpr (AS)
        __builtin_amdgcn_global_load_lds(
            (__attribute__((address_space(1))) void*)(Abl + goff),
            (__attribute__((address_space(3))) void*)(&Sbuf[buf][SAL][loff]), 16, 0, 0);
      __builtin_amdgcn_global_load_lds(
          (__attribute__((address_space(1))) void*)(Bbh + gofB),
          (__attribute__((address_space(3))) void*)(&Sbuf[buf][SBH][loff]), 16, 0, 0);
      if constexpr (BS)
        __builtin_amdgcn_global_load_lds(
            (__attribute__((address_space(1))) void*)(Bbl + gofB),
            (__attribute__((address_space(3))) void*)(&Sbuf[buf][SBL][loff]), 16, 0, 0);
    }
  };

  auto COMPUTE = [&](int buf) {
    bf16x8 afh[4], bfh[4], bfl[4];
#pragma unroll
    for (int mi = 0; mi < 4; ++mi)
      afh[mi] = *(const bf16x8*)&Sbuf[buf][SAH][((wr + (mi << 4) + lrow) << 5) + kc8];
#pragma unroll
    for (int ni = 0; ni < 4; ++ni) {
      bfh[ni] = *(const bf16x8*)&Sbuf[buf][SBH][((wc + (ni << 4) + lrow) << 5) + kc8];
      if constexpr (BS)
        bfl[ni] = *(const bf16x8*)&Sbuf[buf][SBL][((wc + (ni << 4) + lrow) << 5) + kc8];
    }
    __builtin_amdgcn_s_setprio(1);
#pragma unroll
    for (int mi = 0; mi < 4; ++mi)
#pragma unroll
      for (int ni = 0; ni < 4; ++ni) {
        acc[mi][ni] = MFMA_BF16(afh[mi], bfh[ni], acc[mi][ni], 0, 0, 0);
        if constexpr (BS)
          acc[mi][ni] = MFMA_BF16(afh[mi], bfl[ni], acc[mi][ni], 0, 0, 0);
      }
    __builtin_amdgcn_s_setprio(0);
    if constexpr (AS) {
      bf16x8 afl[4];
#pragma unroll
      for (int mi = 0; mi < 4; ++mi)
        afl[mi] = *(const bf16x8*)&Sbuf[buf][SAL][((wr + (mi << 4) + lrow) << 5) + kc8];
      __builtin_amdgcn_s_setprio(1);
#pragma unroll
      for (int mi = 0; mi < 4; ++mi)
#pragma unroll
        for (int ni = 0; ni < 4; ++ni)
          acc[mi][ni] = MFMA_BF16(afl[mi], bfh[ni], acc[mi][ni], 0, 0, 0);
      __builtin_amdgcn_s_setprio(0);
    }
  };

  STAGE(0, kbeg);
  int cur = 0;
  for (int kt = kbeg; kt < kend; ++kt) {
    bool more = (kt + 1 < kend);
    if (more) STAGE(cur ^ 1, kt + 1);
    if (more) {
      if constexpr (NST == 4) asm volatile("s_waitcnt vmcnt(8)" ::: "memory");
      else if constexpr (NST == 3) asm volatile("s_waitcnt vmcnt(6)" ::: "memory");
      else asm volatile("s_waitcnt vmcnt(4)" ::: "memory");
    } else {
      asm volatile("s_waitcnt vmcnt(0)" ::: "memory");
    }
    __builtin_amdgcn_s_barrier();
    asm volatile("" ::: "memory");
    COMPUTE(cur);
    asm volatile("" ::: "memory");
    __builtin_amdgcn_s_barrier();
    asm volatile("" ::: "memory");
    cur ^= 1;
  }

  int m0 = (by << 7) + wr + (kg << 2);
  int n0 = (bx << 7) + wc;
#pragma unroll
  for (int mi = 0; mi < 4; ++mi) {
#pragma unroll
    for (int ni = 0; ni < 4; ++ni) {
      int col = n0 + (ni << 4) + lrow;
      float bv = 0.f;
      if ((KSP == 1) && (F & FB_BIAS)) bv = bias[col];
      int rb = m0 + (mi << 4);
#pragma unroll
      for (int r = 0; r < 4; ++r) {
        float v = acc[mi][ni][r];
        long ci = (long)bz * sCz + (long)(rb + r) * ldc + col;
        if constexpr (KSP > 1) {
          Cf[(long)ks * pstride + ci] = v;
        } else {
          v += bv;
          if (F & FB_RELU) v = fmaxf(v, 0.f);
          if (F & FB_RES) v += resF[ci];
          if (F & FB_F32) Cf[ci] = v;
          if (F & FB_SPLIT) {
            u16 h = f2bf(v);
            Ch[ci] = h;
            Cl[ci] = f2bf(v - bf2f(h));
          }
        }
      }
    }
  }
}

// ============================================================================
// 256x256 split GEMM, 8 waves, BK=32, 4-phase interleave (R9 schedule),
// templated AS/BS. ph0 wait = vmcnt(1+AS).
// ============================================================================
template <int F, int KSP, bool AS, bool BS>
__global__ __launch_bounds__(512, 2) void gemm_big(
    const u16* __restrict__ Ah, const u16* __restrict__ Al, int lda,
    const u16* __restrict__ Bh, const u16* __restrict__ Bl, int ldb,
    const float* __restrict__ bias,
    float* Cf, u16* Ch, u16* Cl, int ldc, int K, long pstride) {
  int gx = gridDim.x, gy = gridDim.y, gz = gridDim.z;
  long o = blockIdx.x + (long)gx * (blockIdx.y + (long)gy * blockIdx.z);
  long nwg = (long)gx * gy * gz;
  long cq = nwg >> 3, cr = nwg & 7;
  long xcd = o & 7, cidx = o >> 3;
  long sl = (xcd < cr ? xcd * (cq + 1) : cr * (cq + 1) + (xcd - cr) * cq) + cidx;
  int bx = (int)(sl % gx);
  long tt = sl / gx;
  int by = (int)(tt % gy);
  int ks = (int)(tt / gy);  // gz == KSP

  constexpr int SAH = 0;
  constexpr int SAL = 1;
  constexpr int SBH = 1 + (AS ? 1 : 0);
  constexpr int SBL = SBH + 1;

  __shared__ __align__(16) u16 Sbuf[2][2 + (AS ? 1 : 0) + (BS ? 1 : 0)][256 * 32];

  int tid = threadIdx.x;
  int lane = tid & 63;
  int wave = tid >> 6;
  int wm = (wave >> 2) << 7;
  int wn = (wave & 3) << 6;
  int lrow = lane & 15;
  int kg = lane >> 4;
  int kc8 = (kg ^ ((lrow >> 1) & 3)) << 3;

  const u16* Abh = Ah + ((long)(by << 8)) * lda;
  const u16* Abl = AS ? (Al + ((long)(by << 8)) * lda) : nullptr;
  const u16* Bbh = Bh + ((long)(bx << 8)) * ldb;
  const u16* Bbl = BS ? (Bl + ((long)(bx << 8)) * ldb) : nullptr;

  int nKtot = K >> 5;
  int kbeg = (KSP > 1) ? (ks * nKtot) / KSP : 0;
  int kend = (KSP > 1) ? ((ks + 1) * nKtot) / KSP : nKtot;

  f32x4 acc[8][4] = {};

  auto LOADA = [&](int buf, int kt, int it) {
    int sidx = (it << 9) + tid;
    int r = sidx >> 2;
    int jsw = (sidx & 3) ^ ((r >> 1) & 3);
    long off = (long)r * lda + ((kt << 5) + (jsw << 3));
    int loff = sidx << 3;
    __builtin_amdgcn_global_load_lds(
        (__attribute__((address_space(1))) void*)(Abh + off),
        (__attribute__((address_space(3))) void*)(&Sbuf[buf][SAH][loff]), 16, 0, 0);
    if constexpr (AS)
      __builtin_amdgcn_global_load_lds(
          (__attribute__((address_space(1))) void*)(Abl + off),
          (__attribute__((address_space(3))) void*)(&Sbuf[buf][SAL][loff]), 16, 0, 0);
  };
  auto LOADB = [&](int buf, int kt, int it) {
    int sidx = (it << 9) + tid;
    int r = sidx >> 2;
    int jsw = (sidx & 3) ^ ((r >> 1) & 3);
    long off = (long)r * ldb + ((kt << 5) + (jsw << 3));
    int loff = sidx << 3;
    __builtin_amdgcn_global_load_lds(
        (__attribute__((address_space(1))) void*)(Bbh + off),
        (__attribute__((address_space(3))) void*)(&Sbuf[buf][SBH][loff]), 16, 0, 0);
    if constexpr (BS)
      __builtin_amdgcn_global_load_lds(
          (__attribute__((address_space(1))) void*)(Bbl + off),
          (__attribute__((address_space(3))) void*)(&Sbuf[buf][SBL][loff]), 16, 0, 0);
  };

  bf16x8 bfh[4], bfl[4];
  auto PHASE = [&](int buf, int mi0) {
    int a0r = ((wm + (mi0 << 4) + lrow) << 5) + kc8;
    int a1r = ((wm + ((mi0 + 1) << 4) + lrow) << 5) + kc8;
    bf16x8 a0h = *(const bf16x8*)&Sbuf[buf][SAH][a0r];
    bf16x8 a1h = *(const bf16x8*)&Sbuf[buf][SAH][a1r];
    bf16x8 a0l, a1l;
    if constexpr (AS) {
      a0l = *(const bf16x8*)&Sbuf[buf][SAL][a0r];
      a1l = *(const bf16x8*)&Sbuf[buf][SAL][a1r];
    }
    __builtin_amdgcn_s_setprio(1);
#pragma unroll
    for (int ni = 0; ni < 4; ++ni) {
      acc[mi0][ni] = MFMA_BF16(a0h, bfh[ni], acc[mi0][ni], 0, 0, 0);
      if constexpr (BS) acc[mi0][ni] = MFMA_BF16(a0h, bfl[ni], acc[mi0][ni], 0, 0, 0);
      if constexpr (AS) acc[mi0][ni] = MFMA_BF16(a0l, bfh[ni], acc[mi0][ni], 0, 0, 0);
      acc[mi0 + 1][ni] = MFMA_BF16(a1h, bfh[ni], acc[mi0 + 1][ni], 0, 0, 0);
      if constexpr (BS) acc[mi0 + 1][ni] = MFMA_BF16(a1h, bfl[ni], acc[mi0 + 1][ni], 0, 0, 0);
      if constexpr (AS) acc[mi0 + 1][ni] = MFMA_BF16(a1l, bfh[ni], acc[mi0 + 1][ni], 0, 0, 0);
    }
    __builtin_amdgcn_s_setprio(0);
  };

#define BAR() do {                                                             \
    asm volatile("" ::: "memory");                                             \
    __builtin_amdgcn_s_barrier();                                              \
    asm volatile("" ::: "memory");                                             \
  } while (0)

  LOADA(0, kbeg, 0); LOADB(0, kbeg, 0);
  LOADA(0, kbeg, 1); LOADB(0, kbeg, 1);

  int cur = 0;
  for (int kt = kbeg; kt < kend; ++kt) {
    bool more = (kt + 1 < kend);
    int nb = cur ^ 1, kt1 = kt + 1;
    // ---- phase 0 ----
    if (more) LOADA(nb, kt1, 0);
    if (more) {
      if constexpr (AS) asm volatile("s_waitcnt vmcnt(2)" ::: "memory");
      else              asm volatile("s_waitcnt vmcnt(1)" ::: "memory");
    } else {
      asm volatile("s_waitcnt vmcnt(0)" ::: "memory");
    }
    BAR();
#pragma unroll
    for (int ni = 0; ni < 4; ++ni) {
      int brow = (wn + (ni << 4) + lrow) << 5;
      bfh[ni] = *(const bf16x8*)&Sbuf[cur][SBH][brow + kc8];
      if constexpr (BS) bfl[ni] = *(const bf16x8*)&Sbuf[cur][SBL][brow + kc8];
    }
    PHASE(cur, 0);
    BAR();
    // ---- phase 1 ----
    if (more) LOADB(nb, kt1, 0);
    PHASE(cur, 2);
    BAR();
    // ---- phase 2 ----
    if (more) LOADA(nb, kt1, 1);
    PHASE(cur, 4);
    BAR();
    // ---- phase 3 ----
    if (more) LOADB(nb, kt1, 1);
    PHASE(cur, 6);
    BAR();
    cur ^= 1;
  }
#undef BAR

  int m0 = (by << 8) + wm + (kg << 2);
  int n0 = (bx << 8) + wn;
#pragma unroll
  for (int mi = 0; mi < 8; ++mi) {
#pragma unroll
    for (int ni = 0; ni < 4; ++ni) {
      int col = n0 + (ni << 4) + lrow;
      float bv = 0.f;
      if ((KSP == 1) && (F & FB_BIAS)) bv = bias[col];
      int rb = m0 + (mi << 4);
#pragma unroll
      for (int r = 0; r < 4; ++r) {
        float v = acc[mi][ni][r];
        long ci = (long)(rb + r) * ldc + col;
        if constexpr (KSP > 1) {
          Cf[(long)ks * pstride + ci] = v;
        } else {
          v += bv;
          if (F & FB_RELU) v = fmaxf(v, 0.f);
          if (F & FB_F32) Cf[ci] = v;
          if (F & FB_SPLIT) {
            u16 h = f2bf(v);
            Ch[ci] = h;
            Cl[ci] = f2bf(v - bf2f(h));
          }
        }
      }
    }
  }
}

// ============================================================================
// reduce for split-K N=1024 GEMMs: v = sum_j p_j + bias (+rs); rs=v; x=split
// ============================================================================
template <int KSP, bool RES>
__global__ void reduce_split(const float* __restrict__ p,
                             const float* __restrict__ bias,
                             float* __restrict__ rs, u16* __restrict__ xh,
                             u16* __restrict__ xl) {
  long i = ((long)blockIdx.x * 256 + threadIdx.x) << 2;
  int col = (int)(i & 1023);
  constexpr long PSTR = (long)MM * HH1;
  float4 v;
  v.x = bias[col]; v.y = bias[col + 1]; v.z = bias[col + 2]; v.w = bias[col + 3];
#pragma unroll
  for (int j = 0; j < KSP; ++j) {
    float4 a = *(const float4*)(p + i + j * PSTR);
    v.x += a.x; v.y += a.y; v.z += a.z; v.w += a.w;
  }
  if (RES) {
    float4 r0 = *(const float4*)(rs + i);
    v.x += r0.x; v.y += r0.y; v.z += r0.z; v.w += r0.w;
  }
  *(float4*)(rs + i) = v;
  ushort4 h, l;
  h.x = f2bf(v.x); l.x = f2bf(v.x - bf2f(h.x));
  h.y = f2bf(v.y); l.y = f2bf(v.y - bf2f(h.y));
  h.z = f2bf(v.z); l.z = f2bf(v.z - bf2f(h.z));
  h.w = f2bf(v.w); l.w = f2bf(v.w - bf2f(h.w));
  *(ushort4*)(xh + i) = h;
  *(ushort4*)(xl + i) = l;
}

// ============================================================================
// fused splits
// ============================================================================
DI void split4(const float* src, u16* hi, u16* lo, long off) {
  float4 v = *(const float4*)(src + off);
  ushort4 h, l;
  h.x = f2bf(v.x); l.x = f2bf(v.x - bf2f(h.x));
  h.y = f2bf(v.y); l.y = f2bf(v.y - bf2f(h.y));
  h.z = f2bf(v.z); l.z = f2bf(v.z - bf2f(h.z));
  h.w = f2bf(v.w); l.w = f2bf(v.w - bf2f(h.w));
  *(ushort4*)(hi + off) = h;
  *(ushort4*)(lo + off) = l;
}

// generic elementwise split (activations)
__global__ void split_kernel(const float* __restrict__ src, u16* __restrict__ hi,
                             u16* __restrict__ lo) {
  long i = ((long)blockIdx.x * 256 + threadIdx.x) << 2;
  split4(src, hi, lo, i);
}

// per-layer mega split: wq/wk/wv -> wqkv, m1, m2, + bias concat.
// grid = 11264 + 3 blocks of 256.
constexpr long W1M = 1024 * 1024;
__global__ void layer_split(const float* __restrict__ wq, const float* __restrict__ wk,
                            const float* __restrict__ wv, const float* __restrict__ m1,
                            const float* __restrict__ m2,
                            const float* __restrict__ qb, const float* __restrict__ kb,
                            const float* __restrict__ vb,
                            u16* __restrict__ wqkvh, u16* __restrict__ wqkvl,
                            u16* __restrict__ m1h, u16* __restrict__ m1l,
                            u16* __restrict__ m2h, u16* __restrict__ m2l,
                            float* __restrict__ qkvb) {
  long bid = blockIdx.x;
  if (bid >= 11264) {  // bias tail: 3072 floats over 3 blocks x 256 thr x 4
    int e = (int)((bid - 11264) * 256 + threadIdx.x) << 2;
#pragma unroll
    for (int t = 0; t < 4; ++t) {
      int j = e + t;
      float v = (j < 1024) ? qb[j] : ((j < 2048) ? kb[j - 1024] : vb[j - 2048]);
      qkvb[j] = v;
    }
    return;
  }
  long i = (bid * 256 + threadIdx.x) << 2;  // f32 element offset, < 11M
  if (i < W1M)             split4(wq, wqkvh, wqkvl, i);
  else if (i < 2 * W1M)    split4(wk, wqkvh + W1M, wqkvl + W1M, i - W1M);
  else if (i < 3 * W1M)    split4(wv, wqkvh + 2 * W1M, wqkvl + 2 * W1M, i - 2 * W1M);
  else if (i < 7 * W1M)    split4(m1, m1h, m1l, i - 3 * W1M);
  else                     split4(m2, m2h, m2l, i - 7 * W1M);
}

// init split: dproj (2M) + uproj (2M). grid = 4096 x 256.
__global__ void init_split(const float* __restrict__ dpw, const float* __restrict__ upw,
                           u16* __restrict__ dpwh, u16* __restrict__ dpwl,
                           u16* __restrict__ upwh, u16* __restrict__ upwl) {
  long i = ((long)blockIdx.x * 256 + threadIdx.x) << 2;
  if (i < 2 * W1M) split4(dpw, dpwh, dpwl, i);
  else             split4(upw, upwh, upwl, i - 2 * W1M);
}

// ============================================================================
// deg: deg[b][q] = 1 iff q < (first k with attmask[b][k]!=0).
// ============================================================================
__global__ void deg_kernel(const int* __restrict__ am, int* __restrict__ deg) {
  int b = blockIdx.x;
  const int* a = am + b * SSQ;
  int tid = threadIdx.x;
  int fz = SSQ;
  for (int k = tid; k < SSQ; k += 256)
    if (a[k] != 0) fz = min(fz, k);
#pragma unroll
  for (int o = 32; o; o >>= 1) fz = min(fz, __shfl_xor(fz, o));
  __shared__ int red[4];
  if ((tid & 63) == 0) red[tid >> 6] = fz;
  __syncthreads();
  int f = min(min(red[0], red[1]), min(red[2], red[3]));
  for (int q = tid; q < SSQ; q += 256) deg[b * SSQ + q] = (q < f) ? 1 : 0;
}

// ============================================================================
// fused hi/lo transpose: VT[b][n][k] = V[b*S+k][n], V leading dim sld
// ============================================================================
__global__ void transpose_v2(const u16* __restrict__ Vh, const u16* __restrict__ Vl,
                             int sld, u16* __restrict__ VTh, u16* __restrict__ VTl) {
  __shared__ u16 th[64][68];
  __shared__ u16 tl[64][68];
  int b = blockIdx.z;
  int c0 = blockIdx.x << 6;
  int r0 = blockIdx.y << 6;
  int tr = threadIdx.x >> 4, tc = threadIdx.x & 15;
  long sbase = ((long)(b * SSQ + r0)) * sld + c0;
#pragma unroll
  for (int j = 0; j < 4; ++j) {
    int r = (j << 4) + tr;
    ushort4 uh = *(const ushort4*)(Vh + sbase + (long)r * sld + (tc << 2));
    ushort4 ul = *(const ushort4*)(Vl + sbase + (long)r * sld + (tc << 2));
    th[r][(tc << 2) + 0] = uh.x; th[r][(tc << 2) + 1] = uh.y;
    th[r][(tc << 2) + 2] = uh.z; th[r][(tc << 2) + 3] = uh.w;
    tl[r][(tc << 2) + 0] = ul.x; tl[r][(tc << 2) + 1] = ul.y;
    tl[r][(tc << 2) + 2] = ul.z; tl[r][(tc << 2) + 3] = ul.w;
  }
  __syncthreads();
  long dbase = ((long)b * HH1 + c0) * SSQ + r0;
#pragma unroll
  for (int j = 0; j < 4; ++j) {
    int c = (j << 4) + tr;
    ushort4 uh, ul;
    uh.x = th[(tc << 2) + 0][c]; uh.y = th[(tc << 2) + 1][c];
    uh.z = th[(tc << 2) + 2][c]; uh.w = th[(tc << 2) + 3][c];
    ul.x = tl[(tc << 2) + 0][c]; ul.y = tl[(tc << 2) + 1][c];
    ul.z = tl[(tc << 2) + 2][c]; ul.w = tl[(tc << 2) + 3][c];
    *(ushort4*)(VTh + dbase + (long)c * SSQ + (tc << 2)) = uh;
    *(ushort4*)(VTl + dbase + (long)c * SSQ + (tc << 2)) = ul;
  }
}

// ============================================================================
// column mean of V (degenerate rows); V hi/lo with leading dim ld
// ============================================================================
__global__ void colmean_partial(const u16* __restrict__ Vh, const u16* __restrict__ Vl,
                                int ld, float* __restrict__ part) {
  int n = blockIdx.x * 256 + threadIdx.x;
  int b = blockIdx.y, kc = blockIdx.z;
  long base = ((long)(b * SSQ + kc * 256)) * ld + n;
  float s = 0.f;
  for (int k = 0; k < 256; ++k) {
    long o = base + (long)k * ld;
    s += bf2f(Vh[o]) + bf2f(Vl[o]);
  }
  part[((kc * BB) + b) * HH1 + n] = s;
}
__global__ void colmean_final(const float* __restrict__ part, float* __restrict__ mV) {
  int i = blockIdx.x * 256 + threadIdx.x;
  int b = i >> 10, n = i & 1023;
  float s = 0.f;
  for (int kc = 0; kc < 8; ++kc) s += part[((kc * BB) + b) * HH1 + n];
  mV[i] = s * (1.f / (float)SSQ);
}

// ============================================================================
// row softmax: sums two score partials into LDS, exp once, writes P hi/lo.
// ============================================================================
__global__ void softmax_kernel(const float* __restrict__ sc, u16* __restrict__ Ph,
                               u16* __restrict__ Pl, const int* __restrict__ am,
                               const int* __restrict__ deg) {
  int q = blockIdx.x, b = blockIdx.y;
  int tid = threadIdx.x;
  long rowoff = ((long)b * SSQ + q) * SSQ;
  int qt_end = ((q >> 7) + 1) << 7;
  if (deg[b * SSQ + q]) {
    for (int k = tid; k < qt_end; k += 256) { Ph[rowoff + k] = 0; Pl[rowoff + k] = 0; }
    return;
  }
  const int* a = am + b * SSQ;
  const float scale = 0.03125f;  // 1/sqrt(1024)
  constexpr long PSTR = (long)BB * SSQ * SSQ;
  __shared__ float rowbuf[2048];
  __shared__ float sred[8];
  int w = tid >> 6, ln = tid & 63;

  for (int k = tid; k < qt_end; k += 256)
    rowbuf[k] = sc[rowoff + k] + sc[rowoff + k + PSTR];
  __syncthreads();

  float m = -1e30f;
  for (int k = tid; k <= q; k += 256)
    if (a[k]) m = fmaxf(m, rowbuf[k]);
#pragma unroll
  for (int o = 32; o; o >>= 1) m = fmaxf(m, __shfl_xor(m, o));
  if (!ln) sred[w] = m;
  __syncthreads();
  float M = fmaxf(fmaxf(sred[0], sred[1]), fmaxf(sred[2], sred[3]));

  float s = 0.f;
  for (int k = tid; k < qt_end; k += 256) {
    float p = 0.f;
    if (k <= q && a[k]) p = expf((rowbuf[k] - M) * scale);
    rowbuf[k] = p;
    s += p;
  }
#pragma unroll
  for (int o = 32; o; o >>= 1) s += __shfl_xor(s, o);
  if (!ln) sred[4 + w] = s;
  __syncthreads();
  float Ssum = sred[4] + sred[5] + sred[6] + sred[7];
  float inv = 1.f / Ssum;

  for (int k = tid; k < qt_end; k += 256) {
    float p = rowbuf[k] * inv;
    u16 h = f2bf(p);
    Ph[rowoff + k] = h;
    Pl[rowoff + k] = f2bf(p - bf2f(h));
  }
}

// ============================================================================
// post-attention: rs += pv0+pv1 (+meanV for degenerate rows); x = split(rs)
// ============================================================================
__global__ void attn_post(float* __restrict__ rs, const float* __restrict__ pv,
                          u16* __restrict__ xh, u16* __restrict__ xl,
                          const int* __restrict__ deg, const float* __restrict__ mV) {
  long t = (long)blockIdx.x * 256 + threadIdx.x;
  long i = t << 2;
  int row = (int)(i >> 10);
  int col = (int)(i & 1023);
  int b = row >> 11;
  constexpr long PSTR = (long)BB * SSQ * HH1;
  float4 v = *(const float4*)(rs + i);
  float4 a = *(const float4*)(pv + i);
  float4 c = *(const float4*)(pv + i + PSTR);
  v.x += a.x + c.x; v.y += a.y + c.y; v.z += a.z + c.z; v.w += a.w + c.w;
  if (deg[row]) {
    const float* m = mV + (b << 10) + col;
    v.x += m[0]; v.y += m[1]; v.z += m[2]; v.w += m[3];
  }
  *(float4*)(rs + i) = v;
  ushort4 h, l;
  h.x = f2bf(v.x); l.x = f2bf(v.x - bf2f(h.x));
  h.y = f2bf(v.y); l.y = f2bf(v.y - bf2f(h.y));
  h.z = f2bf(v.z); l.z = f2bf(v.z - bf2f(h.z));
  h.w = f2bf(v.w); l.w = f2bf(v.w - bf2f(h.w));
  *(ushort4*)(xh + i) = h;
  *(ushort4*)(xl + i) = l;
}

// ============================================================================
// workspace layout (1 MB = 1<<20), ~221MB, lifetime-aliased (R9 layout)
// ============================================================================
constexpr size_t MB = 1u << 20;
constexpr size_t OFF_RS    = 0;
constexpr size_t OFF_XH    = 16 * MB;
constexpr size_t OFF_XL    = 24 * MB;
constexpr size_t OFF_QKVH  = 32 * MB;
constexpr size_t OFF_QKVL  = 56 * MB;
constexpr size_t OFF_PH    = 32 * MB;   // alias
constexpr size_t OFF_PL    = 48 * MB;
constexpr size_t OFF_RED   = 32 * MB;   // f32 [4][4096][1024] 64MB (alias 32-96)
constexpr size_t OFF_VTH   = 80 * MB;
constexpr size_t OFF_VTL   = 88 * MB;
constexpr size_t OFF_SC    = 96 * MB;   // f32 [2][B][S][S] | act | h
constexpr size_t OFF_ACTH  = 96 * MB;
constexpr size_t OFF_ACTL  = 112 * MB;
constexpr size_t OFF_HH    = 96 * MB;
constexpr size_t OFF_HL    = 128 * MB;
constexpr size_t OFF_PVP   = 128 * MB;  // alias with HL (disjoint lifetimes)
constexpr size_t OFF_DPWH  = 160 * MB;
constexpr size_t OFF_DPWL  = 164 * MB;
constexpr size_t OFF_UPWH  = 168 * MB;
constexpr size_t OFF_UPWL  = 172 * MB;
constexpr size_t OFF_WQKVH = 176 * MB;
constexpr size_t OFF_WQKVL = 182 * MB;
constexpr size_t OFF_M1H   = 188 * MB;
constexpr size_t OFF_M1L   = 196 * MB;
constexpr size_t OFF_M2H   = 204 * MB;
constexpr size_t OFF_M2L   = 212 * MB;
constexpr size_t OFF_QKVB  = 220 * MB;
constexpr size_t OFF_MV    = OFF_QKVB + 16 * 1024;
constexpr size_t OFF_PART  = OFF_MV + 16 * 1024;
constexpr size_t OFF_DEG   = OFF_PART + 128 * 1024;

extern "C" void kernel_launch(void* const* d_in, const int* in_sizes, int n_in,
                              void* d_out, int out_size, void* d_ws, size_t ws_size,
                              hipStream_t stream) {
  (void)in_sizes; (void)n_in; (void)out_size; (void)ws_size;

  const float* z    = (const float*)d_in[0];
  const float* act0 = (const float*)d_in[1];
  const float* act1 = (const float*)d_in[2];
  const int* amask  = (const int*)d_in[3];
  const float* dpw  = (const float*)d_in[4];
  const float* dpb  = (const float*)d_in[5];
  const float* upw  = (const float*)d_in[6];
  const float* upb  = (const float*)d_in[7];
  const float* wqw  = (const float*)d_in[8];
  const float* wqb  = (const float*)d_in[9];
  const float* wkw  = (const float*)d_in[10];
  const float* wkb  = (const float*)d_in[11];
  const float* wvw  = (const float*)d_in[12];
  const float* wvb  = (const float*)d_in[13];
  const float* m1w  = (const float*)d_in[14];
  const float* m1b  = (const float*)d_in[15];
  const float* m2w  = (const float*)d_in[16];
  const float* m2b  = (const float*)d_in[17];

  char* ws = (char*)d_ws;
  float* rs    = (float*)(ws + OFF_RS);
  u16* xh      = (u16*)(ws + OFF_XH);    u16* xl    = (u16*)(ws + OFF_XL);
  u16* qkvh    = (u16*)(ws + OFF_QKVH);  u16* qkvl  = (u16*)(ws + OFF_QKVL);
  u16* Ph      = (u16*)(ws + OFF_PH);    u16* Pl    = (u16*)(ws + OFF_PL);
  float* redp  = (float*)(ws + OFF_RED);
  u16* VTh     = (u16*)(ws + OFF_VTH);   u16* VTl   = (u16*)(ws + OFF_VTL);
  float* scb   = (float*)(ws + OFF_SC);
  u16* acth    = (u16*)(ws + OFF_ACTH);  u16* actl  = (u16*)(ws + OFF_ACTL);
  u16* hh      = (u16*)(ws + OFF_HH);    u16* hl    = (u16*)(ws + OFF_HL);
  float* pvp   = (float*)(ws + OFF_PVP);
  u16* dpwh    = (u16*)(ws + OFF_DPWH);  u16* dpwl  = (u16*)(ws + OFF_DPWL);
  u16* upwh    = (u16*)(ws + OFF_UPWH);  u16* upwl  = (u16*)(ws + OFF_UPWL);
  u16* wqkvh   = (u16*)(ws + OFF_WQKVH); u16* wqkvl = (u16*)(ws + OFF_WQKVL);
  u16* m1h     = (u16*)(ws + OFF_M1H);   u16* m1l   = (u16*)(ws + OFF_M1L);
  u16* m2h     = (u16*)(ws + OFF_M2H);   u16* m2l   = (u16*)(ws + OFF_M2L);
  float* qkvb  = (float*)(ws + OFF_QKVB);
  float* mV    = (float*)(ws + OFF_MV);
  float* part  = (float*)(ws + OFF_PART);
  int* deg     = (int*)(ws + OFF_DEG);

  constexpr long RPSTR = (long)MM * HH1;

  deg_kernel<<<dim3(BB), 256, 0, stream>>>(amask, deg);
  init_split<<<dim3(4096), 256, 0, stream>>>(dpw, upw, dpwh, dpwl, upwh, upwl);

  // rs = dproj(act0) + b ; x = split(rs)   [big 256^2 3-term, KSP4 + reduce]
  split_kernel<<<dim3((MM * HH0) / 1024), 256, 0, stream>>>(act0, acth, actl);
  gemm_big<0, 4, true, true><<<dim3(HH1 / 256, MM / 256, 4), 512, 0, stream>>>(
      acth, actl, HH0, dpwh, dpwl, HH0, nullptr,
      redp, nullptr, nullptr, HH1, HH0, RPSTR);
  reduce_split<4, false><<<dim3(MM * HH1 / 1024), 256, 0, stream>>>(
      redp, dpb, rs, xh, xl);

  for (int i = 0; i < NLAY; ++i) {
    // fused per-layer weight split + bias concat (1 dispatch)
    layer_split<<<dim3(11267), 256, 0, stream>>>(
        wqw + (size_t)i * HH1 * HH1, wkw + (size_t)i * HH1 * HH1,
        wvw + (size_t)i * HH1 * HH1, m1w + (size_t)i * HH4 * HH1,
        m2w + (size_t)i * HH1 * HH4,
        wqb + i * HH1, wkb + i * HH1, wvb + i * HH1,
        wqkvh, wqkvl, m1h, m1l, m2h, m2l, qkvb);

    if (i == 1) {
      split_kernel<<<dim3((MM * HH0) / 1024), 256, 0, stream>>>(act1, acth, actl);
      gemm_big<0, 4, true, true><<<dim3(HH1 / 256, MM / 256, 4), 512, 0, stream>>>(
          acth, actl, HH0, dpwh, dpwl, HH0, nullptr,
          redp, nullptr, nullptr, HH1, HH0, RPSTR);
      reduce_split<4, true><<<dim3(MM * HH1 / 1024), 256, 0, stream>>>(
          redp, dpb, rs, xh, xl);
    }

    // ---- attention ----
    gemm_split<FB_BIAS | FB_SPLIT, 1, true, true>
        <<<dim3(3072 / 128, MM / 128, 1), 256, 0, stream>>>(
        xh, xl, 0, HH1, wqkvh, wqkvl, 0, HH1, qkvb, nullptr,
        nullptr, qkvh, qkvl, 0, 3072, HH1, 0);

    transpose_v2<<<dim3(HH1 / 64, SSQ / 64, BB), 256, 0, stream>>>(
        qkvh + 2048, qkvl + 2048, 3072, VTh, VTl);
    colmean_partial<<<dim3(HH1 / 256, BB, 8), 256, 0, stream>>>(
        qkvh + 2048, qkvl + 2048, 3072, part);
    colmean_final<<<dim3((BB * HH1) / 256), 256, 0, stream>>>(part, mV);

    // scores = Q K^T, full 3-term, causal tile skip, split-K=2
    gemm_split<FB_CSKIP, 2, true, true>
        <<<dim3(SSQ / 128, SSQ / 128, BB * 2), 256, 0, stream>>>(
        qkvh, qkvl, (long)SSQ * 3072, 3072, qkvh + 1024, qkvl + 1024,
        (long)SSQ * 3072, 3072, nullptr, nullptr,
        scb, nullptr, nullptr, (long)SSQ * SSQ, SSQ, HH1, (long)BB * SSQ * SSQ);

    softmax_kernel<<<dim3(SSQ, BB), 256, 0, stream>>>(scb, Ph, Pl, amask, deg);

    // PV: full 3-term (Ph/Pl x VTh/VTl), causal-truncated K loop, split-K=2
    gemm_split<FB_CKLOOP, 2, true, true>
        <<<dim3(HH1 / 128, SSQ / 128, BB * 2), 256, 0, stream>>>(
        Ph, Pl, (long)SSQ * SSQ, SSQ, VTh, VTl, (long)HH1 * SSQ, SSQ,
        nullptr, nullptr,
        pvp, nullptr, nullptr, (long)SSQ * HH1, HH1, SSQ, (long)BB * SSQ * HH1);

    attn_post<<<dim3((MM * HH1 / 4) / 256), 256, 0, stream>>>(rs, pvp, xh, xl, deg, mV);

    // ---- mlp ----
    // mlp1: 3-term, writes hh + hl
    gemm_big<FB_BIAS | FB_RELU | FB_SPLIT, 1, true, true>
        <<<dim3(HH4 / 256, MM / 256, 1), 512, 0, stream>>>(
        xh, xl, HH1, m1h, m1l, HH1, m1b + i * HH4,
        nullptr, hh, hl, HH4, HH1, 0);
    // mlp2: 3-term (hh/hl x m2h/m2l), KSP4
    gemm_big<0, 4, true, true><<<dim3(HH1 / 256, MM / 256, 4), 512, 0, stream>>>(
        hh, hl, HH4, m2h, m2l, HH4, nullptr,
        redp, nullptr, nullptr, HH1, HH4, RPSTR);
    reduce_split<4, true><<<dim3(MM * HH1 / 1024), 256, 0, stream>>>(
        redp, m2b + i * HH1, rs, xh, xl);
  }

  // out = uproj(x) + b + z   (3-term, 128^2 kernel, direct epilogue)
  gemm_split<FB_BIAS | FB_RES | FB_F32, 1, true, true>
      <<<dim3(HH0 / 128, MM / 128, 1), 256, 0, stream>>>(
      xh, xl, 0, HH1, upwh, upwl, 0, HH1, upb, z,
      (float*)d_out, nullptr, nullptr, 0, HH0, HH1, 0);
}